// Round 1
// baseline (1268.251 us; speedup 1.0000x reference)
//
#include <hip/hip_runtime.h>

#define NN 20000
#define NE 160000
#define NG 64

// ---------------- CSR build ----------------
__global__ void hist_kernel(const int* __restrict__ dst, int* __restrict__ deg) {
    int e = blockIdx.x * 256 + threadIdx.x;
    if (e < NE) atomicAdd(&deg[dst[e]], 1);
}

__global__ void scan_kernel(const int* __restrict__ deg, int* __restrict__ rowptr) {
    __shared__ int sh[1024];
    __shared__ int carry_s;
    int t = threadIdx.x;
    if (t == 0) carry_s = 0;
    __syncthreads();
    for (int base = 0; base < NN; base += 1024) {
        int i = base + t;
        int v = (i < NN) ? deg[i] : 0;
        sh[t] = v;
        __syncthreads();
        for (int off = 1; off < 1024; off <<= 1) {
            int add = (t >= off) ? sh[t - off] : 0;
            __syncthreads();
            sh[t] += add;
            __syncthreads();
        }
        int carry = carry_s;
        if (i < NN) rowptr[i] = carry + sh[t] - v;   // exclusive
        int total = sh[1023];
        __syncthreads();
        if (t == 0) carry_s = carry + total;
        __syncthreads();
    }
    if (t == 0) rowptr[NN] = carry_s;
}

__global__ void fill_kernel(const int* __restrict__ src, const int* __restrict__ dst,
                            const int* __restrict__ rowptr, int* __restrict__ wcount,
                            int* __restrict__ col) {
    int e = blockIdx.x * 256 + threadIdx.x;
    if (e < NE) {
        int d = dst[e];
        int p = rowptr[d] + atomicAdd(&wcount[d], 1);
        col[p] = src[e];
    }
}

// ---------------- mean aggregation (gather over CSR), fold 1/deg ----------------
template <int V>   // V = din/4 (float4 per row); blockDim.x == V
__global__ void agg_kernel(const float4* __restrict__ h4, const int* __restrict__ rowptr,
                           const int* __restrict__ col, float4* __restrict__ agg) {
    int n = blockIdx.x;
    int t = threadIdx.x;
    int s = rowptr[n], e = rowptr[n + 1];
    float4 acc = make_float4(0.f, 0.f, 0.f, 0.f);
    for (int j = s; j < e; ++j) {
        int c = col[j];
        float4 v = h4[(size_t)c * V + t];
        acc.x += v.x; acc.y += v.y; acc.z += v.z; acc.w += v.w;
    }
    float inv = 1.f / fmaxf((float)(e - s), 1.f);
    acc.x *= inv; acc.y *= inv; acc.z *= inv; acc.w *= inv;
    agg[(size_t)n * V + t] = acc;
}

// ---------------- fused dual GEMM: C = A1@W1 + A2@W2 + bias (+leaky) ----------------
// 64x64 C tile per 256-thread block, 4x4 per thread, K-chunk 16.
template <int ACT>
__global__ __launch_bounds__(256) void gemm_dual(
    const float* __restrict__ A1,   // agg (already mean-scaled) [M x K]
    const float* __restrict__ A2,   // h                         [M x K]
    const float* __restrict__ W1,   // [K x dout]
    const float* __restrict__ W2,   // [K x dout]
    const float* __restrict__ bias, // [dout]
    float* __restrict__ C, int M, int K, int dout) {
    __shared__ float As[16][68];
    __shared__ float Bs[16][68];
    int tid = threadIdx.x;
    int tx = tid & 15, ty = tid >> 4;
    int mblk = blockIdx.x * 64, nblk = blockIdx.y * 64;
    float acc[4][4] = {};

    for (int phase = 0; phase < 2; ++phase) {
        const float* A = phase ? A2 : A1;
        const float* W = phase ? W2 : W1;
        for (int k0 = 0; k0 < K; k0 += 16) {
            {   // A tile: 64 rows x 16 k, one float4 per thread, store transposed
                int row = tid >> 2;
                int kk = (tid & 3) * 4;
                int gr = mblk + row;
                float4 v = make_float4(0.f, 0.f, 0.f, 0.f);
                if (gr < M) v = *(const float4*)&A[(size_t)gr * K + k0 + kk];
                As[kk + 0][row] = v.x; As[kk + 1][row] = v.y;
                As[kk + 2][row] = v.z; As[kk + 3][row] = v.w;
            }
            {   // W tile: 16 k x 64 n
                int kk = tid >> 4;
                int nn = (tid & 15) * 4;
                float4 v = *(const float4*)&W[(size_t)(k0 + kk) * dout + nblk + nn];
                *(float4*)&Bs[kk][nn] = v;
            }
            __syncthreads();
            #pragma unroll
            for (int k = 0; k < 16; ++k) {
                float4 av = *(const float4*)&As[k][ty * 4];
                float4 bv = *(const float4*)&Bs[k][tx * 4];
                float a[4] = {av.x, av.y, av.z, av.w};
                float b[4] = {bv.x, bv.y, bv.z, bv.w};
                #pragma unroll
                for (int i = 0; i < 4; ++i)
                    #pragma unroll
                    for (int j = 0; j < 4; ++j)
                        acc[i][j] += a[i] * b[j];
            }
            __syncthreads();
        }
    }

    #pragma unroll
    for (int i = 0; i < 4; ++i) {
        int gm = mblk + ty * 4 + i;
        if (gm >= M) continue;
        #pragma unroll
        for (int j = 0; j < 4; ++j) {
            int gn = nblk + tx * 4 + j;
            float c = acc[i][j] + bias[gn];
            if (ACT) c = (c >= 0.f) ? c : 0.01f * c;
            C[(size_t)gm * dout + gn] = c;
        }
    }
}

// ---------------- global mean pool (scatter) ----------------
__global__ void pool_scatter(const float* __restrict__ h, const int* __restrict__ batch,
                             float* __restrict__ g, int* __restrict__ gcnt) {
    int n = blockIdx.x;
    int t = threadIdx.x;  // 256
    int b = batch[n];
    atomicAdd(&g[b * 256 + t], h[(size_t)n * 256 + t]);
    if (t == 0) atomicAdd(&gcnt[b], 1);
}

// ---------------- head: out[G,6] = (g/cnt) @ Wlin + blin ----------------
__global__ void final_kernel(const float* __restrict__ g, const int* __restrict__ gcnt,
                             const float* __restrict__ Wlin, const float* __restrict__ blin,
                             float* __restrict__ out) {
    int t = blockIdx.x * blockDim.x + threadIdx.x;
    if (t >= NG * 6) return;
    int gi = t / 6, o = t % 6;
    float inv = 1.f / fmaxf((float)gcnt[gi], 1.f);
    float s = 0.f;
    for (int k = 0; k < 256; ++k) s += g[gi * 256 + k] * Wlin[k * 6 + o];
    out[t] = s * inv + blin[o];
}

extern "C" void kernel_launch(void* const* d_in, const int* in_sizes, int n_in,
                              void* d_out, int out_size, void* d_ws, size_t ws_size,
                              hipStream_t stream) {
    const float* x = (const float*)d_in[0];
    const int* ei = (const int*)d_in[1];       // [2, E] row-major: src then dst
    const int* batch = (const int*)d_in[2];
    const float *Wl[6], *bl[6], *Wr[6];
    for (int l = 0; l < 6; ++l) {
        Wl[l] = (const float*)d_in[3 + 3 * l];
        bl[l] = (const float*)d_in[4 + 3 * l];
        Wr[l] = (const float*)d_in[5 + 3 * l];
    }
    const float* Wlin = (const float*)d_in[21];
    const float* blin = (const float*)d_in[22];
    float* out = (float*)d_out;

    char* ws = (char*)d_ws;
    size_t off = 0;
    auto alloc = [&](size_t bytes) {
        void* p = ws + off;
        off += (bytes + 255) & ~(size_t)255;
        return p;
    };
    float* bufA = (float*)alloc((size_t)NN * 512 * 4);
    float* bufB = (float*)alloc((size_t)NN * 512 * 4);
    float* aggb = (float*)alloc((size_t)NN * 512 * 4);
    int* col    = (int*)alloc((size_t)NE * 4);
    // ---- zeroed region start ----
    float* g    = (float*)alloc((size_t)NG * 256 * 4);
    int* deg    = (int*)alloc((size_t)NN * 4);
    int* wcount = (int*)alloc((size_t)NN * 4);
    int* gcnt   = (int*)alloc((size_t)NG * 4);
    // ---- zeroed region end ----
    int* rowptr = (int*)alloc((size_t)(NN + 1) * 4);
    (void)ws_size; (void)in_sizes; (void)n_in; (void)out_size;

    size_t zero_bytes = (size_t)((char*)gcnt - (char*)g) + NG * 4;
    hipMemsetAsync((void*)g, 0, zero_bytes, stream);

    const int* src = ei;
    const int* dst = ei + NE;
    hist_kernel<<<(NE + 255) / 256, 256, 0, stream>>>(dst, deg);
    scan_kernel<<<1, 1024, 0, stream>>>(deg, rowptr);
    fill_kernel<<<(NE + 255) / 256, 256, 0, stream>>>(src, dst, rowptr, wcount, col);

    const int dins[6]  = {128, 256, 256, 512, 512, 256};
    const int douts[6] = {256, 256, 512, 512, 256, 256};
    const float* hin = x;
    float* ping = bufA;
    float* pong = bufB;
    for (int l = 0; l < 6; ++l) {
        int din = dins[l], dout = douts[l];
        int V = din / 4;
        if (V == 32)
            agg_kernel<32><<<NN, 32, 0, stream>>>((const float4*)hin, rowptr, col, (float4*)aggb);
        else if (V == 64)
            agg_kernel<64><<<NN, 64, 0, stream>>>((const float4*)hin, rowptr, col, (float4*)aggb);
        else
            agg_kernel<128><<<NN, 128, 0, stream>>>((const float4*)hin, rowptr, col, (float4*)aggb);

        dim3 grid((NN + 63) / 64, dout / 64);
        if (l < 5)
            gemm_dual<1><<<grid, 256, 0, stream>>>(aggb, hin, Wl[l], Wr[l], bl[l], ping, NN, din, dout);
        else
            gemm_dual<0><<<grid, 256, 0, stream>>>(aggb, hin, Wl[l], Wr[l], bl[l], ping, NN, din, dout);

        hin = ping;
        float* t = ping; ping = pong; pong = t;
    }

    pool_scatter<<<NN, 256, 0, stream>>>(hin, batch, g, gcnt);
    final_kernel<<<1, 384, 0, stream>>>(g, gcnt, Wlin, blin, out);
}

// Round 3
// 916.702 us; speedup vs baseline: 1.3835x; 1.3835x over previous
//
#include <hip/hip_runtime.h>

#define NN 20000
#define NE 160000
#define NG 64

typedef __attribute__((ext_vector_type(8))) short bf16x8;
typedef __attribute__((ext_vector_type(4))) float f32x4;

// round-to-nearest bf16 split: x ~= hi + lo (both bf16)
__device__ __forceinline__ void f2bf(float x, short& hi, short& lo) {
    unsigned u = __float_as_uint(x);
    unsigned rh = (u + 0x7FFFu + ((u >> 16) & 1u)) & 0xFFFF0000u;
    hi = (short)(rh >> 16);
    float l = x - __uint_as_float(rh);
    unsigned ul = __float_as_uint(l);
    lo = (short)((ul + 0x7FFFu + ((ul >> 16) & 1u)) >> 16);
}

// ---------------- CSR build ----------------
__global__ void hist_kernel(const int* __restrict__ dst, int* __restrict__ deg) {
    int e = blockIdx.x * 256 + threadIdx.x;
    if (e < NE) atomicAdd(&deg[dst[e]], 1);
}

__global__ void scan_kernel(const int* __restrict__ deg, int* __restrict__ rowptr) {
    __shared__ int sh[1024];
    __shared__ int carry_s;
    int t = threadIdx.x;
    if (t == 0) carry_s = 0;
    __syncthreads();
    for (int base = 0; base < NN; base += 1024) {
        int i = base + t;
        int v = (i < NN) ? deg[i] : 0;
        sh[t] = v;
        __syncthreads();
        for (int off = 1; off < 1024; off <<= 1) {
            int add = (t >= off) ? sh[t - off] : 0;
            __syncthreads();
            sh[t] += add;
            __syncthreads();
        }
        int carry = carry_s;
        if (i < NN) rowptr[i] = carry + sh[t] - v;   // exclusive
        int total = sh[1023];
        __syncthreads();
        if (t == 0) carry_s = carry + total;
        __syncthreads();
    }
    if (t == 0) rowptr[NN] = carry_s;
}

__global__ void fill_kernel(const int* __restrict__ src, const int* __restrict__ dst,
                            const int* __restrict__ rowptr, int* __restrict__ wcount,
                            int* __restrict__ col) {
    int e = blockIdx.x * 256 + threadIdx.x;
    if (e < NE) {
        int d = dst[e];
        int p = rowptr[d] + atomicAdd(&wcount[d], 1);
        col[p] = src[e];
    }
}

// ---------------- mean aggregation (gather over CSR), fold 1/deg ----------------
template <int V>   // V = din/4 (float4 per row); 256/V nodes per block
__global__ __launch_bounds__(256) void agg_kernel(const float4* __restrict__ h4,
                                                  const int* __restrict__ rowptr,
                                                  const int* __restrict__ col,
                                                  float4* __restrict__ agg) {
    constexpr int NPB = 256 / V;
    int node = blockIdx.x * NPB + threadIdx.x / V;
    if (node >= NN) return;
    int t = threadIdx.x % V;
    int s = rowptr[node], e = rowptr[node + 1];
    float4 acc = make_float4(0.f, 0.f, 0.f, 0.f);
    for (int j = s; j < e; ++j) {
        int c = col[j];
        float4 v = h4[(size_t)c * V + t];
        acc.x += v.x; acc.y += v.y; acc.z += v.z; acc.w += v.w;
    }
    float inv = 1.f / fmaxf((float)(e - s), 1.f);
    acc.x *= inv; acc.y *= inv; acc.z *= inv; acc.w *= inv;
    agg[(size_t)node * V + t] = acc;
}

// ---------------- W transpose + bf16 hi/lo split: [K][dout] -> [dout][K] ----------------
__global__ __launch_bounds__(256) void wconv_kernel(const float* __restrict__ W,
                                                    short* __restrict__ Wt_hi,
                                                    short* __restrict__ Wt_lo,
                                                    int K, int dout) {
    __shared__ float tile[32][33];
    int kb = blockIdx.x * 32, nb = blockIdx.y * 32;
    int t = threadIdx.x;
    int lr = t >> 5, lc = t & 31;
    #pragma unroll
    for (int r = 0; r < 4; ++r)
        tile[lr + r * 8][lc] = W[(size_t)(kb + lr + r * 8) * dout + nb + lc];
    __syncthreads();
    int nn = t >> 3, kq = (t & 7) * 4;
    short4 h, l;
    f2bf(tile[kq + 0][nn], h.x, l.x);
    f2bf(tile[kq + 1][nn], h.y, l.y);
    f2bf(tile[kq + 2][nn], h.z, l.z);
    f2bf(tile[kq + 3][nn], h.w, l.w);
    *(short4*)&Wt_hi[(size_t)(nb + nn) * K + kb + kq] = h;
    *(short4*)&Wt_lo[(size_t)(nb + nn) * K + kb + kq] = l;
}

// ---------------- fused dual GEMM via split-bf16 MFMA ----------------
// C = A1@W1 + A2@W2 + bias (+leaky). 128x128 tile, 4 waves 2x2, each 64x64.
#define LP 40   // LDS row pitch in shorts (80B: 16B-aligned, spreads banks)

template <int ACT>
__global__ __launch_bounds__(256) void gemm_mfma(
    const float* __restrict__ A1, const float* __restrict__ A2,
    const short* __restrict__ W1h, const short* __restrict__ W1l,   // [dout][K] bf16
    const short* __restrict__ W2h, const short* __restrict__ W2l,
    const float* __restrict__ bias, float* __restrict__ C,
    int M, int K, int dout) {
    __shared__ short As_hi[128][LP];
    __shared__ short As_lo[128][LP];
    __shared__ short Bs_hi[128][LP];
    __shared__ short Bs_lo[128][LP];
    int tid = threadIdx.x;
    int lane = tid & 63, wid = tid >> 6;
    int wm = wid >> 1, wn = wid & 1;
    int mblk = blockIdx.x * 128, nblk = blockIdx.y * 128;
    f32x4 acc[4][4] = {};
    int KK = 2 * K;

    for (int k0 = 0; k0 < KK; k0 += 32) {
        const float* A; const short* Wh; const short* Wl; int kc;
        if (k0 < K) { A = A1; Wh = W1h; Wl = W1l; kc = k0; }
        else        { A = A2; Wh = W2h; Wl = W2l; kc = k0 - K; }

        // stage A tile: 128 rows x 32 k, convert f32 -> hi/lo
        #pragma unroll
        for (int r = 0; r < 4; ++r) {
            int flat = r * 256 + tid;
            int row = flat >> 3, k4 = (flat & 7) * 4;
            int gr = mblk + row;
            float4 v = make_float4(0.f, 0.f, 0.f, 0.f);
            if (gr < M) v = *(const float4*)&A[(size_t)gr * K + kc + k4];
            short4 h, l;
            f2bf(v.x, h.x, l.x); f2bf(v.y, h.y, l.y);
            f2bf(v.z, h.z, l.z); f2bf(v.w, h.w, l.w);
            *(short4*)&As_hi[row][k4] = h;
            *(short4*)&As_lo[row][k4] = l;
        }
        // stage B tile: 128 cols x 32 k from pre-transposed bf16 W^T
        #pragma unroll
        for (int r = 0; r < 2; ++r) {
            int flat = r * 256 + tid;
            int c = flat >> 2, kq = (flat & 3) * 8;
            size_t gb = (size_t)(nblk + c) * K + kc + kq;
            *(bf16x8*)&Bs_hi[c][kq] = *(const bf16x8*)&Wh[gb];
            *(bf16x8*)&Bs_lo[c][kq] = *(const bf16x8*)&Wl[gb];
        }
        __syncthreads();

        int koff = (lane >> 4) * 8;
        int arow = wm * 64 + (lane & 15);
        int bcol = wn * 64 + (lane & 15);
        bf16x8 ah[4], al[4], bh[4], bl[4];
        #pragma unroll
        for (int i = 0; i < 4; ++i) {
            ah[i] = *(const bf16x8*)&As_hi[arow + i * 16][koff];
            al[i] = *(const bf16x8*)&As_lo[arow + i * 16][koff];
            bh[i] = *(const bf16x8*)&Bs_hi[bcol + i * 16][koff];
            bl[i] = *(const bf16x8*)&Bs_lo[bcol + i * 16][koff];
        }
        #pragma unroll
        for (int i = 0; i < 4; ++i)
            #pragma unroll
            for (int j = 0; j < 4; ++j) {
                acc[i][j] = __builtin_amdgcn_mfma_f32_16x16x32_bf16(ah[i], bh[j], acc[i][j], 0, 0, 0);
                acc[i][j] = __builtin_amdgcn_mfma_f32_16x16x32_bf16(ah[i], bl[j], acc[i][j], 0, 0, 0);
                acc[i][j] = __builtin_amdgcn_mfma_f32_16x16x32_bf16(al[i], bh[j], acc[i][j], 0, 0, 0);
            }
        __syncthreads();
    }

    // epilogue: C/D layout col=lane&15, row=(lane>>4)*4+reg
    int crow = mblk + wm * 64 + ((lane >> 4) << 2);
    int ccol = nblk + wn * 64 + (lane & 15);
    #pragma unroll
    for (int i = 0; i < 4; ++i) {
        #pragma unroll
        for (int r = 0; r < 4; ++r) {
            int gm = crow + i * 16 + r;
            if (gm >= M) continue;
            #pragma unroll
            for (int j = 0; j < 4; ++j) {
                int gn = ccol + j * 16;
                float c = acc[i][j][r] + bias[gn];
                if (ACT) c = (c >= 0.f) ? c : 0.01f * c;
                C[(size_t)gm * dout + gn] = c;
            }
        }
    }
}

// ---------------- global mean pool (scatter) ----------------
__global__ void pool_scatter(const float* __restrict__ h, const int* __restrict__ batch,
                             float* __restrict__ g, int* __restrict__ gcnt) {
    int n = blockIdx.x;
    int t = threadIdx.x;  // 256
    int b = batch[n];
    atomicAdd(&g[b * 256 + t], h[(size_t)n * 256 + t]);
    if (t == 0) atomicAdd(&gcnt[b], 1);
}

// ---------------- head: out[G,6] = (g/cnt) @ Wlin + blin ----------------
__global__ void final_kernel(const float* __restrict__ g, const int* __restrict__ gcnt,
                             const float* __restrict__ Wlin, const float* __restrict__ blin,
                             float* __restrict__ out) {
    int t = blockIdx.x * blockDim.x + threadIdx.x;
    if (t >= NG * 6) return;
    int gi = t / 6, o = t % 6;
    float inv = 1.f / fmaxf((float)gcnt[gi], 1.f);
    float s = 0.f;
    for (int k = 0; k < 256; ++k) s += g[gi * 256 + k] * Wlin[k * 6 + o];
    out[t] = s * inv + blin[o];
}

extern "C" void kernel_launch(void* const* d_in, const int* in_sizes, int n_in,
                              void* d_out, int out_size, void* d_ws, size_t ws_size,
                              hipStream_t stream) {
    const float* x = (const float*)d_in[0];
    const int* ei = (const int*)d_in[1];       // [2, E]: src then dst
    const int* batch = (const int*)d_in[2];
    const float *Wl[6], *bl[6], *Wr[6];
    for (int l = 0; l < 6; ++l) {
        Wl[l] = (const float*)d_in[3 + 3 * l];
        bl[l] = (const float*)d_in[4 + 3 * l];
        Wr[l] = (const float*)d_in[5 + 3 * l];
    }
    const float* Wlin = (const float*)d_in[21];
    const float* blin = (const float*)d_in[22];
    float* out = (float*)d_out;

    char* ws = (char*)d_ws;
    size_t off = 0;
    auto alloc = [&](size_t bytes) {
        void* p = ws + off;
        off += (bytes + 255) & ~(size_t)255;
        return p;
    };
    float* bufA = (float*)alloc((size_t)NN * 512 * 4);
    float* bufB = (float*)alloc((size_t)NN * 512 * 4);
    float* aggb = (float*)alloc((size_t)NN * 512 * 4);
    int* col    = (int*)alloc((size_t)NE * 4);
    // ---- zeroed region start ----
    float* g    = (float*)alloc((size_t)NG * 256 * 4);
    int* deg    = (int*)alloc((size_t)NN * 4);
    int* wcount = (int*)alloc((size_t)NN * 4);
    int* gcnt   = (int*)alloc((size_t)NG * 4);
    // ---- zeroed region end ----
    int* rowptr = (int*)alloc((size_t)(NN + 1) * 4);
    short* wtbuf = (short*)alloc((size_t)4 * 688128 * 2);  // hi/lo for Wl,Wr all layers
    (void)ws_size; (void)in_sizes; (void)n_in; (void)out_size;

    size_t zero_bytes = (size_t)((char*)gcnt - (char*)g) + NG * 4;
    hipMemsetAsync((void*)g, 0, zero_bytes, stream);

    const int* src = ei;
    const int* dst = ei + NE;
    hist_kernel<<<(NE + 255) / 256, 256, 0, stream>>>(dst, deg);
    scan_kernel<<<1, 1024, 0, stream>>>(deg, rowptr);
    fill_kernel<<<(NE + 255) / 256, 256, 0, stream>>>(src, dst, rowptr, wcount, col);

    const int dins[6]  = {128, 256, 256, 512, 512, 256};
    const int douts[6] = {256, 256, 512, 512, 256, 256};

    // pre-transpose + split all weights to bf16 hi/lo [dout][K]
    short *W1h[6], *W1l[6], *W2h[6], *W2l[6];
    {
        short* p = wtbuf;
        for (int l = 0; l < 6; ++l) {
            size_t sz = (size_t)dins[l] * douts[l];
            W1h[l] = p; p += sz;  W1l[l] = p; p += sz;
            W2h[l] = p; p += sz;  W2l[l] = p; p += sz;
            dim3 wg(dins[l] / 32, douts[l] / 32);
            wconv_kernel<<<wg, 256, 0, stream>>>(Wl[l], W1h[l], W1l[l], dins[l], douts[l]);
            wconv_kernel<<<wg, 256, 0, stream>>>(Wr[l], W2h[l], W2l[l], dins[l], douts[l]);
        }
    }

    const float* hin = x;
    float* ping = bufA;
    float* pong = bufB;
    for (int l = 0; l < 6; ++l) {
        int din = dins[l], dout = douts[l];
        int V = din / 4;
        if (V == 32)
            agg_kernel<32><<<(NN + 7) / 8, 256, 0, stream>>>((const float4*)hin, rowptr, col, (float4*)aggb);
        else if (V == 64)
            agg_kernel<64><<<(NN + 3) / 4, 256, 0, stream>>>((const float4*)hin, rowptr, col, (float4*)aggb);
        else
            agg_kernel<128><<<(NN + 1) / 2, 256, 0, stream>>>((const float4*)hin, rowptr, col, (float4*)aggb);

        dim3 grid((NN + 127) / 128, dout / 128);
        if (l < 5)
            gemm_mfma<1><<<grid, 256, 0, stream>>>(aggb, hin, W1h[l], W1l[l], W2h[l], W2l[l],
                                                   bl[l], ping, NN, din, dout);
        else
            gemm_mfma<0><<<grid, 256, 0, stream>>>(aggb, hin, W1h[l], W1l[l], W2h[l], W2l[l],
                                                   bl[l], ping, NN, din, dout);

        hin = ping;
        float* t = ping; ping = pong; pong = t;
    }

    pool_scatter<<<NN, 256, 0, stream>>>(hin, batch, g, gcnt);
    final_kernel<<<1, 384, 0, stream>>>(g, gcnt, Wlin, blin, out);
}

// Round 4
// 776.922 us; speedup vs baseline: 1.6324x; 1.1799x over previous
//
#include <hip/hip_runtime.h>

#define NN 20000
#define NE 160000
#define NG 64

typedef __attribute__((ext_vector_type(8))) short bf16x8;
typedef __attribute__((ext_vector_type(4))) float f32x4;

// round-to-nearest bf16 split: x ~= hi + lo (both bf16)
__device__ __forceinline__ void f2bf(float x, short& hi, short& lo) {
    unsigned u = __float_as_uint(x);
    unsigned rh = (u + 0x7FFFu + ((u >> 16) & 1u)) & 0xFFFF0000u;
    hi = (short)(rh >> 16);
    float l = x - __uint_as_float(rh);
    unsigned ul = __float_as_uint(l);
    lo = (short)((ul + 0x7FFFu + ((ul >> 16) & 1u)) >> 16);
}

// ---------------- CSR build ----------------
__global__ void hist_kernel(const int* __restrict__ dst, int* __restrict__ deg) {
    int e = blockIdx.x * 256 + threadIdx.x;
    if (e < NE) atomicAdd(&deg[dst[e]], 1);
}

// shfl-based scan: 1024 threads, 16 waves, 3 barriers per 1024-chunk
__global__ void scan_kernel(const int* __restrict__ deg, int* __restrict__ rowptr) {
    __shared__ int wsum[16];
    __shared__ int carry_s;
    int t = threadIdx.x;
    int lane = t & 63, w = t >> 6;
    if (t == 0) carry_s = 0;
    __syncthreads();
    for (int base = 0; base < NN; base += 1024) {
        int i = base + t;
        int v = (i < NN) ? deg[i] : 0;
        int s = v;  // inclusive wave scan
        #pragma unroll
        for (int off = 1; off < 64; off <<= 1) {
            int u = __shfl_up(s, off, 64);
            if (lane >= off) s += u;
        }
        if (lane == 63) wsum[w] = s;
        __syncthreads();
        if (w == 0 && lane < 16) {
            int ws = wsum[lane];
            #pragma unroll
            for (int off = 1; off < 16; off <<= 1) {
                int u = __shfl_up(ws, off, 64);
                if (lane >= off) ws += u;
            }
            wsum[lane] = ws;  // inclusive wave-sum scan
        }
        __syncthreads();
        int wpre = (w > 0) ? wsum[w - 1] : 0;
        int carry = carry_s;
        if (i < NN) rowptr[i] = carry + wpre + s - v;   // exclusive
        int total = wsum[15];
        __syncthreads();
        if (t == 0) carry_s = carry + total;
        __syncthreads();
    }
    if (t == 0) rowptr[NN] = carry_s;
}

__global__ void fill_kernel(const int* __restrict__ src, const int* __restrict__ dst,
                            const int* __restrict__ rowptr, int* __restrict__ wcount,
                            int* __restrict__ col) {
    int e = blockIdx.x * 256 + threadIdx.x;
    if (e < NE) {
        int d = dst[e];
        int p = rowptr[d] + atomicAdd(&wcount[d], 1);
        col[p] = src[e];
    }
}

// ---------------- mean aggregation (gather over CSR), fold 1/deg ----------------
template <int V>   // V = din/4 (float4 per row); 256/V nodes per block
__global__ __launch_bounds__(256) void agg_kernel(const float4* __restrict__ h4,
                                                  const int* __restrict__ rowptr,
                                                  const int* __restrict__ col,
                                                  float4* __restrict__ agg) {
    constexpr int NPB = 256 / V;
    int node = blockIdx.x * NPB + threadIdx.x / V;
    if (node >= NN) return;
    int t = threadIdx.x % V;
    int s = rowptr[node], e = rowptr[node + 1];
    float4 acc = make_float4(0.f, 0.f, 0.f, 0.f);
    for (int j = s; j < e; ++j) {
        int c = col[j];
        float4 v = h4[(size_t)c * V + t];
        acc.x += v.x; acc.y += v.y; acc.z += v.z; acc.w += v.w;
    }
    float inv = 1.f / fmaxf((float)(e - s), 1.f);
    acc.x *= inv; acc.y *= inv; acc.z *= inv; acc.w *= inv;
    agg[(size_t)node * V + t] = acc;
}

// ---------------- W transpose + bf16 hi/lo split: [K][dout] -> [dout][K] ----------------
__global__ __launch_bounds__(256) void wconv_kernel(const float* __restrict__ W,
                                                    short* __restrict__ Wt_hi,
                                                    short* __restrict__ Wt_lo,
                                                    int K, int dout) {
    __shared__ float tile[32][33];
    int kb = blockIdx.x * 32, nb = blockIdx.y * 32;
    int t = threadIdx.x;
    int lr = t >> 5, lc = t & 31;
    #pragma unroll
    for (int r = 0; r < 4; ++r)
        tile[lr + r * 8][lc] = W[(size_t)(kb + lr + r * 8) * dout + nb + lc];
    __syncthreads();
    int nn = t >> 3, kq = (t & 7) * 4;
    short4 h, l;
    f2bf(tile[kq + 0][nn], h.x, l.x);
    f2bf(tile[kq + 1][nn], h.y, l.y);
    f2bf(tile[kq + 2][nn], h.z, l.z);
    f2bf(tile[kq + 3][nn], h.w, l.w);
    *(short4*)&Wt_hi[(size_t)(nb + nn) * K + kb + kq] = h;
    *(short4*)&Wt_lo[(size_t)(nb + nn) * K + kb + kq] = l;
}

// ---------------- fused dual GEMM via split-bf16 MFMA ----------------
// C = A1@W1 + A2@W2 + bias (+leaky). 128x128 tile, 4 waves 2x2, each 64x64.
#define LP 40   // LDS row pitch in shorts (80B: 16B-aligned, spreads banks)

template <int ACT>
__global__ __launch_bounds__(256) void gemm_mfma(
    const float* __restrict__ A1, const float* __restrict__ A2,
    const short* __restrict__ W1h, const short* __restrict__ W1l,   // [dout][K] bf16
    const short* __restrict__ W2h, const short* __restrict__ W2l,
    const float* __restrict__ bias, float* __restrict__ C,
    int M, int K, int dout) {
    __shared__ short As_hi[128][LP];
    __shared__ short As_lo[128][LP];
    __shared__ short Bs_hi[128][LP];
    __shared__ short Bs_lo[128][LP];
    int tid = threadIdx.x;
    int lane = tid & 63, wid = tid >> 6;
    int wm = wid >> 1, wn = wid & 1;
    int mblk = blockIdx.x * 128, nblk = blockIdx.y * 128;
    f32x4 acc[4][4] = {};
    int KK = 2 * K;

    for (int k0 = 0; k0 < KK; k0 += 32) {
        const float* A; const short* Wh; const short* Wl; int kc;
        if (k0 < K) { A = A1; Wh = W1h; Wl = W1l; kc = k0; }
        else        { A = A2; Wh = W2h; Wl = W2l; kc = k0 - K; }

        // stage A tile: 128 rows x 32 k, convert f32 -> hi/lo
        #pragma unroll
        for (int r = 0; r < 4; ++r) {
            int flat = r * 256 + tid;
            int row = flat >> 3, k4 = (flat & 7) * 4;
            int gr = mblk + row;
            float4 v = make_float4(0.f, 0.f, 0.f, 0.f);
            if (gr < M) v = *(const float4*)&A[(size_t)gr * K + kc + k4];
            short4 h, l;
            f2bf(v.x, h.x, l.x); f2bf(v.y, h.y, l.y);
            f2bf(v.z, h.z, l.z); f2bf(v.w, h.w, l.w);
            *(short4*)&As_hi[row][k4] = h;
            *(short4*)&As_lo[row][k4] = l;
        }
        // stage B tile: 128 cols x 32 k from pre-transposed bf16 W^T
        #pragma unroll
        for (int r = 0; r < 2; ++r) {
            int flat = r * 256 + tid;
            int c = flat >> 2, kq = (flat & 3) * 8;
            size_t gb = (size_t)(nblk + c) * K + kc + kq;
            *(bf16x8*)&Bs_hi[c][kq] = *(const bf16x8*)&Wh[gb];
            *(bf16x8*)&Bs_lo[c][kq] = *(const bf16x8*)&Wl[gb];
        }
        __syncthreads();

        int koff = (lane >> 4) * 8;
        int arow = wm * 64 + (lane & 15);
        int bcol = wn * 64 + (lane & 15);
        bf16x8 ah[4], al[4], bh[4], bl[4];
        #pragma unroll
        for (int i = 0; i < 4; ++i) {
            ah[i] = *(const bf16x8*)&As_hi[arow + i * 16][koff];
            al[i] = *(const bf16x8*)&As_lo[arow + i * 16][koff];
            bh[i] = *(const bf16x8*)&Bs_hi[bcol + i * 16][koff];
            bl[i] = *(const bf16x8*)&Bs_lo[bcol + i * 16][koff];
        }
        #pragma unroll
        for (int i = 0; i < 4; ++i)
            #pragma unroll
            for (int j = 0; j < 4; ++j) {
                acc[i][j] = __builtin_amdgcn_mfma_f32_16x16x32_bf16(ah[i], bh[j], acc[i][j], 0, 0, 0);
                acc[i][j] = __builtin_amdgcn_mfma_f32_16x16x32_bf16(ah[i], bl[j], acc[i][j], 0, 0, 0);
                acc[i][j] = __builtin_amdgcn_mfma_f32_16x16x32_bf16(al[i], bh[j], acc[i][j], 0, 0, 0);
            }
        __syncthreads();
    }

    // epilogue: C/D layout col=lane&15, row=(lane>>4)*4+reg
    int crow = mblk + wm * 64 + ((lane >> 4) << 2);
    int ccol = nblk + wn * 64 + (lane & 15);
    #pragma unroll
    for (int i = 0; i < 4; ++i) {
        #pragma unroll
        for (int r = 0; r < 4; ++r) {
            int gm = crow + i * 16 + r;
            if (gm >= M) continue;
            #pragma unroll
            for (int j = 0; j < 4; ++j) {
                int gn = ccol + j * 16;
                float c = acc[i][j][r] + bias[gn];
                if (ACT) c = (c >= 0.f) ? c : 0.01f * c;
                C[(size_t)gm * dout + gn] = c;
            }
        }
    }
}

// ---------------- global mean pool: segmented reduction over sorted batch ----------------
// grid = (NG, SPLIT); each block sums its chunk of graph g's node range, one atomic per feature.
#define PSPLIT 16
__global__ __launch_bounds__(256) void pool_seg(const float* __restrict__ h,
                                                const int* __restrict__ batch,
                                                float* __restrict__ g, int* __restrict__ gcnt) {
    int gi = blockIdx.x, c = blockIdx.y;
    int t = threadIdx.x;  // 256 = feature index
    // lower_bound(batch, gi) and lower_bound(batch, gi+1), redundantly per thread
    int lo = 0, hi = NN;
    while (lo < hi) { int m = (lo + hi) >> 1; if (batch[m] < gi) lo = m + 1; else hi = m; }
    int start = lo;
    hi = NN;
    while (lo < hi) { int m = (lo + hi) >> 1; if (batch[m] < gi + 1) lo = m + 1; else hi = m; }
    int end = lo;
    int L = end - start;
    if (c == 0 && t == 0) gcnt[gi] = L;
    int cs = start + (int)(((long)L * c) / PSPLIT);
    int ce = start + (int)(((long)L * (c + 1)) / PSPLIT);
    float acc = 0.f;
    for (int n = cs; n < ce; ++n) acc += h[(size_t)n * 256 + t];
    if (acc != 0.f || ce > cs) atomicAdd(&g[gi * 256 + t], acc);
}

// ---------------- head: out[G,6] = (g/cnt) @ Wlin + blin ----------------
__global__ void final_kernel(const float* __restrict__ g, const int* __restrict__ gcnt,
                             const float* __restrict__ Wlin, const float* __restrict__ blin,
                             float* __restrict__ out) {
    int t = blockIdx.x * blockDim.x + threadIdx.x;
    if (t >= NG * 6) return;
    int gi = t / 6, o = t % 6;
    float inv = 1.f / fmaxf((float)gcnt[gi], 1.f);
    float s = 0.f;
    for (int k = 0; k < 256; ++k) s += g[gi * 256 + k] * Wlin[k * 6 + o];
    out[t] = s * inv + blin[o];
}

extern "C" void kernel_launch(void* const* d_in, const int* in_sizes, int n_in,
                              void* d_out, int out_size, void* d_ws, size_t ws_size,
                              hipStream_t stream) {
    const float* x = (const float*)d_in[0];
    const int* ei = (const int*)d_in[1];       // [2, E]: src then dst
    const int* batch = (const int*)d_in[2];
    const float *Wl[6], *bl[6], *Wr[6];
    for (int l = 0; l < 6; ++l) {
        Wl[l] = (const float*)d_in[3 + 3 * l];
        bl[l] = (const float*)d_in[4 + 3 * l];
        Wr[l] = (const float*)d_in[5 + 3 * l];
    }
    const float* Wlin = (const float*)d_in[21];
    const float* blin = (const float*)d_in[22];
    float* out = (float*)d_out;

    char* ws = (char*)d_ws;
    size_t off = 0;
    auto alloc = [&](size_t bytes) {
        void* p = ws + off;
        off += (bytes + 255) & ~(size_t)255;
        return p;
    };
    float* bufA = (float*)alloc((size_t)NN * 512 * 4);
    float* bufB = (float*)alloc((size_t)NN * 512 * 4);
    float* aggb = (float*)alloc((size_t)NN * 512 * 4);
    int* col    = (int*)alloc((size_t)NE * 4);
    // ---- zeroed region start ----
    float* g    = (float*)alloc((size_t)NG * 256 * 4);
    int* deg    = (int*)alloc((size_t)NN * 4);
    int* wcount = (int*)alloc((size_t)NN * 4);
    int* gcnt   = (int*)alloc((size_t)NG * 4);
    // ---- zeroed region end ----
    int* rowptr = (int*)alloc((size_t)(NN + 1) * 4);
    short* wtbuf = (short*)alloc((size_t)4 * 688128 * 2);  // hi/lo for Wl,Wr all layers
    (void)ws_size; (void)in_sizes; (void)n_in; (void)out_size;

    size_t zero_bytes = (size_t)((char*)gcnt - (char*)g) + NG * 4;
    hipMemsetAsync((void*)g, 0, zero_bytes, stream);

    const int* src = ei;
    const int* dst = ei + NE;
    hist_kernel<<<(NE + 255) / 256, 256, 0, stream>>>(dst, deg);
    scan_kernel<<<1, 1024, 0, stream>>>(deg, rowptr);
    fill_kernel<<<(NE + 255) / 256, 256, 0, stream>>>(src, dst, rowptr, wcount, col);

    const int dins[6]  = {128, 256, 256, 512, 512, 256};
    const int douts[6] = {256, 256, 512, 512, 256, 256};

    // pre-transpose + split all weights to bf16 hi/lo [dout][K]
    short *W1h[6], *W1l[6], *W2h[6], *W2l[6];
    {
        short* p = wtbuf;
        for (int l = 0; l < 6; ++l) {
            size_t sz = (size_t)dins[l] * douts[l];
            W1h[l] = p; p += sz;  W1l[l] = p; p += sz;
            W2h[l] = p; p += sz;  W2l[l] = p; p += sz;
            dim3 wg(dins[l] / 32, douts[l] / 32);
            wconv_kernel<<<wg, 256, 0, stream>>>(Wl[l], W1h[l], W1l[l], dins[l], douts[l]);
            wconv_kernel<<<wg, 256, 0, stream>>>(Wr[l], W2h[l], W2l[l], dins[l], douts[l]);
        }
    }

    const float* hin = x;
    float* ping = bufA;
    float* pong = bufB;
    for (int l = 0; l < 6; ++l) {
        int din = dins[l], dout = douts[l];
        int V = din / 4;
        if (V == 32)
            agg_kernel<32><<<(NN + 7) / 8, 256, 0, stream>>>((const float4*)hin, rowptr, col, (float4*)aggb);
        else if (V == 64)
            agg_kernel<64><<<(NN + 3) / 4, 256, 0, stream>>>((const float4*)hin, rowptr, col, (float4*)aggb);
        else
            agg_kernel<128><<<(NN + 1) / 2, 256, 0, stream>>>((const float4*)hin, rowptr, col, (float4*)aggb);

        dim3 grid((NN + 127) / 128, dout / 128);
        if (l < 5)
            gemm_mfma<1><<<grid, 256, 0, stream>>>(aggb, hin, W1h[l], W1l[l], W2h[l], W2l[l],
                                                   bl[l], ping, NN, din, dout);
        else
            gemm_mfma<0><<<grid, 256, 0, stream>>>(aggb, hin, W1h[l], W1l[l], W2h[l], W2l[l],
                                                   bl[l], ping, NN, din, dout);

        hin = ping;
        float* t = ping; ping = pong; pong = t;
    }

    dim3 pgrid(NG, PSPLIT);
    pool_seg<<<pgrid, 256, 0, stream>>>(hin, batch, g, gcnt);
    final_kernel<<<1, 384, 0, stream>>>(g, gcnt, Wlin, blin, out);
}

// Round 5
// 665.511 us; speedup vs baseline: 1.9057x; 1.1674x over previous
//
#include <hip/hip_runtime.h>

#define NN 20000
#define MP 20096   // NN padded to 157*128
#define NE 160000
#define NG 64

typedef __attribute__((ext_vector_type(8))) short bf16x8;
typedef __attribute__((ext_vector_type(4))) float f32x4;

// round-to-nearest bf16 split: x ~= hi + lo (both bf16)
__device__ __forceinline__ void f2bf(float x, short& hi, short& lo) {
    unsigned u = __float_as_uint(x);
    unsigned rh = (u + 0x7FFFu + ((u >> 16) & 1u)) & 0xFFFF0000u;
    hi = (short)(rh >> 16);
    float l = x - __uint_as_float(rh);
    unsigned ul = __float_as_uint(l);
    lo = (short)((ul + 0x7FFFu + ((ul >> 16) & 1u)) >> 16);
}

__device__ __forceinline__ float bf2f(short h) {
    return __uint_as_float(((unsigned)(unsigned short)h) << 16);
}

typedef const __attribute__((address_space(1))) unsigned int* as1_u32p;
typedef __attribute__((address_space(3))) unsigned int* as3_u32p;
__device__ __forceinline__ void gll16(const void* g, void* l) {
    __builtin_amdgcn_global_load_lds((as1_u32p)g, (as3_u32p)l, 16, 0, 0);
}

// ---------------- CSR build ----------------
__global__ void hist_kernel(const int* __restrict__ dst, int* __restrict__ deg) {
    int e = blockIdx.x * 256 + threadIdx.x;
    if (e < NE) atomicAdd(&deg[dst[e]], 1);
}

__global__ void scan_kernel(const int* __restrict__ deg, int* __restrict__ rowptr) {
    __shared__ int wsum[16];
    __shared__ int carry_s;
    int t = threadIdx.x;
    int lane = t & 63, w = t >> 6;
    if (t == 0) carry_s = 0;
    __syncthreads();
    for (int base = 0; base < NN; base += 1024) {
        int i = base + t;
        int v = (i < NN) ? deg[i] : 0;
        int s = v;
        #pragma unroll
        for (int off = 1; off < 64; off <<= 1) {
            int u = __shfl_up(s, off, 64);
            if (lane >= off) s += u;
        }
        if (lane == 63) wsum[w] = s;
        __syncthreads();
        if (w == 0 && lane < 16) {
            int ws = wsum[lane];
            #pragma unroll
            for (int off = 1; off < 16; off <<= 1) {
                int u = __shfl_up(ws, off, 64);
                if (lane >= off) ws += u;
            }
            wsum[lane] = ws;
        }
        __syncthreads();
        int wpre = (w > 0) ? wsum[w - 1] : 0;
        int carry = carry_s;
        if (i < NN) rowptr[i] = carry + wpre + s - v;
        int total = wsum[15];
        __syncthreads();
        if (t == 0) carry_s = carry + total;
        __syncthreads();
    }
    if (t == 0) rowptr[NN] = carry_s;
}

__global__ void fill_kernel(const int* __restrict__ src, const int* __restrict__ dst,
                            const int* __restrict__ rowptr, int* __restrict__ wcount,
                            int* __restrict__ col) {
    int e = blockIdx.x * 256 + threadIdx.x;
    if (e < NE) {
        int d = dst[e];
        int p = rowptr[d] + atomicAdd(&wcount[d], 1);
        col[p] = src[e];
    }
}

// ---------------- x -> bf16 hi/lo split ----------------
__global__ void xsplit_kernel(const float* __restrict__ x, short* __restrict__ xh,
                              short* __restrict__ xl) {
    int i = blockIdx.x * 256 + threadIdx.x;   // over NN*32 float4s
    if (i >= NN * 32) return;
    float4 v = *(const float4*)&x[(size_t)i * 4];
    short4 h, l;
    f2bf(v.x, h.x, l.x); f2bf(v.y, h.y, l.y);
    f2bf(v.z, h.z, l.z); f2bf(v.w, h.w, l.w);
    *(short4*)&xh[(size_t)i * 4] = h;
    *(short4*)&xl[(size_t)i * 4] = l;
}

// ---------------- mean aggregation from hi/lo, output hi/lo ----------------
template <int K>
__global__ __launch_bounds__(256) void agg_bf(const short* __restrict__ hh,
                                              const short* __restrict__ hl,
                                              const int* __restrict__ rowptr,
                                              const int* __restrict__ col,
                                              short* __restrict__ ah, short* __restrict__ al) {
    constexpr int TPN = K / 8;
    constexpr int NPB = 256 / TPN;
    int node = blockIdx.x * NPB + threadIdx.x / TPN;
    if (node >= NN) return;
    int t = threadIdx.x % TPN;
    int s = rowptr[node], e = rowptr[node + 1];
    float acc[8] = {};
    for (int j = s; j < e; ++j) {
        int c = col[j];
        bf16x8 vh = *(const bf16x8*)&hh[(size_t)c * K + t * 8];
        bf16x8 vl = *(const bf16x8*)&hl[(size_t)c * K + t * 8];
        #pragma unroll
        for (int m = 0; m < 8; ++m)
            acc[m] += bf2f(vh[m]) + bf2f(vl[m]);
    }
    float inv = 1.f / fmaxf((float)(e - s), 1.f);
    bf16x8 ph, pl;
    #pragma unroll
    for (int m = 0; m < 8; ++m) {
        short h, l;
        f2bf(acc[m] * inv, h, l);
        ph[m] = h; pl[m] = l;
    }
    *(bf16x8*)&ah[(size_t)node * K + t * 8] = ph;
    *(bf16x8*)&al[(size_t)node * K + t * 8] = pl;
}

// ---------------- W transpose + bf16 hi/lo split: [K][dout] -> [dout][K] ----------------
__global__ __launch_bounds__(256) void wconv_kernel(const float* __restrict__ W,
                                                    short* __restrict__ Wt_hi,
                                                    short* __restrict__ Wt_lo,
                                                    int K, int dout) {
    __shared__ float tile[32][33];
    int kb = blockIdx.x * 32, nb = blockIdx.y * 32;
    int t = threadIdx.x;
    int lr = t >> 5, lc = t & 31;
    #pragma unroll
    for (int r = 0; r < 4; ++r)
        tile[lr + r * 8][lc] = W[(size_t)(kb + lr + r * 8) * dout + nb + lc];
    __syncthreads();
    int nn = t >> 3, kq = (t & 7) * 4;
    short4 h, l;
    f2bf(tile[kq + 0][nn], h.x, l.x);
    f2bf(tile[kq + 1][nn], h.y, l.y);
    f2bf(tile[kq + 2][nn], h.z, l.z);
    f2bf(tile[kq + 3][nn], h.w, l.w);
    *(short4*)&Wt_hi[(size_t)(nb + nn) * K + kb + kq] = h;
    *(short4*)&Wt_lo[(size_t)(nb + nn) * K + kb + kq] = l;
}

// ---------------- fused dual GEMM, split-bf16 MFMA, gll staging + dbuf ----------------
// 128x128 block tile, 4 waves 2x2, wave 64x64 of 16x16x32 frags.
// LDS linear [128][32] shorts per tile; chunk swizzle c ^= (row>>1)&3 applied on
// SOURCE (pre-swizzled global addr) and on READ (rule #21).
template <int ACT, int LASTF32>
__global__ __launch_bounds__(256, 2) void gemm_mfma(
    const short* __restrict__ A1h, const short* __restrict__ A1l,
    const short* __restrict__ A2h, const short* __restrict__ A2l,
    const short* __restrict__ W1h, const short* __restrict__ W1l,
    const short* __restrict__ W2h, const short* __restrict__ W2l,
    const float* __restrict__ bias,
    short* __restrict__ Oh, short* __restrict__ Ol, float* __restrict__ Of,
    int M, int K, int dout) {
    __shared__ short lds[2][4][4096];   // [dbuf][Ah,Al,Bh,Bl][128*32]
    int tid = threadIdx.x;
    int lane = tid & 63, w = tid >> 6;
    int wm = w >> 1, wn = w & 1;
    int mblk = blockIdx.x * 128, nblk = blockIdx.y * 128;

    int rl = lane >> 2;                              // staging: row within 16-row DMA
    int gchunk = (lane & 3) ^ ((lane >> 3) & 3);     // pre-swizzled source chunk
    int s1 = K >> 5;
    int nsteps = s1 * 2;

    auto stage = [&](int b, int t) {
        const short *Ah, *Al, *Bh, *Bl;
        int kc;
        if (t < s1) { Ah = A1h; Al = A1l; Bh = W1h; Bl = W1l; kc = t << 5; }
        else        { Ah = A2h; Al = A2l; Bh = W2h; Bl = W2l; kc = (t - s1) << 5; }
        short* L = &lds[b][0][0];
        size_t ko = (size_t)kc + gchunk * 8;
        #pragma unroll
        for (int q = 0; q < 2; ++q) {
            int row = w * 32 + q * 16;
            int gr = row + rl;
            gll16(Ah + (size_t)(mblk + gr) * K + ko, L + 0 * 4096 + row * 32);
            gll16(Al + (size_t)(mblk + gr) * K + ko, L + 1 * 4096 + row * 32);
            gll16(Bh + (size_t)(nblk + gr) * K + ko, L + 2 * 4096 + row * 32);
            gll16(Bl + (size_t)(nblk + gr) * K + ko, L + 3 * 4096 + row * 32);
        }
    };

    f32x4 acc[4][4] = {};
    int chunk_sw = (((lane >> 4) ^ ((lane >> 1) & 3))) << 3;  // swizzled read offset (shorts)
    int ar = (wm << 6) + (lane & 15);
    int br = (wn << 6) + (lane & 15);

    stage(0, 0);
    __syncthreads();
    for (int t = 0; t < nsteps; ++t) {
        int b = t & 1;
        if (t + 1 < nsteps) stage(b ^ 1, t + 1);
        const short* L = &lds[b][0][0];
        bf16x8 ah[4], al[4], bh[4], bl[4];
        #pragma unroll
        for (int i = 0; i < 4; ++i) {
            ah[i] = *(const bf16x8*)(L + 0 * 4096 + (ar + i * 16) * 32 + chunk_sw);
            al[i] = *(const bf16x8*)(L + 1 * 4096 + (ar + i * 16) * 32 + chunk_sw);
            bh[i] = *(const bf16x8*)(L + 2 * 4096 + (br + i * 16) * 32 + chunk_sw);
            bl[i] = *(const bf16x8*)(L + 3 * 4096 + (br + i * 16) * 32 + chunk_sw);
        }
        #pragma unroll
        for (int i = 0; i < 4; ++i)
            #pragma unroll
            for (int j = 0; j < 4; ++j) {
                acc[i][j] = __builtin_amdgcn_mfma_f32_16x16x32_bf16(ah[i], bh[j], acc[i][j], 0, 0, 0);
                acc[i][j] = __builtin_amdgcn_mfma_f32_16x16x32_bf16(ah[i], bl[j], acc[i][j], 0, 0, 0);
                acc[i][j] = __builtin_amdgcn_mfma_f32_16x16x32_bf16(al[i], bh[j], acc[i][j], 0, 0, 0);
            }
        __syncthreads();
    }

    // epilogue: C/D layout col=lane&15, row=(lane>>4)*4+reg
    int crow = mblk + (wm << 6) + ((lane >> 4) << 2);
    int ccol = nblk + (wn << 6) + (lane & 15);
    #pragma unroll
    for (int i = 0; i < 4; ++i) {
        #pragma unroll
        for (int r = 0; r < 4; ++r) {
            int gm = crow + i * 16 + r;
            if (gm >= M) continue;
            #pragma unroll
            for (int j = 0; j < 4; ++j) {
                int gn = ccol + j * 16;
                float c = acc[i][j][r] + bias[gn];
                if (ACT) c = (c >= 0.f) ? c : 0.01f * c;
                if (LASTF32) {
                    Of[(size_t)gm * dout + gn] = c;
                } else {
                    short h, l;
                    f2bf(c, h, l);
                    Oh[(size_t)gm * dout + gn] = h;
                    Ol[(size_t)gm * dout + gn] = l;
                }
            }
        }
    }
}

// ---------------- global mean pool: segmented reduction over sorted batch ----------------
#define PSPLIT 16
__global__ __launch_bounds__(256) void pool_seg(const float* __restrict__ h,
                                                const int* __restrict__ batch,
                                                float* __restrict__ g, int* __restrict__ gcnt) {
    int gi = blockIdx.x, c = blockIdx.y;
    int t = threadIdx.x;
    int lo = 0, hi = NN;
    while (lo < hi) { int m = (lo + hi) >> 1; if (batch[m] < gi) lo = m + 1; else hi = m; }
    int start = lo;
    hi = NN;
    while (lo < hi) { int m = (lo + hi) >> 1; if (batch[m] < gi + 1) lo = m + 1; else hi = m; }
    int end = lo;
    int L = end - start;
    if (c == 0 && t == 0) gcnt[gi] = L;
    int cs = start + (int)(((long)L * c) / PSPLIT);
    int ce = start + (int)(((long)L * (c + 1)) / PSPLIT);
    float acc = 0.f;
    for (int n = cs; n < ce; ++n) acc += h[(size_t)n * 256 + t];
    if (ce > cs) atomicAdd(&g[gi * 256 + t], acc);
}

// ---------------- head ----------------
__global__ void final_kernel(const float* __restrict__ g, const int* __restrict__ gcnt,
                             const float* __restrict__ Wlin, const float* __restrict__ blin,
                             float* __restrict__ out) {
    int t = blockIdx.x * blockDim.x + threadIdx.x;
    if (t >= NG * 6) return;
    int gi = t / 6, o = t % 6;
    float inv = 1.f / fmaxf((float)gcnt[gi], 1.f);
    float s = 0.f;
    for (int k = 0; k < 256; ++k) s += g[gi * 256 + k] * Wlin[k * 6 + o];
    out[t] = s * inv + blin[o];
}

extern "C" void kernel_launch(void* const* d_in, const int* in_sizes, int n_in,
                              void* d_out, int out_size, void* d_ws, size_t ws_size,
                              hipStream_t stream) {
    const float* x = (const float*)d_in[0];
    const int* ei = (const int*)d_in[1];
    const int* batch = (const int*)d_in[2];
    const float *Wl[6], *bl[6], *Wr[6];
    for (int l = 0; l < 6; ++l) {
        Wl[l] = (const float*)d_in[3 + 3 * l];
        bl[l] = (const float*)d_in[4 + 3 * l];
        Wr[l] = (const float*)d_in[5 + 3 * l];
    }
    const float* Wlin = (const float*)d_in[21];
    const float* blin = (const float*)d_in[22];
    float* out = (float*)d_out;

    char* ws = (char*)d_ws;
    size_t off = 0;
    auto alloc = [&](size_t bytes) {
        void* p = ws + off;
        off += (bytes + 255) & ~(size_t)255;
        return p;
    };
    short* xh   = (short*)alloc((size_t)MP * 128 * 2);
    short* xl   = (short*)alloc((size_t)MP * 128 * 2);
    short* hhA  = (short*)alloc((size_t)MP * 512 * 2);
    short* hlA  = (short*)alloc((size_t)MP * 512 * 2);
    short* hhB  = (short*)alloc((size_t)MP * 512 * 2);
    short* hlB  = (short*)alloc((size_t)MP * 512 * 2);
    short* aggh = (short*)alloc((size_t)MP * 512 * 2);
    short* aggl = (short*)alloc((size_t)MP * 512 * 2);
    float* hf32 = (float*)alloc((size_t)MP * 256 * 4);
    int* col    = (int*)alloc((size_t)NE * 4);
    // ---- zeroed region start ----
    float* g    = (float*)alloc((size_t)NG * 256 * 4);
    int* deg    = (int*)alloc((size_t)NN * 4);
    int* wcount = (int*)alloc((size_t)NN * 4);
    int* gcnt   = (int*)alloc((size_t)NG * 4);
    // ---- zeroed region end ----
    int* rowptr = (int*)alloc((size_t)(NN + 1) * 4);
    short* wtbuf = (short*)alloc((size_t)4 * 688128 * 2);
    (void)ws_size; (void)in_sizes; (void)n_in; (void)out_size;

    size_t zero_bytes = (size_t)((char*)gcnt - (char*)g) + NG * 4;
    hipMemsetAsync((void*)g, 0, zero_bytes, stream);

    const int* src = ei;
    const int* dst = ei + NE;
    hist_kernel<<<(NE + 255) / 256, 256, 0, stream>>>(dst, deg);
    scan_kernel<<<1, 1024, 0, stream>>>(deg, rowptr);
    fill_kernel<<<(NE + 255) / 256, 256, 0, stream>>>(src, dst, rowptr, wcount, col);
    xsplit_kernel<<<(NN * 32 + 255) / 256, 256, 0, stream>>>(x, xh, xl);

    const int dins[6]  = {128, 256, 256, 512, 512, 256};
    const int douts[6] = {256, 256, 512, 512, 256, 256};

    short *W1h[6], *W1l[6], *W2h[6], *W2l[6];
    {
        short* p = wtbuf;
        for (int l = 0; l < 6; ++l) {
            size_t sz = (size_t)dins[l] * douts[l];
            W1h[l] = p; p += sz;  W1l[l] = p; p += sz;
            W2h[l] = p; p += sz;  W2l[l] = p; p += sz;
            dim3 wg(dins[l] / 32, douts[l] / 32);
            wconv_kernel<<<wg, 256, 0, stream>>>(Wl[l], W1h[l], W1l[l], dins[l], douts[l]);
            wconv_kernel<<<wg, 256, 0, stream>>>(Wr[l], W2h[l], W2l[l], dins[l], douts[l]);
        }
    }

    const short* curh = xh;
    const short* curl = xl;
    short* ph[2] = {hhA, hhB};
    short* pl[2] = {hlA, hlB};
    for (int l = 0; l < 6; ++l) {
        int K = dins[l], dout = douts[l];
        if (K == 128)
            agg_bf<128><<<(NN + 15) / 16, 256, 0, stream>>>(curh, curl, rowptr, col, aggh, aggl);
        else if (K == 256)
            agg_bf<256><<<(NN + 7) / 8, 256, 0, stream>>>(curh, curl, rowptr, col, aggh, aggl);
        else
            agg_bf<512><<<(NN + 3) / 4, 256, 0, stream>>>(curh, curl, rowptr, col, aggh, aggl);

        dim3 grid(MP / 128, dout / 128);
        if (l < 5) {
            gemm_mfma<1, 0><<<grid, 256, 0, stream>>>(aggh, aggl, curh, curl,
                                                      W1h[l], W1l[l], W2h[l], W2l[l], bl[l],
                                                      ph[l & 1], pl[l & 1], nullptr, NN, K, dout);
            curh = ph[l & 1];
            curl = pl[l & 1];
        } else {
            gemm_mfma<0, 1><<<grid, 256, 0, stream>>>(aggh, aggl, curh, curl,
                                                      W1h[l], W1l[l], W2h[l], W2l[l], bl[l],
                                                      nullptr, nullptr, hf32, NN, K, dout);
        }
    }

    dim3 pgrid(NG, PSPLIT);
    pool_seg<<<pgrid, 256, 0, stream>>>(hf32, batch, g, gcnt);
    final_kernel<<<1, 384, 0, stream>>>(g, gcnt, Wlin, blin, out);
}

// Round 6
// 612.084 us; speedup vs baseline: 2.0720x; 1.0873x over previous
//
#include <hip/hip_runtime.h>

#define NN 20000
#define MP 20096   // NN padded to 157*128
#define NE 160000
#define NG 64

typedef __attribute__((ext_vector_type(8))) short bf16x8;
typedef __attribute__((ext_vector_type(4))) float f32x4;

// round-to-nearest bf16 split: x ~= hi + lo (both bf16)
__device__ __forceinline__ void f2bf(float x, short& hi, short& lo) {
    unsigned u = __float_as_uint(x);
    unsigned rh = (u + 0x7FFFu + ((u >> 16) & 1u)) & 0xFFFF0000u;
    hi = (short)(rh >> 16);
    float l = x - __uint_as_float(rh);
    unsigned ul = __float_as_uint(l);
    lo = (short)((ul + 0x7FFFu + ((ul >> 16) & 1u)) >> 16);
}

__device__ __forceinline__ float bf2f(short h) {
    return __uint_as_float(((unsigned)(unsigned short)h) << 16);
}

typedef const __attribute__((address_space(1))) unsigned int* as1_u32p;
typedef __attribute__((address_space(3))) unsigned int* as3_u32p;
__device__ __forceinline__ void gll16(const void* g, void* l) {
    __builtin_amdgcn_global_load_lds((as1_u32p)g, (as3_u32p)l, 16, 0, 0);
}

// ---------------- CSR build ----------------
__global__ void hist_kernel(const int* __restrict__ dst, int* __restrict__ deg) {
    int e = blockIdx.x * 256 + threadIdx.x;
    if (e < NE) atomicAdd(&deg[dst[e]], 1);
}

__global__ void scan_kernel(const int* __restrict__ deg, int* __restrict__ rowptr) {
    __shared__ int wsum[16];
    __shared__ int carry_s;
    int t = threadIdx.x;
    int lane = t & 63, w = t >> 6;
    if (t == 0) carry_s = 0;
    __syncthreads();
    for (int base = 0; base < NN; base += 1024) {
        int i = base + t;
        int v = (i < NN) ? deg[i] : 0;
        int s = v;
        #pragma unroll
        for (int off = 1; off < 64; off <<= 1) {
            int u = __shfl_up(s, off, 64);
            if (lane >= off) s += u;
        }
        if (lane == 63) wsum[w] = s;
        __syncthreads();
        if (w == 0 && lane < 16) {
            int ws = wsum[lane];
            #pragma unroll
            for (int off = 1; off < 16; off <<= 1) {
                int u = __shfl_up(ws, off, 64);
                if (lane >= off) ws += u;
            }
            wsum[lane] = ws;
        }
        __syncthreads();
        int wpre = (w > 0) ? wsum[w - 1] : 0;
        int carry = carry_s;
        if (i < NN) rowptr[i] = carry + wpre + s - v;
        int total = wsum[15];
        __syncthreads();
        if (t == 0) carry_s = carry + total;
        __syncthreads();
    }
    if (t == 0) rowptr[NN] = carry_s;
}

__global__ void fill_kernel(const int* __restrict__ src, const int* __restrict__ dst,
                            const int* __restrict__ rowptr, int* __restrict__ wcount,
                            int* __restrict__ col) {
    int e = blockIdx.x * 256 + threadIdx.x;
    if (e < NE) {
        int d = dst[e];
        int p = rowptr[d] + atomicAdd(&wcount[d], 1);
        col[p] = src[e];
    }
}

// ---------------- x -> bf16 hi/lo split ----------------
__global__ void xsplit_kernel(const float* __restrict__ x, short* __restrict__ xh,
                              short* __restrict__ xl) {
    int i = blockIdx.x * 256 + threadIdx.x;   // over NN*32 float4s
    if (i >= NN * 32) return;
    float4 v = *(const float4*)&x[(size_t)i * 4];
    short4 h, l;
    f2bf(v.x, h.x, l.x); f2bf(v.y, h.y, l.y);
    f2bf(v.z, h.z, l.z); f2bf(v.w, h.w, l.w);
    *(short4*)&xh[(size_t)i * 4] = h;
    *(short4*)&xl[(size_t)i * 4] = l;
}

// ---------------- mean aggregation from hi/lo, output hi/lo ----------------
template <int K>
__global__ __launch_bounds__(256) void agg_bf(const short* __restrict__ hh,
                                              const short* __restrict__ hl,
                                              const int* __restrict__ rowptr,
                                              const int* __restrict__ col,
                                              short* __restrict__ ah, short* __restrict__ al) {
    constexpr int TPN = K / 8;
    constexpr int NPB = 256 / TPN;
    int node = blockIdx.x * NPB + threadIdx.x / TPN;
    if (node >= NN) return;
    int t = threadIdx.x % TPN;
    int s = rowptr[node], e = rowptr[node + 1];
    float acc[8] = {};
    for (int j = s; j < e; ++j) {
        int c = col[j];
        bf16x8 vh = *(const bf16x8*)&hh[(size_t)c * K + t * 8];
        bf16x8 vl = *(const bf16x8*)&hl[(size_t)c * K + t * 8];
        #pragma unroll
        for (int m = 0; m < 8; ++m)
            acc[m] += bf2f(vh[m]) + bf2f(vl[m]);
    }
    float inv = 1.f / fmaxf((float)(e - s), 1.f);
    bf16x8 ph, pl;
    #pragma unroll
    for (int m = 0; m < 8; ++m) {
        short h, l;
        f2bf(acc[m] * inv, h, l);
        ph[m] = h; pl[m] = l;
    }
    *(bf16x8*)&ah[(size_t)node * K + t * 8] = ph;
    *(bf16x8*)&al[(size_t)node * K + t * 8] = pl;
}

// ---------------- batched W transpose + hi/lo split (single launch) ----------------
struct WDesc { const float* W; short* Wh; short* Wl; int K; int dout; int tstart; };
struct WPack { WDesc d[12]; };

__global__ __launch_bounds__(256) void wconv_all(WPack p) {
    __shared__ float tile[32][33];
    int bid = blockIdx.x;
    int i = 0;
    #pragma unroll
    for (int k = 1; k < 12; ++k)
        if (bid >= p.d[k].tstart) i = k;
    const float* W = p.d[i].W;
    short* Wh = p.d[i].Wh;
    short* Wl = p.d[i].Wl;
    int K = p.d[i].K, dout = p.d[i].dout;
    int local = bid - p.d[i].tstart;
    int ntk = K >> 5;
    int kb = (local % ntk) * 32, nb = (local / ntk) * 32;
    int t = threadIdx.x;
    int lr = t >> 5, lc = t & 31;
    #pragma unroll
    for (int r = 0; r < 4; ++r)
        tile[lr + r * 8][lc] = W[(size_t)(kb + lr + r * 8) * dout + nb + lc];
    __syncthreads();
    int nn = t >> 3, kq = (t & 7) * 4;
    short4 h, l;
    f2bf(tile[kq + 0][nn], h.x, l.x);
    f2bf(tile[kq + 1][nn], h.y, l.y);
    f2bf(tile[kq + 2][nn], h.z, l.z);
    f2bf(tile[kq + 3][nn], h.w, l.w);
    *(short4*)&Wh[(size_t)(nb + nn) * K + kb + kq] = h;
    *(short4*)&Wl[(size_t)(nb + nn) * K + kb + kq] = l;
}

// ---------------- fused dual GEMM, split-bf16 MFMA ----------------
// 128x128 tile, 4 waves 2x2. T4 counted-vmcnt 2-deep pipeline; T1 XCD swizzle
// (panel-major: the dout/128 col-siblings of an M-panel are consecutive in one
// XCD chunk -> A-panel L2 reuse). LDS source-chunk swizzle per rule #21.
template <int ACT, int LASTF32>
__global__ __launch_bounds__(256, 2) void gemm_mfma(
    const short* __restrict__ A1h, const short* __restrict__ A1l,
    const short* __restrict__ A2h, const short* __restrict__ A2l,
    const short* __restrict__ W1h, const short* __restrict__ W1l,
    const short* __restrict__ W2h, const short* __restrict__ W2l,
    const float* __restrict__ bias,
    short* __restrict__ Oh, short* __restrict__ Ol, float* __restrict__ Of,
    int M, int K, int dout, int ncsh) {
    __shared__ short lds[2][4][4096];   // [dbuf][Ah,Al,Bh,Bl][128*32]
    int tid = threadIdx.x;
    int lane = tid & 63, w = tid >> 6;
    int wm = w >> 1, wn = w & 1;

    // bijective XCD swizzle (m204): XCD k gets a contiguous chunk of panel-major work ids
    int nwg = gridDim.x;
    int q = nwg >> 3, r = nwg & 7;
    int xcd = blockIdx.x & 7, idx = blockIdx.x >> 3;
    int swz = (xcd < r ? xcd * (q + 1) : r * (q + 1) + (xcd - r) * q) + idx;
    int mblk = (swz >> ncsh) << 7;
    int nblk = (swz & ((1 << ncsh) - 1)) << 7;

    int rl = lane >> 2;                              // staging: row within 16-row DMA
    int gchunk = (lane & 3) ^ ((lane >> 3) & 3);     // pre-swizzled source chunk
    int s1 = K >> 5;
    int nsteps = s1 * 2;

    auto stage = [&](int b, int t) {
        const short *Ah, *Al, *Bh, *Bl;
        int kc;
        if (t < s1) { Ah = A1h; Al = A1l; Bh = W1h; Bl = W1l; kc = t << 5; }
        else        { Ah = A2h; Al = A2l; Bh = W2h; Bl = W2l; kc = (t - s1) << 5; }
        short* L = &lds[b][0][0];
        size_t ko = (size_t)kc + gchunk * 8;
        #pragma unroll
        for (int qq = 0; qq < 2; ++qq) {
            int row = w * 32 + qq * 16;
            int gr = row + rl;
            gll16(Ah + (size_t)(mblk + gr) * K + ko, L + 0 * 4096 + row * 32);
            gll16(Al + (size_t)(mblk + gr) * K + ko, L + 1 * 4096 + row * 32);
            gll16(Bh + (size_t)(nblk + gr) * K + ko, L + 2 * 4096 + row * 32);
            gll16(Bl + (size_t)(nblk + gr) * K + ko, L + 3 * 4096 + row * 32);
        }
    };

    f32x4 acc[4][4] = {};
    int chunk_sw = (((lane >> 4) ^ ((lane >> 1) & 3))) << 3;  // swizzled read offset (shorts)
    int ar = (wm << 6) + (lane & 15);
    int br = (wn << 6) + (lane & 15);
    int ccol = nblk + (wn << 6) + (lane & 15);

    // pre-load bias and force materialization so loop vmcnt counting is exact
    float bv0 = bias[ccol], bv1 = bias[ccol + 16], bv2 = bias[ccol + 32], bv3 = bias[ccol + 48];
    asm volatile("" : "+v"(bv0), "+v"(bv1), "+v"(bv2), "+v"(bv3));

    stage(0, 0);
    stage(1, 1);
    for (int t = 0; t < nsteps; ++t) {
        int b = t & 1;
        if (t < nsteps - 1) asm volatile("s_waitcnt vmcnt(8)" ::: "memory");
        else                asm volatile("s_waitcnt vmcnt(0)" ::: "memory");
        __builtin_amdgcn_s_barrier();          // BARRIER-A: tile t landed on all waves
        __builtin_amdgcn_sched_barrier(0);
        const short* L = &lds[b][0][0];
        bf16x8 ah[4], al[4], bh[4], bl[4];
        #pragma unroll
        for (int i = 0; i < 4; ++i) {
            ah[i] = *(const bf16x8*)(L + 0 * 4096 + (ar + i * 16) * 32 + chunk_sw);
            al[i] = *(const bf16x8*)(L + 1 * 4096 + (ar + i * 16) * 32 + chunk_sw);
            bh[i] = *(const bf16x8*)(L + 2 * 4096 + (br + i * 16) * 32 + chunk_sw);
            bl[i] = *(const bf16x8*)(L + 3 * 4096 + (br + i * 16) * 32 + chunk_sw);
        }
        #pragma unroll
        for (int i = 0; i < 4; ++i)
            #pragma unroll
            for (int j = 0; j < 4; ++j) {
                acc[i][j] = __builtin_amdgcn_mfma_f32_16x16x32_bf16(ah[i], bh[j], acc[i][j], 0, 0, 0);
                acc[i][j] = __builtin_amdgcn_mfma_f32_16x16x32_bf16(ah[i], bl[j], acc[i][j], 0, 0, 0);
                acc[i][j] = __builtin_amdgcn_mfma_f32_16x16x32_bf16(al[i], bh[j], acc[i][j], 0, 0, 0);
            }
        __builtin_amdgcn_sched_barrier(0);
        __builtin_amdgcn_s_barrier();          // BARRIER-B: all waves done reading buffer b
        __builtin_amdgcn_sched_barrier(0);
        if (t + 2 < nsteps) stage(b, t + 2);   // overwrite b for step t+2 (WAR-safe)
    }

    // epilogue: C/D layout col=lane&15, row=(lane>>4)*4+reg
    int crow = mblk + (wm << 6) + ((lane >> 4) << 2);
    float bvv[4] = {bv0, bv1, bv2, bv3};
    #pragma unroll
    for (int i = 0; i < 4; ++i) {
        #pragma unroll
        for (int r = 0; r < 4; ++r) {
            int gm = crow + i * 16 + r;
            if (gm >= M) continue;
            #pragma unroll
            for (int j = 0; j < 4; ++j) {
                int gn = ccol + j * 16;
                float c = acc[i][j][r] + bvv[j];
                if (ACT) c = (c >= 0.f) ? c : 0.01f * c;
                if (LASTF32) {
                    Of[(size_t)gm * dout + gn] = c;
                } else {
                    short h, l;
                    f2bf(c, h, l);
                    Oh[(size_t)gm * dout + gn] = h;
                    Ol[(size_t)gm * dout + gn] = l;
                }
            }
        }
    }
}

// ---------------- global mean pool: segmented reduction over sorted batch ----------------
#define PSPLIT 16
__global__ __launch_bounds__(256) void pool_seg(const float* __restrict__ h,
                                                const int* __restrict__ batch,
                                                float* __restrict__ g, int* __restrict__ gcnt) {
    int gi = blockIdx.x, c = blockIdx.y;
    int t = threadIdx.x;
    int lo = 0, hi = NN;
    while (lo < hi) { int m = (lo + hi) >> 1; if (batch[m] < gi) lo = m + 1; else hi = m; }
    int start = lo;
    hi = NN;
    while (lo < hi) { int m = (lo + hi) >> 1; if (batch[m] < gi + 1) lo = m + 1; else hi = m; }
    int end = lo;
    int L = end - start;
    if (c == 0 && t == 0) gcnt[gi] = L;
    int cs = start + (int)(((long)L * c) / PSPLIT);
    int ce = start + (int)(((long)L * (c + 1)) / PSPLIT);
    float acc = 0.f;
    for (int n = cs; n < ce; ++n) acc += h[(size_t)n * 256 + t];
    if (ce > cs) atomicAdd(&g[gi * 256 + t], acc);
}

// ---------------- head ----------------
__global__ void final_kernel(const float* __restrict__ g, const int* __restrict__ gcnt,
                             const float* __restrict__ Wlin, const float* __restrict__ blin,
                             float* __restrict__ out) {
    int t = blockIdx.x * blockDim.x + threadIdx.x;
    if (t >= NG * 6) return;
    int gi = t / 6, o = t % 6;
    float inv = 1.f / fmaxf((float)gcnt[gi], 1.f);
    float s = 0.f;
    for (int k = 0; k < 256; ++k) s += g[gi * 256 + k] * Wlin[k * 6 + o];
    out[t] = s * inv + blin[o];
}

extern "C" void kernel_launch(void* const* d_in, const int* in_sizes, int n_in,
                              void* d_out, int out_size, void* d_ws, size_t ws_size,
                              hipStream_t stream) {
    const float* x = (const float*)d_in[0];
    const int* ei = (const int*)d_in[1];
    const int* batch = (const int*)d_in[2];
    const float *Wl[6], *bl[6], *Wr[6];
    for (int l = 0; l < 6; ++l) {
        Wl[l] = (const float*)d_in[3 + 3 * l];
        bl[l] = (const float*)d_in[4 + 3 * l];
        Wr[l] = (const float*)d_in[5 + 3 * l];
    }
    const float* Wlin = (const float*)d_in[21];
    const float* blin = (const float*)d_in[22];
    float* out = (float*)d_out;

    char* ws = (char*)d_ws;
    size_t off = 0;
    auto alloc = [&](size_t bytes) {
        void* p = ws + off;
        off += (bytes + 255) & ~(size_t)255;
        return p;
    };
    short* xh   = (short*)alloc((size_t)MP * 128 * 2);
    short* xl   = (short*)alloc((size_t)MP * 128 * 2);
    short* hhA  = (short*)alloc((size_t)MP * 512 * 2);
    short* hlA  = (short*)alloc((size_t)MP * 512 * 2);
    short* hhB  = (short*)alloc((size_t)MP * 512 * 2);
    short* hlB  = (short*)alloc((size_t)MP * 512 * 2);
    short* aggh = (short*)alloc((size_t)MP * 512 * 2);
    short* aggl = (short*)alloc((size_t)MP * 512 * 2);
    float* hf32 = (float*)alloc((size_t)MP * 256 * 4);
    int* col    = (int*)alloc((size_t)NE * 4);
    // ---- zeroed region start ----
    float* g    = (float*)alloc((size_t)NG * 256 * 4);
    int* deg    = (int*)alloc((size_t)NN * 4);
    int* wcount = (int*)alloc((size_t)NN * 4);
    int* gcnt   = (int*)alloc((size_t)NG * 4);
    // ---- zeroed region end ----
    int* rowptr = (int*)alloc((size_t)(NN + 1) * 4);
    short* wtbuf = (short*)alloc((size_t)4 * 688128 * 2);
    (void)ws_size; (void)in_sizes; (void)n_in; (void)out_size;

    size_t zero_bytes = (size_t)((char*)gcnt - (char*)g) + NG * 4;
    hipMemsetAsync((void*)g, 0, zero_bytes, stream);

    const int* src = ei;
    const int* dst = ei + NE;
    hist_kernel<<<(NE + 255) / 256, 256, 0, stream>>>(dst, deg);
    scan_kernel<<<1, 1024, 0, stream>>>(deg, rowptr);
    fill_kernel<<<(NE + 255) / 256, 256, 0, stream>>>(src, dst, rowptr, wcount, col);
    xsplit_kernel<<<(NN * 32 + 255) / 256, 256, 0, stream>>>(x, xh, xl);

    const int dins[6]  = {128, 256, 256, 512, 512, 256};
    const int douts[6] = {256, 256, 512, 512, 256, 256};

    // batched weight transpose+split: one launch for all 12 matrices
    short *W1h[6], *W1l[6], *W2h[6], *W2l[6];
    {
        WPack pack;
        short* p = wtbuf;
        int tcum = 0;
        for (int l = 0; l < 6; ++l) {
            size_t sz = (size_t)dins[l] * douts[l];
            int ntiles = (dins[l] / 32) * (douts[l] / 32);
            W1h[l] = p; p += sz;  W1l[l] = p; p += sz;
            W2h[l] = p; p += sz;  W2l[l] = p; p += sz;
            pack.d[2 * l]     = { Wl[l], W1h[l], W1l[l], dins[l], douts[l], tcum }; tcum += ntiles;
            pack.d[2 * l + 1] = { Wr[l], W2h[l], W2l[l], dins[l], douts[l], tcum }; tcum += ntiles;
        }
        wconv_all<<<tcum, 256, 0, stream>>>(pack);
    }

    const short* curh = xh;
    const short* curl = xl;
    short* ph[2] = {hhA, hhB};
    short* pl[2] = {hlA, hlB};
    for (int l = 0; l < 6; ++l) {
        int K = dins[l], dout = douts[l];
        if (K == 128)
            agg_bf<128><<<(NN + 15) / 16, 256, 0, stream>>>(curh, curl, rowptr, col, aggh, aggl);
        else if (K == 256)
            agg_bf<256><<<(NN + 7) / 8, 256, 0, stream>>>(curh, curl, rowptr, col, aggh, aggl);
        else
            agg_bf<512><<<(NN + 3) / 4, 256, 0, stream>>>(curh, curl, rowptr, col, aggh, aggl);

        int ncol = dout / 128;
        int ncsh = (ncol == 4) ? 2 : 1;
        int nwg = (MP / 128) * ncol;
        if (l < 5) {
            gemm_mfma<1, 0><<<nwg, 256, 0, stream>>>(aggh, aggl, curh, curl,
                                                     W1h[l], W1l[l], W2h[l], W2l[l], bl[l],
                                                     ph[l & 1], pl[l & 1], nullptr, NN, K, dout, ncsh);
            curh = ph[l & 1];
            curl = pl[l & 1];
        } else {
            gemm_mfma<0, 1><<<nwg, 256, 0, stream>>>(aggh, aggl, curh, curl,
                                                     W1h[l], W1l[l], W2h[l], W2l[l], bl[l],
                                                     nullptr, nullptr, hf32, NN, K, dout, ncsh);
        }
    }

    dim3 pgrid(NG, PSPLIT);
    pool_seg<<<pgrid, 256, 0, stream>>>(hf32, batch, g, gcnt);
    final_kernel<<<1, 384, 0, stream>>>(g, gcnt, Wlin, blin, out);
}

// Round 7
// 544.904 us; speedup vs baseline: 2.3275x; 1.1233x over previous
//
#include <hip/hip_runtime.h>

#define NN 20000
#define MP 20096   // NN padded to 157*128
#define NE 160000
#define NG 64

typedef __attribute__((ext_vector_type(8))) short bf16x8;
typedef __attribute__((ext_vector_type(4))) float f32x4;

// round-to-nearest bf16 split: x ~= hi + lo (both bf16)
__device__ __forceinline__ void f2bf(float x, short& hi, short& lo) {
    unsigned u = __float_as_uint(x);
    unsigned rh = (u + 0x7FFFu + ((u >> 16) & 1u)) & 0xFFFF0000u;
    hi = (short)(rh >> 16);
    float l = x - __uint_as_float(rh);
    unsigned ul = __float_as_uint(l);
    lo = (short)((ul + 0x7FFFu + ((ul >> 16) & 1u)) >> 16);
}

__device__ __forceinline__ short f2bf_hi(float x) {
    unsigned u = __float_as_uint(x);
    return (short)((u + 0x7FFFu + ((u >> 16) & 1u)) >> 16);
}

__device__ __forceinline__ float bf2f(short h) {
    return __uint_as_float(((unsigned)(unsigned short)h) << 16);
}

typedef const __attribute__((address_space(1))) unsigned int* as1_u32p;
typedef __attribute__((address_space(3))) unsigned int* as3_u32p;
__device__ __forceinline__ void gll16(const void* g, void* l) {
    __builtin_amdgcn_global_load_lds((as1_u32p)g, (as3_u32p)l, 16, 0, 0);
}

// ---------------- CSR build ----------------
__global__ void hist_kernel(const int* __restrict__ dst, int* __restrict__ deg) {
    int e = blockIdx.x * 256 + threadIdx.x;
    if (e < NE) atomicAdd(&deg[dst[e]], 1);
}

__global__ void scan_kernel(const int* __restrict__ deg, int* __restrict__ rowptr) {
    __shared__ int wsum[16];
    __shared__ int carry_s;
    int t = threadIdx.x;
    int lane = t & 63, w = t >> 6;
    if (t == 0) carry_s = 0;
    __syncthreads();
    for (int base = 0; base < NN; base += 1024) {
        int i = base + t;
        int v = (i < NN) ? deg[i] : 0;
        int s = v;
        #pragma unroll
        for (int off = 1; off < 64; off <<= 1) {
            int u = __shfl_up(s, off, 64);
            if (lane >= off) s += u;
        }
        if (lane == 63) wsum[w] = s;
        __syncthreads();
        if (w == 0 && lane < 16) {
            int ws = wsum[lane];
            #pragma unroll
            for (int off = 1; off < 16; off <<= 1) {
                int u = __shfl_up(ws, off, 64);
                if (lane >= off) ws += u;
            }
            wsum[lane] = ws;
        }
        __syncthreads();
        int wpre = (w > 0) ? wsum[w - 1] : 0;
        int carry = carry_s;
        if (i < NN) rowptr[i] = carry + wpre + s - v;
        int total = wsum[15];
        __syncthreads();
        if (t == 0) carry_s = carry + total;
        __syncthreads();
    }
    if (t == 0) rowptr[NN] = carry_s;
}

__global__ void fill_kernel(const int* __restrict__ src, const int* __restrict__ dst,
                            const int* __restrict__ rowptr, int* __restrict__ wcount,
                            int* __restrict__ col) {
    int e = blockIdx.x * 256 + threadIdx.x;
    if (e < NE) {
        int d = dst[e];
        int p = rowptr[d] + atomicAdd(&wcount[d], 1);
        col[p] = src[e];
    }
}

// ---------------- x -> bf16 hi/lo split ----------------
__global__ void xsplit_kernel(const float* __restrict__ x, short* __restrict__ xh,
                              short* __restrict__ xl) {
    int i = blockIdx.x * 256 + threadIdx.x;   // over NN*32 float4s
    if (i >= NN * 32) return;
    float4 v = *(const float4*)&x[(size_t)i * 4];
    short4 h, l;
    f2bf(v.x, h.x, l.x); f2bf(v.y, h.y, l.y);
    f2bf(v.z, h.z, l.z); f2bf(v.w, h.w, l.w);
    *(short4*)&xh[(size_t)i * 4] = h;
    *(short4*)&xl[(size_t)i * 4] = l;
}

// ---------------- batched W transpose + hi/lo split (single launch) ----------------
// Builds B^T = [Wl ; Wr] (2*dout rows of K) per layer, bf16 hi/lo.
struct WDesc { const float* W; short* Wh; short* Wl; int K; int dout; int tstart; };
struct WPack { WDesc d[12]; };

__global__ __launch_bounds__(256) void wconv_all(WPack p) {
    __shared__ float tile[32][33];
    int bid = blockIdx.x;
    int i = 0;
    #pragma unroll
    for (int k = 1; k < 12; ++k)
        if (bid >= p.d[k].tstart) i = k;
    const float* W = p.d[i].W;
    short* Wh = p.d[i].Wh;
    short* Wl = p.d[i].Wl;
    int K = p.d[i].K, dout = p.d[i].dout;
    int local = bid - p.d[i].tstart;
    int ntk = K >> 5;
    int kb = (local % ntk) * 32, nb = (local / ntk) * 32;
    int t = threadIdx.x;
    int lr = t >> 5, lc = t & 31;
    #pragma unroll
    for (int r = 0; r < 4; ++r)
        tile[lr + r * 8][lc] = W[(size_t)(kb + lr + r * 8) * dout + nb + lc];
    __syncthreads();
    int nn = t >> 3, kq = (t & 7) * 4;
    short4 h, l;
    f2bf(tile[kq + 0][nn], h.x, l.x);
    f2bf(tile[kq + 1][nn], h.y, l.y);
    f2bf(tile[kq + 2][nn], h.z, l.z);
    f2bf(tile[kq + 3][nn], h.w, l.w);
    *(short4*)&Wh[(size_t)(nb + nn) * K + kb + kq] = h;
    *(short4*)&Wl[(size_t)(nb + nn) * K + kb + kq] = l;
}

// ---------------- single-A dual-N GEMM: [P1|P2] = h @ [Wl|Wr] ----------------
// 128x128 tile, 4 waves 2x2. Counted-vmcnt 2-deep pipeline; bijective XCD swizzle,
// panel-major (all N-siblings of an M-panel contiguous in one XCD chunk).
// N = 2*dout: cols [0,dout) -> P1 (bf16), cols [dout,2*dout) -> P2 (f32, raw).
__global__ __launch_bounds__(256, 2) void gemm_mfma(
    const short* __restrict__ Ah, const short* __restrict__ Al,
    const short* __restrict__ Bh, const short* __restrict__ Bl,   // [2*dout][K] bf16
    short* __restrict__ P1, float* __restrict__ P2,
    int M, int K, int dout, int ncsh) {
    __shared__ short lds[2][4][4096];   // [dbuf][Ah,Al,Bh,Bl][128*32]
    int tid = threadIdx.x;
    int lane = tid & 63, w = tid >> 6;
    int wm = w >> 1, wn = w & 1;

    // bijective XCD swizzle (m204)
    int nwg = gridDim.x;
    int q = nwg >> 3, r = nwg & 7;
    int xcd = blockIdx.x & 7, idx = blockIdx.x >> 3;
    int swz = (xcd < r ? xcd * (q + 1) : r * (q + 1) + (xcd - r) * q) + idx;
    int mblk = (swz >> ncsh) << 7;
    int nblk = (swz & ((1 << ncsh) - 1)) << 7;

    int rl = lane >> 2;                              // staging: row within 16-row DMA
    int gchunk = (lane & 3) ^ ((lane >> 3) & 3);     // pre-swizzled source chunk
    int nsteps = K >> 5;

    auto stage = [&](int b, int t) {
        int kc = t << 5;
        short* L = &lds[b][0][0];
        size_t ko = (size_t)kc + gchunk * 8;
        #pragma unroll
        for (int qq = 0; qq < 2; ++qq) {
            int row = w * 32 + qq * 16;
            int gr = row + rl;
            gll16(Ah + (size_t)(mblk + gr) * K + ko, L + 0 * 4096 + row * 32);
            gll16(Al + (size_t)(mblk + gr) * K + ko, L + 1 * 4096 + row * 32);
            gll16(Bh + (size_t)(nblk + gr) * K + ko, L + 2 * 4096 + row * 32);
            gll16(Bl + (size_t)(nblk + gr) * K + ko, L + 3 * 4096 + row * 32);
        }
    };

    f32x4 acc[4][4] = {};
    int chunk_sw = (((lane >> 4) ^ ((lane >> 1) & 3))) << 3;  // swizzled read offset (shorts)
    int ar = (wm << 6) + (lane & 15);
    int br = (wn << 6) + (lane & 15);

    stage(0, 0);
    stage(1, 1);
    for (int t = 0; t < nsteps; ++t) {
        int b = t & 1;
        if (t < nsteps - 1) asm volatile("s_waitcnt vmcnt(8)" ::: "memory");
        else                asm volatile("s_waitcnt vmcnt(0)" ::: "memory");
        __builtin_amdgcn_s_barrier();          // tile t landed on all waves
        __builtin_amdgcn_sched_barrier(0);
        const short* L = &lds[b][0][0];
        bf16x8 ah[4], al[4], bh[4], bl[4];
        #pragma unroll
        for (int i = 0; i < 4; ++i) {
            ah[i] = *(const bf16x8*)(L + 0 * 4096 + (ar + i * 16) * 32 + chunk_sw);
            al[i] = *(const bf16x8*)(L + 1 * 4096 + (ar + i * 16) * 32 + chunk_sw);
            bh[i] = *(const bf16x8*)(L + 2 * 4096 + (br + i * 16) * 32 + chunk_sw);
            bl[i] = *(const bf16x8*)(L + 3 * 4096 + (br + i * 16) * 32 + chunk_sw);
        }
        #pragma unroll
        for (int i = 0; i < 4; ++i)
            #pragma unroll
            for (int j = 0; j < 4; ++j) {
                acc[i][j] = __builtin_amdgcn_mfma_f32_16x16x32_bf16(ah[i], bh[j], acc[i][j], 0, 0, 0);
                acc[i][j] = __builtin_amdgcn_mfma_f32_16x16x32_bf16(ah[i], bl[j], acc[i][j], 0, 0, 0);
                acc[i][j] = __builtin_amdgcn_mfma_f32_16x16x32_bf16(al[i], bh[j], acc[i][j], 0, 0, 0);
            }
        __builtin_amdgcn_sched_barrier(0);
        __builtin_amdgcn_s_barrier();          // all waves done reading buffer b
        __builtin_amdgcn_sched_barrier(0);
        if (t + 2 < nsteps) stage(b, t + 2);   // overwrite b for step t+2 (WAR-safe)
    }

    // epilogue: C/D layout col=lane&15, row=(lane>>4)*4+reg
    int crow = mblk + (wm << 6) + ((lane >> 4) << 2);
    int ccol = nblk + (wn << 6) + (lane & 15);
    bool is_p1 = (nblk < dout);   // 128-wide n-block lies entirely in one half
    #pragma unroll
    for (int i = 0; i < 4; ++i) {
        #pragma unroll
        for (int r = 0; r < 4; ++r) {
            int gm = crow + i * 16 + r;
            if (gm >= M) continue;
            #pragma unroll
            for (int j = 0; j < 4; ++j) {
                int gn = ccol + j * 16;
                float c = acc[i][j][r];
                if (is_p1) P1[(size_t)gm * dout + gn] = f2bf_hi(c);
                else       P2[(size_t)gm * dout + (gn - dout)] = c;
            }
        }
    }
}

// ---------------- fused epilogue: h_next = leaky(mean_nbr(P1) + P2 + bias) ----------------
template <int DOUT, int LAST>
__global__ __launch_bounds__(256) void agg_post(
    const short* __restrict__ P1, const float* __restrict__ P2,
    const float* __restrict__ bias,
    const int* __restrict__ rowptr, const int* __restrict__ col,
    short* __restrict__ oh, short* __restrict__ ol, float* __restrict__ of) {
    constexpr int TPN = DOUT / 8;
    constexpr int NPB = 256 / TPN;
    int node = blockIdx.x * NPB + threadIdx.x / TPN;
    if (node >= NN) return;
    int t = threadIdx.x % TPN;
    int s = rowptr[node], e = rowptr[node + 1];
    float acc[8] = {};
    for (int j = s; j < e; ++j) {
        int c = col[j];
        bf16x8 v = *(const bf16x8*)&P1[(size_t)c * DOUT + t * 8];
        #pragma unroll
        for (int m = 0; m < 8; ++m) acc[m] += bf2f(v[m]);
    }
    float inv = 1.f / fmaxf((float)(e - s), 1.f);
    const float* p2 = &P2[(size_t)node * DOUT + t * 8];
    float4 pa = *(const float4*)p2;
    float4 pb = *(const float4*)(p2 + 4);
    float4 ba = *(const float4*)&bias[t * 8];
    float4 bb = *(const float4*)&bias[t * 8 + 4];
    float p2v[8] = {pa.x, pa.y, pa.z, pa.w, pb.x, pb.y, pb.z, pb.w};
    float bv[8]  = {ba.x, ba.y, ba.z, ba.w, bb.x, bb.y, bb.z, bb.w};
    float o[8];
    #pragma unroll
    for (int m = 0; m < 8; ++m) {
        float c = acc[m] * inv + p2v[m] + bv[m];
        if (!LAST) c = (c >= 0.f) ? c : 0.01f * c;
        o[m] = c;
    }
    if (LAST) {
        float4 o0 = make_float4(o[0], o[1], o[2], o[3]);
        float4 o1 = make_float4(o[4], o[5], o[6], o[7]);
        *(float4*)&of[(size_t)node * DOUT + t * 8] = o0;
        *(float4*)&of[(size_t)node * DOUT + t * 8 + 4] = o1;
    } else {
        bf16x8 vh, vl;
        #pragma unroll
        for (int m = 0; m < 8; ++m) {
            short h, l;
            f2bf(o[m], h, l);
            vh[m] = h; vl[m] = l;
        }
        *(bf16x8*)&oh[(size_t)node * DOUT + t * 8] = vh;
        *(bf16x8*)&ol[(size_t)node * DOUT + t * 8] = vl;
    }
}

// ---------------- global mean pool: segmented reduction over sorted batch ----------------
#define PSPLIT 16
__global__ __launch_bounds__(256) void pool_seg(const float* __restrict__ h,
                                                const int* __restrict__ batch,
                                                float* __restrict__ g, int* __restrict__ gcnt) {
    int gi = blockIdx.x, c = blockIdx.y;
    int t = threadIdx.x;
    int lo = 0, hi = NN;
    while (lo < hi) { int m = (lo + hi) >> 1; if (batch[m] < gi) lo = m + 1; else hi = m; }
    int start = lo;
    hi = NN;
    while (lo < hi) { int m = (lo + hi) >> 1; if (batch[m] < gi + 1) lo = m + 1; else hi = m; }
    int end = lo;
    int L = end - start;
    if (c == 0 && t == 0) gcnt[gi] = L;
    int cs = start + (int)(((long)L * c) / PSPLIT);
    int ce = start + (int)(((long)L * (c + 1)) / PSPLIT);
    float acc = 0.f;
    for (int n = cs; n < ce; ++n) acc += h[(size_t)n * 256 + t];
    if (ce > cs) atomicAdd(&g[gi * 256 + t], acc);
}

// ---------------- head ----------------
__global__ void final_kernel(const float* __restrict__ g, const int* __restrict__ gcnt,
                             const float* __restrict__ Wlin, const float* __restrict__ blin,
                             float* __restrict__ out) {
    int t = blockIdx.x * blockDim.x + threadIdx.x;
    if (t >= NG * 6) return;
    int gi = t / 6, o = t % 6;
    float inv = 1.f / fmaxf((float)gcnt[gi], 1.f);
    float s = 0.f;
    for (int k = 0; k < 256; ++k) s += g[gi * 256 + k] * Wlin[k * 6 + o];
    out[t] = s * inv + blin[o];
}

extern "C" void kernel_launch(void* const* d_in, const int* in_sizes, int n_in,
                              void* d_out, int out_size, void* d_ws, size_t ws_size,
                              hipStream_t stream) {
    const float* x = (const float*)d_in[0];
    const int* ei = (const int*)d_in[1];
    const int* batch = (const int*)d_in[2];
    const float *Wl[6], *bl[6], *Wr[6];
    for (int l = 0; l < 6; ++l) {
        Wl[l] = (const float*)d_in[3 + 3 * l];
        bl[l] = (const float*)d_in[4 + 3 * l];
        Wr[l] = (const float*)d_in[5 + 3 * l];
    }
    const float* Wlin = (const float*)d_in[21];
    const float* blin = (const float*)d_in[22];
    float* out = (float*)d_out;

    char* ws = (char*)d_ws;
    size_t off = 0;
    auto alloc = [&](size_t bytes) {
        void* p = ws + off;
        off += (bytes + 255) & ~(size_t)255;
        return p;
    };
    short* xh   = (short*)alloc((size_t)MP * 128 * 2);
    short* xl   = (short*)alloc((size_t)MP * 128 * 2);
    short* hhA  = (short*)alloc((size_t)MP * 512 * 2);
    short* hlA  = (short*)alloc((size_t)MP * 512 * 2);
    short* hhB  = (short*)alloc((size_t)MP * 512 * 2);
    short* hlB  = (short*)alloc((size_t)MP * 512 * 2);
    short* P1   = (short*)alloc((size_t)MP * 512 * 2);
    float* P2   = (float*)alloc((size_t)MP * 512 * 4);
    int* col    = (int*)alloc((size_t)NE * 4);
    // ---- zeroed region start ----
    float* g    = (float*)alloc((size_t)NG * 256 * 4);
    int* deg    = (int*)alloc((size_t)NN * 4);
    int* wcount = (int*)alloc((size_t)NN * 4);
    int* gcnt   = (int*)alloc((size_t)NG * 4);
    // ---- zeroed region end ----
    int* rowptr = (int*)alloc((size_t)(NN + 1) * 4);
    short* wtbuf = (short*)alloc((size_t)4 * 688128 * 2);
    float* hf32 = (float*)hhA;   // layer-6 output aliases dead h buffer (MP*256 f32 fits)
    (void)ws_size; (void)in_sizes; (void)n_in; (void)out_size;

    size_t zero_bytes = (size_t)((char*)gcnt - (char*)g) + NG * 4;
    hipMemsetAsync((void*)g, 0, zero_bytes, stream);

    const int* src = ei;
    const int* dst = ei + NE;
    hist_kernel<<<(NE + 255) / 256, 256, 0, stream>>>(dst, deg);
    scan_kernel<<<1, 1024, 0, stream>>>(deg, rowptr);
    fill_kernel<<<(NE + 255) / 256, 256, 0, stream>>>(src, dst, rowptr, wcount, col);
    xsplit_kernel<<<(NN * 32 + 255) / 256, 256, 0, stream>>>(x, xh, xl);

    const int dins[6]  = {128, 256, 256, 512, 512, 256};
    const int douts[6] = {256, 256, 512, 512, 256, 256};

    // batched weight transpose+split -> per-layer B^T = [Wl ; Wr], bf16 hi/lo
    short *Bth[6], *Btl[6];
    {
        WPack pack;
        short* p = wtbuf;
        int tcum = 0;
        for (int l = 0; l < 6; ++l) {
            size_t half = (size_t)dins[l] * douts[l];
            int ntiles = (dins[l] / 32) * (douts[l] / 32);
            Bth[l] = p; p += 2 * half;
            Btl[l] = p; p += 2 * half;
            pack.d[2 * l]     = { Wl[l], Bth[l],        Btl[l],        dins[l], douts[l], tcum }; tcum += ntiles;
            pack.d[2 * l + 1] = { Wr[l], Bth[l] + half, Btl[l] + half, dins[l], douts[l], tcum }; tcum += ntiles;
        }
        wconv_all<<<tcum, 256, 0, stream>>>(pack);
    }

    const short* curh = xh;
    const short* curl = xl;
    short* ph[2] = {hhA, hhB};
    short* pl[2] = {hlA, hlB};
    for (int l = 0; l < 6; ++l) {
        int K = dins[l], dout = douts[l];
        int ncol = (2 * dout) >> 7;            // 4 or 8
        int ncsh = (ncol == 4) ? 2 : 3;
        int nwg = (MP / 128) * ncol;
        gemm_mfma<<<nwg, 256, 0, stream>>>(curh, curl, Bth[l], Btl[l],
                                           P1, P2, NN, K, dout, ncsh);
        if (l < 5) {
            if (dout == 256)
                agg_post<256, 0><<<(NN + 7) / 8, 256, 0, stream>>>(P1, P2, bl[l], rowptr, col,
                                                                   ph[l & 1], pl[l & 1], nullptr);
            else
                agg_post<512, 0><<<(NN + 3) / 4, 256, 0, stream>>>(P1, P2, bl[l], rowptr, col,
                                                                   ph[l & 1], pl[l & 1], nullptr);
            curh = ph[l & 1];
            curl = pl[l & 1];
        } else {
            agg_post<256, 1><<<(NN + 7) / 8, 256, 0, stream>>>(P1, P2, bl[l], rowptr, col,
                                                               nullptr, nullptr, hf32);
        }
    }

    dim3 pgrid(NG, PSPLIT);
    pool_seg<<<pgrid, 256, 0, stream>>>(hf32, batch, g, gcnt);
    final_kernel<<<1, 384, 0, stream>>>(g, gcnt, Wlin, blin, out);
}

// Round 8
// 512.957 us; speedup vs baseline: 2.4724x; 1.0623x over previous
//
#include <hip/hip_runtime.h>

#define NN 20000
#define MP 20096   // NN padded to 157*128
#define NE 160000
#define NG 64

typedef __attribute__((ext_vector_type(8))) short bf16x8;
typedef __attribute__((ext_vector_type(4))) float f32x4;

// round-to-nearest bf16 split: x ~= hi + lo (both bf16)
__device__ __forceinline__ void f2bf(float x, short& hi, short& lo) {
    unsigned u = __float_as_uint(x);
    unsigned rh = (u + 0x7FFFu + ((u >> 16) & 1u)) & 0xFFFF0000u;
    hi = (short)(rh >> 16);
    float l = x - __uint_as_float(rh);
    unsigned ul = __float_as_uint(l);
    lo = (short)((ul + 0x7FFFu + ((ul >> 16) & 1u)) >> 16);
}

__device__ __forceinline__ short f2bf_hi(float x) {
    unsigned u = __float_as_uint(x);
    return (short)((u + 0x7FFFu + ((u >> 16) & 1u)) >> 16);
}

__device__ __forceinline__ float bf2f(short h) {
    return __uint_as_float(((unsigned)(unsigned short)h) << 16);
}

typedef const __attribute__((address_space(1))) unsigned int* as1_u32p;
typedef __attribute__((address_space(3))) unsigned int* as3_u32p;
__device__ __forceinline__ void gll16(const void* g, void* l) {
    __builtin_amdgcn_global_load_lds((as1_u32p)g, (as3_u32p)l, 16, 0, 0);
}

// ---------------- CSR build ----------------
__global__ void hist_kernel(const int* __restrict__ dst, int* __restrict__ deg) {
    int e = blockIdx.x * 256 + threadIdx.x;
    if (e < NE) atomicAdd(&deg[dst[e]], 1);
}

__global__ void scan_kernel(const int* __restrict__ deg, int* __restrict__ rowptr) {
    __shared__ int wsum[16];
    __shared__ int carry_s;
    int t = threadIdx.x;
    int lane = t & 63, w = t >> 6;
    if (t == 0) carry_s = 0;
    __syncthreads();
    for (int base = 0; base < NN; base += 1024) {
        int i = base + t;
        int v = (i < NN) ? deg[i] : 0;
        int s = v;
        #pragma unroll
        for (int off = 1; off < 64; off <<= 1) {
            int u = __shfl_up(s, off, 64);
            if (lane >= off) s += u;
        }
        if (lane == 63) wsum[w] = s;
        __syncthreads();
        if (w == 0 && lane < 16) {
            int ws = wsum[lane];
            #pragma unroll
            for (int off = 1; off < 16; off <<= 1) {
                int u = __shfl_up(ws, off, 64);
                if (lane >= off) ws += u;
            }
            wsum[lane] = ws;
        }
        __syncthreads();
        int wpre = (w > 0) ? wsum[w - 1] : 0;
        int carry = carry_s;
        if (i < NN) rowptr[i] = carry + wpre + s - v;
        int total = wsum[15];
        __syncthreads();
        if (t == 0) carry_s = carry + total;
        __syncthreads();
    }
    if (t == 0) rowptr[NN] = carry_s;
}

__global__ void fill_kernel(const int* __restrict__ src, const int* __restrict__ dst,
                            const int* __restrict__ rowptr, int* __restrict__ wcount,
                            int* __restrict__ col) {
    int e = blockIdx.x * 256 + threadIdx.x;
    if (e < NE) {
        int d = dst[e];
        int p = rowptr[d] + atomicAdd(&wcount[d], 1);
        col[p] = src[e];
    }
}

// ---------------- x -> bf16 (hi only) ----------------
__global__ void xbf_kernel(const float* __restrict__ x, short* __restrict__ xh) {
    int i = blockIdx.x * 256 + threadIdx.x;   // over NN*16 groups of 8 floats
    if (i >= NN * 16) return;
    float4 a = *(const float4*)&x[(size_t)i * 8];
    float4 b = *(const float4*)&x[(size_t)i * 8 + 4];
    bf16x8 v;
    v[0] = f2bf_hi(a.x); v[1] = f2bf_hi(a.y); v[2] = f2bf_hi(a.z); v[3] = f2bf_hi(a.w);
    v[4] = f2bf_hi(b.x); v[5] = f2bf_hi(b.y); v[6] = f2bf_hi(b.z); v[7] = f2bf_hi(b.w);
    *(bf16x8*)&xh[(size_t)i * 8] = v;
}

// ---------------- batched W transpose + hi/lo split (layers 1-5) ----------------
struct WDesc { const float* W; short* Wh; short* Wl; int K; int dout; int tstart; };
struct WPack { WDesc d[10]; };

__global__ __launch_bounds__(256) void wconv_all(WPack p) {
    __shared__ float tile[32][33];
    int bid = blockIdx.x;
    int i = 0;
    #pragma unroll
    for (int k = 1; k < 10; ++k)
        if (bid >= p.d[k].tstart) i = k;
    const float* W = p.d[i].W;
    short* Wh = p.d[i].Wh;
    short* Wl = p.d[i].Wl;
    int K = p.d[i].K, dout = p.d[i].dout;
    int local = bid - p.d[i].tstart;
    int ntk = K >> 5;
    int kb = (local % ntk) * 32, nb = (local / ntk) * 32;
    int t = threadIdx.x;
    int lr = t >> 5, lc = t & 31;
    #pragma unroll
    for (int r = 0; r < 4; ++r)
        tile[lr + r * 8][lc] = W[(size_t)(kb + lr + r * 8) * dout + nb + lc];
    __syncthreads();
    int nn = t >> 3, kq = (t & 7) * 4;
    short4 h, l;
    f2bf(tile[kq + 0][nn], h.x, l.x);
    f2bf(tile[kq + 1][nn], h.y, l.y);
    f2bf(tile[kq + 2][nn], h.z, l.z);
    f2bf(tile[kq + 3][nn], h.w, l.w);
    *(short4*)&Wh[(size_t)(nb + nn) * K + kb + kq] = h;
    *(short4*)&Wl[(size_t)(nb + nn) * K + kb + kq] = l;
}

// ---------------- single-A dual-N GEMM: [P1|P2] = h_bf16 @ (Bh+Bl) ----------------
// A bf16 single stream; W split hi/lo -> 2 MFMAs per fragment pair.
// 128x128 tile, 4 waves 2x2, counted-vmcnt 2-deep pipeline, bijective XCD swizzle.
__global__ __launch_bounds__(256, 3) void gemm_mfma(
    const short* __restrict__ A,
    const short* __restrict__ Bh, const short* __restrict__ Bl,   // [2*dout][K] bf16
    short* __restrict__ P1, float* __restrict__ P2,
    int M, int K, int dout, int ncsh) {
    __shared__ short lds[2][3][4096];   // [dbuf][A,Bh,Bl][128*32]
    int tid = threadIdx.x;
    int lane = tid & 63, w = tid >> 6;
    int wm = w >> 1, wn = w & 1;

    // bijective XCD swizzle (m204), panel-major work ids
    int nwg = gridDim.x;
    int q = nwg >> 3, r = nwg & 7;
    int xcd = blockIdx.x & 7, idx = blockIdx.x >> 3;
    int swz = (xcd < r ? xcd * (q + 1) : r * (q + 1) + (xcd - r) * q) + idx;
    int mblk = (swz >> ncsh) << 7;
    int nblk = (swz & ((1 << ncsh) - 1)) << 7;

    int rl = lane >> 2;                              // staging: row within 16-row DMA
    int gchunk = (lane & 3) ^ ((lane >> 3) & 3);     // pre-swizzled source chunk
    int nsteps = K >> 5;

    auto stage = [&](int b, int t) {
        int kc = t << 5;
        short* L = &lds[b][0][0];
        size_t ko = (size_t)kc + gchunk * 8;
        #pragma unroll
        for (int qq = 0; qq < 2; ++qq) {
            int row = w * 32 + qq * 16;
            int gr = row + rl;
            gll16(A  + (size_t)(mblk + gr) * K + ko, L + 0 * 4096 + row * 32);
            gll16(Bh + (size_t)(nblk + gr) * K + ko, L + 1 * 4096 + row * 32);
            gll16(Bl + (size_t)(nblk + gr) * K + ko, L + 2 * 4096 + row * 32);
        }
    };

    f32x4 acc[4][4] = {};
    int chunk_sw = (((lane >> 4) ^ ((lane >> 1) & 3))) << 3;  // swizzled read offset (shorts)
    int ar = (wm << 6) + (lane & 15);
    int br = (wn << 6) + (lane & 15);

    stage(0, 0);
    stage(1, 1);
    for (int t = 0; t < nsteps; ++t) {
        int b = t & 1;
        if (t < nsteps - 1) asm volatile("s_waitcnt vmcnt(6)" ::: "memory");
        else                asm volatile("s_waitcnt vmcnt(0)" ::: "memory");
        __builtin_amdgcn_s_barrier();          // tile t landed on all waves
        __builtin_amdgcn_sched_barrier(0);
        const short* L = &lds[b][0][0];
        bf16x8 av[4], bh[4], bl[4];
        #pragma unroll
        for (int i = 0; i < 4; ++i) {
            av[i] = *(const bf16x8*)(L + 0 * 4096 + (ar + i * 16) * 32 + chunk_sw);
            bh[i] = *(const bf16x8*)(L + 1 * 4096 + (br + i * 16) * 32 + chunk_sw);
            bl[i] = *(const bf16x8*)(L + 2 * 4096 + (br + i * 16) * 32 + chunk_sw);
        }
        #pragma unroll
        for (int i = 0; i < 4; ++i)
            #pragma unroll
            for (int j = 0; j < 4; ++j) {
                acc[i][j] = __builtin_amdgcn_mfma_f32_16x16x32_bf16(av[i], bh[j], acc[i][j], 0, 0, 0);
                acc[i][j] = __builtin_amdgcn_mfma_f32_16x16x32_bf16(av[i], bl[j], acc[i][j], 0, 0, 0);
            }
        __builtin_amdgcn_sched_barrier(0);
        __builtin_amdgcn_s_barrier();          // all waves done reading buffer b
        __builtin_amdgcn_sched_barrier(0);
        if (t + 2 < nsteps) stage(b, t + 2);   // overwrite b for step t+2 (WAR-safe)
    }

    // epilogue: C/D layout col=lane&15, row=(lane>>4)*4+reg
    int crow = mblk + (wm << 6) + ((lane >> 4) << 2);
    int ccol = nblk + (wn << 6) + (lane & 15);
    bool is_p1 = (nblk < dout);   // 128-wide n-block lies entirely in one half
    #pragma unroll
    for (int i = 0; i < 4; ++i) {
        #pragma unroll
        for (int r = 0; r < 4; ++r) {
            int gm = crow + i * 16 + r;
            if (gm >= M) continue;
            #pragma unroll
            for (int j = 0; j < 4; ++j) {
                int gn = ccol + j * 16;
                float c = acc[i][j][r];
                if (is_p1) P1[(size_t)gm * dout + gn] = f2bf_hi(c);
                else       P2[(size_t)gm * dout + (gn - dout)] = c;
            }
        }
    }
}

// ---------------- fused epilogue: h_next = bf16(leaky(mean_nbr(P1) + P2 + bias)) ----------------
template <int DOUT>
__global__ __launch_bounds__(256) void agg_post(
    const short* __restrict__ P1, const float* __restrict__ P2,
    const float* __restrict__ bias,
    const int* __restrict__ rowptr, const int* __restrict__ col,
    short* __restrict__ oh) {
    constexpr int TPN = DOUT / 8;
    constexpr int NPB = 256 / TPN;
    int node = blockIdx.x * NPB + threadIdx.x / TPN;
    if (node >= NN) return;
    int t = threadIdx.x % TPN;
    int s = rowptr[node], e = rowptr[node + 1];
    float acc[8] = {};
    for (int j = s; j < e; ++j) {
        int c = col[j];
        bf16x8 v = *(const bf16x8*)&P1[(size_t)c * DOUT + t * 8];
        #pragma unroll
        for (int m = 0; m < 8; ++m) acc[m] += bf2f(v[m]);
    }
    float inv = 1.f / fmaxf((float)(e - s), 1.f);
    const float* p2 = &P2[(size_t)node * DOUT + t * 8];
    float4 pa = *(const float4*)p2;
    float4 pb = *(const float4*)(p2 + 4);
    float4 ba = *(const float4*)&bias[t * 8];
    float4 bb = *(const float4*)&bias[t * 8 + 4];
    float p2v[8] = {pa.x, pa.y, pa.z, pa.w, pb.x, pb.y, pb.z, pb.w};
    float bv[8]  = {ba.x, ba.y, ba.z, ba.w, bb.x, bb.y, bb.z, bb.w};
    bf16x8 vh;
    #pragma unroll
    for (int m = 0; m < 8; ++m) {
        float c = acc[m] * inv + p2v[m] + bv[m];
        c = (c >= 0.f) ? c : 0.01f * c;
        vh[m] = f2bf_hi(c);
    }
    *(bf16x8*)&oh[(size_t)node * DOUT + t * 8] = vh;
}

// ---------------- pooled adjacency gather: ap[g] = sum_{i in G_g} (1/deg_i) sum_nbr h5 ----------------
#define PSPLIT 16
__global__ __launch_bounds__(256) void sgather(const short* __restrict__ h5,
                                               const int* __restrict__ batch,
                                               const int* __restrict__ rowptr,
                                               const int* __restrict__ col,
                                               float* __restrict__ ap) {
    int gi = blockIdx.x, c = blockIdx.y;
    int t = threadIdx.x;   // feature
    int lo = 0, hi = NN;
    while (lo < hi) { int m = (lo + hi) >> 1; if (batch[m] < gi) lo = m + 1; else hi = m; }
    int start = lo;
    hi = NN;
    while (lo < hi) { int m = (lo + hi) >> 1; if (batch[m] < gi + 1) lo = m + 1; else hi = m; }
    int end = lo;
    int L = end - start;
    int cs = start + (int)(((long)L * c) / PSPLIT);
    int ce = start + (int)(((long)L * (c + 1)) / PSPLIT);
    float acc = 0.f;
    for (int n = cs; n < ce; ++n) {
        int s = rowptr[n], e = rowptr[n + 1];
        float w = 1.f / fmaxf((float)(e - s), 1.f);
        float a = 0.f;
        for (int j = s; j < e; ++j)
            a += bf2f(h5[(size_t)col[j] * 256 + t]);
        acc += w * a;
    }
    if (ce > cs) atomicAdd(&ap[gi * 256 + t], acc);
}

// ---------------- per-graph mean of h5 (bf16) ----------------
__global__ __launch_bounds__(256) void pool_h(const short* __restrict__ h5,
                                              const int* __restrict__ batch,
                                              float* __restrict__ hp, int* __restrict__ gcnt) {
    int gi = blockIdx.x, c = blockIdx.y;
    int t = threadIdx.x;
    int lo = 0, hi = NN;
    while (lo < hi) { int m = (lo + hi) >> 1; if (batch[m] < gi) lo = m + 1; else hi = m; }
    int start = lo;
    hi = NN;
    while (lo < hi) { int m = (lo + hi) >> 1; if (batch[m] < gi + 1) lo = m + 1; else hi = m; }
    int end = lo;
    int L = end - start;
    if (c == 0 && t == 0) gcnt[gi] = L;
    int cs = start + (int)(((long)L * c) / PSPLIT);
    int ce = start + (int)(((long)L * (c + 1)) / PSPLIT);
    float acc = 0.f;
    for (int n = cs; n < ce; ++n) acc += bf2f(h5[(size_t)n * 256 + t]);
    if (ce > cs) atomicAdd(&hp[gi * 256 + t], acc);
}

// ---------------- fused layer-6 + head (64 rows, exact f32) ----------------
__global__ __launch_bounds__(256) void head_kernel(
    const float* __restrict__ ap, const float* __restrict__ hp,
    const int* __restrict__ gcnt,
    const float* __restrict__ Wl6, const float* __restrict__ Wr6,
    const float* __restrict__ bl6,
    const float* __restrict__ Wlin, const float* __restrict__ blin,
    float* __restrict__ out) {
    __shared__ float a_s[256], h_s[256], t6[256];
    int g = blockIdx.x, t = threadIdx.x;
    float inv = 1.f / fmaxf((float)gcnt[g], 1.f);
    a_s[t] = ap[g * 256 + t] * inv;
    h_s[t] = hp[g * 256 + t] * inv;
    __syncthreads();
    float acc = 0.f;
    for (int k = 0; k < 256; ++k)
        acc += a_s[k] * Wl6[k * 256 + t] + h_s[k] * Wr6[k * 256 + t];
    t6[t] = acc + bl6[t];
    __syncthreads();
    if (t < 6) {
        float s = 0.f;
        for (int k = 0; k < 256; ++k) s += t6[k] * Wlin[k * 6 + t];
        out[g * 6 + t] = s + blin[t];
    }
}

extern "C" void kernel_launch(void* const* d_in, const int* in_sizes, int n_in,
                              void* d_out, int out_size, void* d_ws, size_t ws_size,
                              hipStream_t stream) {
    const float* x = (const float*)d_in[0];
    const int* ei = (const int*)d_in[1];
    const int* batch = (const int*)d_in[2];
    const float *Wl[6], *bl[6], *Wr[6];
    for (int l = 0; l < 6; ++l) {
        Wl[l] = (const float*)d_in[3 + 3 * l];
        bl[l] = (const float*)d_in[4 + 3 * l];
        Wr[l] = (const float*)d_in[5 + 3 * l];
    }
    const float* Wlin = (const float*)d_in[21];
    const float* blin = (const float*)d_in[22];
    float* out = (float*)d_out;

    char* ws = (char*)d_ws;
    size_t off = 0;
    auto alloc = [&](size_t bytes) {
        void* p = ws + off;
        off += (bytes + 255) & ~(size_t)255;
        return p;
    };
    short* xh   = (short*)alloc((size_t)MP * 128 * 2);
    short* hA   = (short*)alloc((size_t)MP * 512 * 2);
    short* hB   = (short*)alloc((size_t)MP * 512 * 2);
    short* P1   = (short*)alloc((size_t)MP * 512 * 2);
    float* P2   = (float*)alloc((size_t)MP * 512 * 4);
    int* col    = (int*)alloc((size_t)NE * 4);
    // ---- zeroed region start ----
    float* ap   = (float*)alloc((size_t)NG * 256 * 4);
    float* hp   = (float*)alloc((size_t)NG * 256 * 4);
    int* deg    = (int*)alloc((size_t)NN * 4);
    int* wcount = (int*)alloc((size_t)NN * 4);
    int* gcnt   = (int*)alloc((size_t)NG * 4);
    // ---- zeroed region end ----
    int* rowptr = (int*)alloc((size_t)(NN + 1) * 4);
    short* wtbuf = (short*)alloc((size_t)4 * 688128 * 2);
    (void)ws_size; (void)in_sizes; (void)n_in; (void)out_size;

    size_t zero_bytes = (size_t)((char*)gcnt - (char*)ap) + NG * 4;
    hipMemsetAsync((void*)ap, 0, zero_bytes, stream);

    const int* src = ei;
    const int* dst = ei + NE;
    hist_kernel<<<(NE + 255) / 256, 256, 0, stream>>>(dst, deg);
    scan_kernel<<<1, 1024, 0, stream>>>(deg, rowptr);
    fill_kernel<<<(NE + 255) / 256, 256, 0, stream>>>(src, dst, rowptr, wcount, col);
    xbf_kernel<<<(NN * 16 + 255) / 256, 256, 0, stream>>>(x, xh);

    const int dins[5]  = {128, 256, 256, 512, 512};
    const int douts[5] = {256, 256, 512, 512, 256};

    // batched weight transpose+split for layers 1-5 -> B^T = [Wl ; Wr], bf16 hi/lo
    short *Bth[5], *Btl[5];
    {
        WPack pack;
        short* p = wtbuf;
        int tcum = 0;
        for (int l = 0; l < 5; ++l) {
            size_t half = (size_t)dins[l] * douts[l];
            int ntiles = (dins[l] / 32) * (douts[l] / 32);
            Bth[l] = p; p += 2 * half;
            Btl[l] = p; p += 2 * half;
            pack.d[2 * l]     = { Wl[l], Bth[l],        Btl[l],        dins[l], douts[l], tcum }; tcum += ntiles;
            pack.d[2 * l + 1] = { Wr[l], Bth[l] + half, Btl[l] + half, dins[l], douts[l], tcum }; tcum += ntiles;
        }
        wconv_all<<<tcum, 256, 0, stream>>>(pack);
    }

    const short* cur = xh;
    short* hbuf[2] = {hA, hB};
    for (int l = 0; l < 5; ++l) {
        int K = dins[l], dout = douts[l];
        int ncol = (2 * dout) >> 7;            // 4 or 8
        int ncsh = (ncol == 4) ? 2 : 3;
        int nwg = (MP / 128) * ncol;
        gemm_mfma<<<nwg, 256, 0, stream>>>(cur, Bth[l], Btl[l], P1, P2, NN, K, dout, ncsh);
        if (dout == 256)
            agg_post<256><<<(NN + 7) / 8, 256, 0, stream>>>(P1, P2, bl[l], rowptr, col, hbuf[l & 1]);
        else
            agg_post<512><<<(NN + 3) / 4, 256, 0, stream>>>(P1, P2, bl[l], rowptr, col, hbuf[l & 1]);
        cur = hbuf[l & 1];
    }

    // fused layer-6 + pool + head (exact: pool commutes with the linear layer)
    dim3 pgrid(NG, PSPLIT);
    sgather<<<pgrid, 256, 0, stream>>>(cur, batch, rowptr, col, ap);
    pool_h<<<pgrid, 256, 0, stream>>>(cur, batch, hp, gcnt);
    head_kernel<<<NG, 256, 0, stream>>>(ap, hp, gcnt, Wl[5], Wr[5], bl[5], Wlin, blin, out);
}

// Round 9
// 450.262 us; speedup vs baseline: 2.8167x; 1.1392x over previous
//
#include <hip/hip_runtime.h>

#define NN 20000
#define MP 20096   // NN padded to 157*128
#define NE 160000
#define NG 64

typedef __attribute__((ext_vector_type(8))) short bf16x8;
typedef __attribute__((ext_vector_type(4))) float f32x4;

// round-to-nearest bf16 split: x ~= hi + lo (both bf16)
__device__ __forceinline__ void f2bf(float x, short& hi, short& lo) {
    unsigned u = __float_as_uint(x);
    unsigned rh = (u + 0x7FFFu + ((u >> 16) & 1u)) & 0xFFFF0000u;
    hi = (short)(rh >> 16);
    float l = x - __uint_as_float(rh);
    unsigned ul = __float_as_uint(l);
    lo = (short)((ul + 0x7FFFu + ((ul >> 16) & 1u)) >> 16);
}

__device__ __forceinline__ short f2bf_hi(float x) {
    unsigned u = __float_as_uint(x);
    return (short)((u + 0x7FFFu + ((u >> 16) & 1u)) >> 16);
}

__device__ __forceinline__ float bf2f(short h) {
    return __uint_as_float(((unsigned)(unsigned short)h) << 16);
}

typedef const __attribute__((address_space(1))) unsigned int* as1_u32p;
typedef __attribute__((address_space(3))) unsigned int* as3_u32p;
__device__ __forceinline__ void gll16(const void* g, void* l) {
    __builtin_amdgcn_global_load_lds((as1_u32p)g, (as3_u32p)l, 16, 0, 0);
}

// ---------------- CSR build ----------------
__global__ void hist_kernel(const int* __restrict__ dst, int* __restrict__ deg) {
    int e = blockIdx.x * 256 + threadIdx.x;
    if (e < NE) atomicAdd(&deg[dst[e]], 1);
}

__global__ void scan_kernel(const int* __restrict__ deg, int* __restrict__ rowptr) {
    __shared__ int wsum[16];
    __shared__ int carry_s;
    int t = threadIdx.x;
    int lane = t & 63, w = t >> 6;
    if (t == 0) carry_s = 0;
    __syncthreads();
    for (int base = 0; base < NN; base += 1024) {
        int i = base + t;
        int v = (i < NN) ? deg[i] : 0;
        int s = v;
        #pragma unroll
        for (int off = 1; off < 64; off <<= 1) {
            int u = __shfl_up(s, off, 64);
            if (lane >= off) s += u;
        }
        if (lane == 63) wsum[w] = s;
        __syncthreads();
        if (w == 0 && lane < 16) {
            int ws = wsum[lane];
            #pragma unroll
            for (int off = 1; off < 16; off <<= 1) {
                int u = __shfl_up(ws, off, 64);
                if (lane >= off) ws += u;
            }
            wsum[lane] = ws;
        }
        __syncthreads();
        int wpre = (w > 0) ? wsum[w - 1] : 0;
        int carry = carry_s;
        if (i < NN) rowptr[i] = carry + wpre + s - v;
        int total = wsum[15];
        __syncthreads();
        if (t == 0) carry_s = carry + total;
        __syncthreads();
    }
    if (t == 0) rowptr[NN] = carry_s;
}

// also writes per-CSR-position pool weight wgt[p] = 1/max(deg[dst],1)
__global__ void fill_kernel(const int* __restrict__ src, const int* __restrict__ dst,
                            const int* __restrict__ rowptr, const int* __restrict__ deg,
                            int* __restrict__ wcount, int* __restrict__ col,
                            float* __restrict__ wgt) {
    int e = blockIdx.x * 256 + threadIdx.x;
    if (e < NE) {
        int d = dst[e];
        int p = rowptr[d] + atomicAdd(&wcount[d], 1);
        col[p] = src[e];
        wgt[p] = 1.f / fmaxf((float)deg[d], 1.f);
    }
}

// ---------------- x -> bf16 (hi only) ----------------
__global__ void xbf_kernel(const float* __restrict__ x, short* __restrict__ xh) {
    int i = blockIdx.x * 256 + threadIdx.x;   // over NN*16 groups of 8 floats
    if (i >= NN * 16) return;
    float4 a = *(const float4*)&x[(size_t)i * 8];
    float4 b = *(const float4*)&x[(size_t)i * 8 + 4];
    bf16x8 v;
    v[0] = f2bf_hi(a.x); v[1] = f2bf_hi(a.y); v[2] = f2bf_hi(a.z); v[3] = f2bf_hi(a.w);
    v[4] = f2bf_hi(b.x); v[5] = f2bf_hi(b.y); v[6] = f2bf_hi(b.z); v[7] = f2bf_hi(b.w);
    *(bf16x8*)&xh[(size_t)i * 8] = v;
}

// ---------------- batched W transpose + hi/lo split (layers 1-5) ----------------
struct WDesc { const float* W; short* Wh; short* Wl; int K; int dout; int tstart; };
struct WPack { WDesc d[10]; };

__global__ __launch_bounds__(256) void wconv_all(WPack p) {
    __shared__ float tile[32][33];
    int bid = blockIdx.x;
    int i = 0;
    #pragma unroll
    for (int k = 1; k < 10; ++k)
        if (bid >= p.d[k].tstart) i = k;
    const float* W = p.d[i].W;
    short* Wh = p.d[i].Wh;
    short* Wl = p.d[i].Wl;
    int K = p.d[i].K, dout = p.d[i].dout;
    int local = bid - p.d[i].tstart;
    int ntk = K >> 5;
    int kb = (local % ntk) * 32, nb = (local / ntk) * 32;
    int t = threadIdx.x;
    int lr = t >> 5, lc = t & 31;
    #pragma unroll
    for (int r = 0; r < 4; ++r)
        tile[lr + r * 8][lc] = W[(size_t)(kb + lr + r * 8) * dout + nb + lc];
    __syncthreads();
    int nn = t >> 3, kq = (t & 7) * 4;
    short4 h, l;
    f2bf(tile[kq + 0][nn], h.x, l.x);
    f2bf(tile[kq + 1][nn], h.y, l.y);
    f2bf(tile[kq + 2][nn], h.z, l.z);
    f2bf(tile[kq + 3][nn], h.w, l.w);
    *(short4*)&Wh[(size_t)(nb + nn) * K + kb + kq] = h;
    *(short4*)&Wl[(size_t)(nb + nn) * K + kb + kq] = l;
}

// ---------------- single-A dual-N GEMM: [P1|P2] = h_bf16 @ (Bh+Bl) ----------------
__global__ __launch_bounds__(256, 3) void gemm_mfma(
    const short* __restrict__ A,
    const short* __restrict__ Bh, const short* __restrict__ Bl,   // [2*dout][K] bf16
    short* __restrict__ P1, float* __restrict__ P2,
    int M, int K, int dout, int ncsh) {
    __shared__ short lds[2][3][4096];   // [dbuf][A,Bh,Bl][128*32]
    int tid = threadIdx.x;
    int lane = tid & 63, w = tid >> 6;
    int wm = w >> 1, wn = w & 1;

    // bijective XCD swizzle (m204), panel-major work ids
    int nwg = gridDim.x;
    int q = nwg >> 3, r = nwg & 7;
    int xcd = blockIdx.x & 7, idx = blockIdx.x >> 3;
    int swz = (xcd < r ? xcd * (q + 1) : r * (q + 1) + (xcd - r) * q) + idx;
    int mblk = (swz >> ncsh) << 7;
    int nblk = (swz & ((1 << ncsh) - 1)) << 7;

    int rl = lane >> 2;                              // staging: row within 16-row DMA
    int gchunk = (lane & 3) ^ ((lane >> 3) & 3);     // pre-swizzled source chunk
    int nsteps = K >> 5;

    auto stage = [&](int b, int t) {
        int kc = t << 5;
        short* L = &lds[b][0][0];
        size_t ko = (size_t)kc + gchunk * 8;
        #pragma unroll
        for (int qq = 0; qq < 2; ++qq) {
            int row = w * 32 + qq * 16;
            int gr = row + rl;
            gll16(A  + (size_t)(mblk + gr) * K + ko, L + 0 * 4096 + row * 32);
            gll16(Bh + (size_t)(nblk + gr) * K + ko, L + 1 * 4096 + row * 32);
            gll16(Bl + (size_t)(nblk + gr) * K + ko, L + 2 * 4096 + row * 32);
        }
    };

    f32x4 acc[4][4] = {};
    int chunk_sw = (((lane >> 4) ^ ((lane >> 1) & 3))) << 3;  // swizzled read offset (shorts)
    int ar = (wm << 6) + (lane & 15);
    int br = (wn << 6) + (lane & 15);

    stage(0, 0);
    stage(1, 1);
    for (int t = 0; t < nsteps; ++t) {
        int b = t & 1;
        if (t < nsteps - 1) asm volatile("s_waitcnt vmcnt(6)" ::: "memory");
        else                asm volatile("s_waitcnt vmcnt(0)" ::: "memory");
        __builtin_amdgcn_s_barrier();          // tile t landed on all waves
        __builtin_amdgcn_sched_barrier(0);
        const short* L = &lds[b][0][0];
        bf16x8 av[4], bh[4], bl[4];
        #pragma unroll
        for (int i = 0; i < 4; ++i) {
            av[i] = *(const bf16x8*)(L + 0 * 4096 + (ar + i * 16) * 32 + chunk_sw);
            bh[i] = *(const bf16x8*)(L + 1 * 4096 + (br + i * 16) * 32 + chunk_sw);
            bl[i] = *(const bf16x8*)(L + 2 * 4096 + (br + i * 16) * 32 + chunk_sw);
        }
        #pragma unroll
        for (int i = 0; i < 4; ++i)
            #pragma unroll
            for (int j = 0; j < 4; ++j) {
                acc[i][j] = __builtin_amdgcn_mfma_f32_16x16x32_bf16(av[i], bh[j], acc[i][j], 0, 0, 0);
                acc[i][j] = __builtin_amdgcn_mfma_f32_16x16x32_bf16(av[i], bl[j], acc[i][j], 0, 0, 0);
            }
        __builtin_amdgcn_sched_barrier(0);
        __builtin_amdgcn_s_barrier();          // all waves done reading buffer b
        __builtin_amdgcn_sched_barrier(0);
        if (t + 2 < nsteps) stage(b, t + 2);   // overwrite b for step t+2 (WAR-safe)
    }

    // epilogue: C/D layout col=lane&15, row=(lane>>4)*4+reg
    int crow = mblk + (wm << 6) + ((lane >> 4) << 2);
    int ccol = nblk + (wn << 6) + (lane & 15);
    bool is_p1 = (nblk < dout);   // 128-wide n-block lies entirely in one half
    #pragma unroll
    for (int i = 0; i < 4; ++i) {
        #pragma unroll
        for (int r = 0; r < 4; ++r) {
            int gm = crow + i * 16 + r;
            if (gm >= M) continue;
            #pragma unroll
            for (int j = 0; j < 4; ++j) {
                int gn = ccol + j * 16;
                float c = acc[i][j][r];
                if (is_p1) P1[(size_t)gm * dout + gn] = f2bf_hi(c);
                else       P2[(size_t)gm * dout + (gn - dout)] = c;
            }
        }
    }
}

// ---------------- fused epilogue: h_next = bf16(leaky(mean_nbr(P1) + P2 + bias)) ----------------
// Edge loop 4-deep batched for memory-level parallelism.
template <int DOUT>
__global__ __launch_bounds__(256) void agg_post(
    const short* __restrict__ P1, const float* __restrict__ P2,
    const float* __restrict__ bias,
    const int* __restrict__ rowptr, const int* __restrict__ col,
    short* __restrict__ oh) {
    constexpr int TPN = DOUT / 8;
    constexpr int NPB = 256 / TPN;
    int node = blockIdx.x * NPB + threadIdx.x / TPN;
    if (node >= NN) return;
    int t = threadIdx.x % TPN;
    int s = rowptr[node], e = rowptr[node + 1];
    float acc[8] = {};
    int j = s;
    for (; j + 4 <= e; j += 4) {
        int c0 = col[j], c1 = col[j + 1], c2 = col[j + 2], c3 = col[j + 3];
        bf16x8 v0 = *(const bf16x8*)&P1[(size_t)c0 * DOUT + t * 8];
        bf16x8 v1 = *(const bf16x8*)&P1[(size_t)c1 * DOUT + t * 8];
        bf16x8 v2 = *(const bf16x8*)&P1[(size_t)c2 * DOUT + t * 8];
        bf16x8 v3 = *(const bf16x8*)&P1[(size_t)c3 * DOUT + t * 8];
        #pragma unroll
        for (int m = 0; m < 8; ++m)
            acc[m] += (bf2f(v0[m]) + bf2f(v1[m])) + (bf2f(v2[m]) + bf2f(v3[m]));
    }
    for (; j < e; ++j) {
        int c = col[j];
        bf16x8 v = *(const bf16x8*)&P1[(size_t)c * DOUT + t * 8];
        #pragma unroll
        for (int m = 0; m < 8; ++m) acc[m] += bf2f(v[m]);
    }
    float inv = 1.f / fmaxf((float)(e - s), 1.f);
    const float* p2 = &P2[(size_t)node * DOUT + t * 8];
    float4 pa = *(const float4*)p2;
    float4 pb = *(const float4*)(p2 + 4);
    float4 ba = *(const float4*)&bias[t * 8];
    float4 bb = *(const float4*)&bias[t * 8 + 4];
    float p2v[8] = {pa.x, pa.y, pa.z, pa.w, pb.x, pb.y, pb.z, pb.w};
    float bv[8]  = {ba.x, ba.y, ba.z, ba.w, bb.x, bb.y, bb.z, bb.w};
    bf16x8 vh;
    #pragma unroll
    for (int m = 0; m < 8; ++m) {
        float c = acc[m] * inv + p2v[m] + bv[m];
        c = (c >= 0.f) ? c : 0.01f * c;
        vh[m] = f2bf_hi(c);
    }
    *(bf16x8*)&oh[(size_t)node * DOUT + t * 8] = vh;
}

// ---------------- edge-parallel pooled-adjacency gather ----------------
// CSR positions are dst-sorted and dst nodes are graph-sorted => graph g's
// incoming edges are the contiguous range [rowptr[start_g], rowptr[end_g]).
// ap[g][t] = sum_p wgt[p] * h5[col[p]][t].
#define ESPLIT 32
__global__ __launch_bounds__(256) void sgather(const short* __restrict__ h5,
                                               const int* __restrict__ batch,
                                               const int* __restrict__ rowptr,
                                               const int* __restrict__ col,
                                               const float* __restrict__ wgt,
                                               float* __restrict__ ap) {
    int gi = blockIdx.x, c = blockIdx.y;
    int t = threadIdx.x;   // feature
    int lo = 0, hi = NN;
    while (lo < hi) { int m = (lo + hi) >> 1; if (batch[m] < gi) lo = m + 1; else hi = m; }
    int start = lo;
    hi = NN;
    while (lo < hi) { int m = (lo + hi) >> 1; if (batch[m] < gi + 1) lo = m + 1; else hi = m; }
    int end = lo;
    int e0 = rowptr[start], e1 = rowptr[end];
    int L = e1 - e0;
    int ps = e0 + (int)(((long)L * c) / ESPLIT);
    int pe = e0 + (int)(((long)L * (c + 1)) / ESPLIT);
    float acc = 0.f;
    int p = ps;
    for (; p + 4 <= pe; p += 4) {
        int c0 = col[p], c1 = col[p + 1], c2 = col[p + 2], c3 = col[p + 3];
        float w0 = wgt[p], w1 = wgt[p + 1], w2 = wgt[p + 2], w3 = wgt[p + 3];
        float a0 = bf2f(h5[(size_t)c0 * 256 + t]);
        float a1 = bf2f(h5[(size_t)c1 * 256 + t]);
        float a2 = bf2f(h5[(size_t)c2 * 256 + t]);
        float a3 = bf2f(h5[(size_t)c3 * 256 + t]);
        acc += (w0 * a0 + w1 * a1) + (w2 * a2 + w3 * a3);
    }
    for (; p < pe; ++p)
        acc += wgt[p] * bf2f(h5[(size_t)col[p] * 256 + t]);
    if (pe > ps) atomicAdd(&ap[gi * 256 + t], acc);
}

// ---------------- per-graph mean of h5 (bf16) ----------------
#define PSPLIT 16
__global__ __launch_bounds__(256) void pool_h(const short* __restrict__ h5,
                                              const int* __restrict__ batch,
                                              float* __restrict__ hp, int* __restrict__ gcnt) {
    int gi = blockIdx.x, c = blockIdx.y;
    int t = threadIdx.x;
    int lo = 0, hi = NN;
    while (lo < hi) { int m = (lo + hi) >> 1; if (batch[m] < gi) lo = m + 1; else hi = m; }
    int start = lo;
    hi = NN;
    while (lo < hi) { int m = (lo + hi) >> 1; if (batch[m] < gi + 1) lo = m + 1; else hi = m; }
    int end = lo;
    int L = end - start;
    if (c == 0 && t == 0) gcnt[gi] = L;
    int cs = start + (int)(((long)L * c) / PSPLIT);
    int ce = start + (int)(((long)L * (c + 1)) / PSPLIT);
    float acc = 0.f;
    for (int n = cs; n < ce; ++n) acc += bf2f(h5[(size_t)n * 256 + t]);
    if (ce > cs) atomicAdd(&hp[gi * 256 + t], acc);
}

// ---------------- fused layer-6 + head (64 rows, exact f32) ----------------
__global__ __launch_bounds__(256) void head_kernel(
    const float* __restrict__ ap, const float* __restrict__ hp,
    const int* __restrict__ gcnt,
    const float* __restrict__ Wl6, const float* __restrict__ Wr6,
    const float* __restrict__ bl6,
    const float* __restrict__ Wlin, const float* __restrict__ blin,
    float* __restrict__ out) {
    __shared__ float a_s[256], h_s[256], t6[256];
    int g = blockIdx.x, t = threadIdx.x;
    float inv = 1.f / fmaxf((float)gcnt[g], 1.f);
    a_s[t] = ap[g * 256 + t] * inv;
    h_s[t] = hp[g * 256 + t] * inv;
    __syncthreads();
    float acc = 0.f;
    for (int k = 0; k < 256; ++k)
        acc += a_s[k] * Wl6[k * 256 + t] + h_s[k] * Wr6[k * 256 + t];
    t6[t] = acc + bl6[t];
    __syncthreads();
    if (t < 6) {
        float s = 0.f;
        for (int k = 0; k < 256; ++k) s += t6[k] * Wlin[k * 6 + t];
        out[g * 6 + t] = s + blin[t];
    }
}

extern "C" void kernel_launch(void* const* d_in, const int* in_sizes, int n_in,
                              void* d_out, int out_size, void* d_ws, size_t ws_size,
                              hipStream_t stream) {
    const float* x = (const float*)d_in[0];
    const int* ei = (const int*)d_in[1];
    const int* batch = (const int*)d_in[2];
    const float *Wl[6], *bl[6], *Wr[6];
    for (int l = 0; l < 6; ++l) {
        Wl[l] = (const float*)d_in[3 + 3 * l];
        bl[l] = (const float*)d_in[4 + 3 * l];
        Wr[l] = (const float*)d_in[5 + 3 * l];
    }
    const float* Wlin = (const float*)d_in[21];
    const float* blin = (const float*)d_in[22];
    float* out = (float*)d_out;

    char* ws = (char*)d_ws;
    size_t off = 0;
    auto alloc = [&](size_t bytes) {
        void* p = ws + off;
        off += (bytes + 255) & ~(size_t)255;
        return p;
    };
    short* xh   = (short*)alloc((size_t)MP * 128 * 2);
    short* hA   = (short*)alloc((size_t)MP * 512 * 2);
    short* hB   = (short*)alloc((size_t)MP * 512 * 2);
    short* P1   = (short*)alloc((size_t)MP * 512 * 2);
    float* P2   = (float*)alloc((size_t)MP * 512 * 4);
    int* col    = (int*)alloc((size_t)NE * 4);
    float* wgt  = (float*)alloc((size_t)NE * 4);
    // ---- zeroed region start ----
    float* ap   = (float*)alloc((size_t)NG * 256 * 4);
    float* hp   = (float*)alloc((size_t)NG * 256 * 4);
    int* deg    = (int*)alloc((size_t)NN * 4);
    int* wcount = (int*)alloc((size_t)NN * 4);
    int* gcnt   = (int*)alloc((size_t)NG * 4);
    // ---- zeroed region end ----
    int* rowptr = (int*)alloc((size_t)(NN + 1) * 4);
    short* wtbuf = (short*)alloc((size_t)4 * 688128 * 2);
    (void)ws_size; (void)in_sizes; (void)n_in; (void)out_size;

    size_t zero_bytes = (size_t)((char*)gcnt - (char*)ap) + NG * 4;
    hipMemsetAsync((void*)ap, 0, zero_bytes, stream);

    const int* src = ei;
    const int* dst = ei + NE;
    hist_kernel<<<(NE + 255) / 256, 256, 0, stream>>>(dst, deg);
    scan_kernel<<<1, 1024, 0, stream>>>(deg, rowptr);
    fill_kernel<<<(NE + 255) / 256, 256, 0, stream>>>(src, dst, rowptr, deg, wcount, col, wgt);
    xbf_kernel<<<(NN * 16 + 255) / 256, 256, 0, stream>>>(x, xh);

    const int dins[5]  = {128, 256, 256, 512, 512};
    const int douts[5] = {256, 256, 512, 512, 256};

    // batched weight transpose+split for layers 1-5 -> B^T = [Wl ; Wr], bf16 hi/lo
    short *Bth[5], *Btl[5];
    {
        WPack pack;
        short* p = wtbuf;
        int tcum = 0;
        for (int l = 0; l < 5; ++l) {
            size_t half = (size_t)dins[l] * douts[l];
            int ntiles = (dins[l] / 32) * (douts[l] / 32);
            Bth[l] = p; p += 2 * half;
            Btl[l] = p; p += 2 * half;
            pack.d[2 * l]     = { Wl[l], Bth[l],        Btl[l],        dins[l], douts[l], tcum }; tcum += ntiles;
            pack.d[2 * l + 1] = { Wr[l], Bth[l] + half, Btl[l] + half, dins[l], douts[l], tcum }; tcum += ntiles;
        }
        wconv_all<<<tcum, 256, 0, stream>>>(pack);
    }

    const short* cur = xh;
    short* hbuf[2] = {hA, hB};
    for (int l = 0; l < 5; ++l) {
        int K = dins[l], dout = douts[l];
        int ncol = (2 * dout) >> 7;            // 4 or 8
        int ncsh = (ncol == 4) ? 2 : 3;
        int nwg = (MP / 128) * ncol;
        gemm_mfma<<<nwg, 256, 0, stream>>>(cur, Bth[l], Btl[l], P1, P2, NN, K, dout, ncsh);
        if (dout == 256)
            agg_post<256><<<(NN + 7) / 8, 256, 0, stream>>>(P1, P2, bl[l], rowptr, col, hbuf[l & 1]);
        else
            agg_post<512><<<(NN + 3) / 4, 256, 0, stream>>>(P1, P2, bl[l], rowptr, col, hbuf[l & 1]);
        cur = hbuf[l & 1];
    }

    // fused layer-6 + pool + head (exact: pool commutes with the linear layer)
    dim3 egrid(NG, ESPLIT);
    sgather<<<egrid, 256, 0, stream>>>(cur, batch, rowptr, col, wgt, ap);
    dim3 pgrid(NG, PSPLIT);
    pool_h<<<pgrid, 256, 0, stream>>>(cur, batch, hp, gcnt);
    head_kernel<<<NG, 256, 0, stream>>>(ap, hp, gcnt, Wl[5], Wr[5], bl[5], Wlin, blin, out);
}

// Round 11
// 423.629 us; speedup vs baseline: 2.9938x; 1.0629x over previous
//
#include <hip/hip_runtime.h>

#define NN 20000
#define MP 20096   // NN padded to 157*128
#define NE 160000
#define NG 64

typedef __attribute__((ext_vector_type(8))) short bf16x8;
typedef __attribute__((ext_vector_type(4))) float f32x4;

// round-to-nearest bf16 split: x ~= hi + lo (both bf16)
__device__ __forceinline__ void f2bf(float x, short& hi, short& lo) {
    unsigned u = __float_as_uint(x);
    unsigned rh = (u + 0x7FFFu + ((u >> 16) & 1u)) & 0xFFFF0000u;
    hi = (short)(rh >> 16);
    float l = x - __uint_as_float(rh);
    unsigned ul = __float_as_uint(l);
    lo = (short)((ul + 0x7FFFu + ((ul >> 16) & 1u)) >> 16);
}

__device__ __forceinline__ short f2bf_hi(float x) {
    unsigned u = __float_as_uint(x);
    return (short)((u + 0x7FFFu + ((u >> 16) & 1u)) >> 16);
}

__device__ __forceinline__ float bf2f(short h) {
    return __uint_as_float(((unsigned)(unsigned short)h) << 16);
}

typedef const __attribute__((address_space(1))) unsigned int* as1_u32p;
typedef __attribute__((address_space(3))) unsigned int* as3_u32p;
__device__ __forceinline__ void gll16(const void* g, void* l) {
    __builtin_amdgcn_global_load_lds((as1_u32p)g, (as3_u32p)l, 16, 0, 0);
}

// ---------------- CSR build ----------------
__global__ void hist_kernel(const int* __restrict__ dst, int* __restrict__ deg) {
    int e = blockIdx.x * 256 + threadIdx.x;
    if (e < NE) atomicAdd(&deg[dst[e]], 1);
}

__global__ void scan_kernel(const int* __restrict__ deg, int* __restrict__ rowptr) {
    __shared__ int wsum[16];
    __shared__ int carry_s;
    int t = threadIdx.x;
    int lane = t & 63, w = t >> 6;
    if (t == 0) carry_s = 0;
    __syncthreads();
    for (int base = 0; base < NN; base += 1024) {
        int i = base + t;
        int v = (i < NN) ? deg[i] : 0;
        int s = v;
        #pragma unroll
        for (int off = 1; off < 64; off <<= 1) {
            int u = __shfl_up(s, off, 64);
            if (lane >= off) s += u;
        }
        if (lane == 63) wsum[w] = s;
        __syncthreads();
        if (w == 0 && lane < 16) {
            int ws = wsum[lane];
            #pragma unroll
            for (int off = 1; off < 16; off <<= 1) {
                int u = __shfl_up(ws, off, 64);
                if (lane >= off) ws += u;
            }
            wsum[lane] = ws;
        }
        __syncthreads();
        int wpre = (w > 0) ? wsum[w - 1] : 0;
        int carry = carry_s;
        if (i < NN) rowptr[i] = carry + wpre + s - v;
        int total = wsum[15];
        __syncthreads();
        if (t == 0) carry_s = carry + total;
        __syncthreads();
    }
    if (t == 0) rowptr[NN] = carry_s;
}

// also writes per-CSR-position pool weight wgt[p] = 1/max(deg[dst],1)
__global__ void fill_kernel(const int* __restrict__ src, const int* __restrict__ dst,
                            const int* __restrict__ rowptr, const int* __restrict__ deg,
                            int* __restrict__ wcount, int* __restrict__ col,
                            float* __restrict__ wgt) {
    int e = blockIdx.x * 256 + threadIdx.x;
    if (e < NE) {
        int d = dst[e];
        int p = rowptr[d] + atomicAdd(&wcount[d], 1);
        col[p] = src[e];
        wgt[p] = 1.f / fmaxf((float)deg[d], 1.f);
    }
}

// ---------------- x -> bf16 (hi only) ----------------
__global__ void xbf_kernel(const float* __restrict__ x, short* __restrict__ xh) {
    int i = blockIdx.x * 256 + threadIdx.x;   // over NN*16 groups of 8 floats
    if (i >= NN * 16) return;
    float4 a = *(const float4*)&x[(size_t)i * 8];
    float4 b = *(const float4*)&x[(size_t)i * 8 + 4];
    bf16x8 v;
    v[0] = f2bf_hi(a.x); v[1] = f2bf_hi(a.y); v[2] = f2bf_hi(a.z); v[3] = f2bf_hi(a.w);
    v[4] = f2bf_hi(b.x); v[5] = f2bf_hi(b.y); v[6] = f2bf_hi(b.z); v[7] = f2bf_hi(b.w);
    *(bf16x8*)&xh[(size_t)i * 8] = v;
}

// ---------------- batched W transpose + bf16 round (layers 1-5) ----------------
struct WDesc { const float* W; short* Wh; int K; int dout; int tstart; };
struct WPack { WDesc d[10]; };

__global__ __launch_bounds__(256) void wconv_all(WPack p) {
    __shared__ float tile[32][33];
    int bid = blockIdx.x;
    int i = 0;
    #pragma unroll
    for (int k = 1; k < 10; ++k)
        if (bid >= p.d[k].tstart) i = k;
    const float* W = p.d[i].W;
    short* Wh = p.d[i].Wh;
    int K = p.d[i].K, dout = p.d[i].dout;
    int local = bid - p.d[i].tstart;
    int ntk = K >> 5;
    int kb = (local % ntk) * 32, nb = (local / ntk) * 32;
    int t = threadIdx.x;
    int lr = t >> 5, lc = t & 31;
    #pragma unroll
    for (int r = 0; r < 4; ++r)
        tile[lr + r * 8][lc] = W[(size_t)(kb + lr + r * 8) * dout + nb + lc];
    __syncthreads();
    int nn = t >> 3, kq = (t & 7) * 4;
    short4 h;
    h.x = f2bf_hi(tile[kq + 0][nn]);
    h.y = f2bf_hi(tile[kq + 1][nn]);
    h.z = f2bf_hi(tile[kq + 2][nn]);
    h.w = f2bf_hi(tile[kq + 3][nn]);
    *(short4*)&Wh[(size_t)(nb + nn) * K + kb + kq] = h;
}

// ---------------- single-A single-B GEMM: [P1|P2] = h_bf16 @ W_bf16 ----------------
// 128x128 tile, 4 waves 2x2, counted-vmcnt 2-deep pipeline, bijective XCD swizzle.
__global__ __launch_bounds__(256, 4) void gemm_mfma(
    const short* __restrict__ A,
    const short* __restrict__ Bh,                                 // [2*dout][K] bf16
    short* __restrict__ P1, float* __restrict__ P2,
    int M, int K, int dout, int ncsh) {
    __shared__ short lds[2][2][4096];   // [dbuf][A,B][128*32]
    int tid = threadIdx.x;
    int lane = tid & 63, w = tid >> 6;
    int wm = w >> 1, wn = w & 1;

    // bijective XCD swizzle (m204), panel-major work ids
    int nwg = gridDim.x;
    int q = nwg >> 3, r = nwg & 7;
    int xcd = blockIdx.x & 7, idx = blockIdx.x >> 3;
    int swz = (xcd < r ? xcd * (q + 1) : r * (q + 1) + (xcd - r) * q) + idx;
    int mblk = (swz >> ncsh) << 7;
    int nblk = (swz & ((1 << ncsh) - 1)) << 7;

    int rl = lane >> 2;                              // staging: row within 16-row DMA
    int gchunk = (lane & 3) ^ ((lane >> 3) & 3);     // pre-swizzled source chunk
    int nsteps = K >> 5;

    auto stage = [&](int b, int t) {
        int kc = t << 5;
        short* L = &lds[b][0][0];
        size_t ko = (size_t)kc + gchunk * 8;
        #pragma unroll
        for (int qq = 0; qq < 2; ++qq) {
            int row = w * 32 + qq * 16;
            int gr = row + rl;
            gll16(A  + (size_t)(mblk + gr) * K + ko, L + 0 * 4096 + row * 32);
            gll16(Bh + (size_t)(nblk + gr) * K + ko, L + 1 * 4096 + row * 32);
        }
    };

    f32x4 acc[4][4] = {};
    int chunk_sw = (((lane >> 4) ^ ((lane >> 1) & 3))) << 3;  // swizzled read offset (shorts)
    int ar = (wm << 6) + (lane & 15);
    int br = (wn << 6) + (lane & 15);

    stage(0, 0);
    stage(1, 1);
    for (int t = 0; t < nsteps; ++t) {
        int b = t & 1;
        if (t < nsteps - 1) asm volatile("s_waitcnt vmcnt(4)" ::: "memory");
        else                asm volatile("s_waitcnt vmcnt(0)" ::: "memory");
        __builtin_amdgcn_s_barrier();          // tile t landed on all waves
        __builtin_amdgcn_sched_barrier(0);
        const short* L = &lds[b][0][0];
        bf16x8 av[4], bv[4];
        #pragma unroll
        for (int i = 0; i < 4; ++i) {
            av[i] = *(const bf16x8*)(L + 0 * 4096 + (ar + i * 16) * 32 + chunk_sw);
            bv[i] = *(const bf16x8*)(L + 1 * 4096 + (br + i * 16) * 32 + chunk_sw);
        }
        #pragma unroll
        for (int i = 0; i < 4; ++i)
            #pragma unroll
            for (int j = 0; j < 4; ++j)
                acc[i][j] = __builtin_amdgcn_mfma_f32_16x16x32_bf16(av[i], bv[j], acc[i][j], 0, 0, 0);
        __builtin_amdgcn_sched_barrier(0);
        __builtin_amdgcn_s_barrier();          // all waves done reading buffer b
        __builtin_amdgcn_sched_barrier(0);
        if (t + 2 < nsteps) stage(b, t + 2);   // overwrite b for step t+2 (WAR-safe)
    }

    // epilogue: C/D layout col=lane&15, row=(lane>>4)*4+reg
    int crow = mblk + (wm << 6) + ((lane >> 4) << 2);
    int ccol = nblk + (wn << 6) + (lane & 15);
    bool is_p1 = (nblk < dout);   // 128-wide n-block lies entirely in one half
    #pragma unroll
    for (int i = 0; i < 4; ++i) {
        #pragma unroll
        for (int r = 0; r < 4; ++r) {
            int gm = crow + i * 16 + r;
            if (gm >= M) continue;
            #pragma unroll
            for (int j = 0; j < 4; ++j) {
                int gn = ccol + j * 16;
                float c = acc[i][j][r];
                if (is_p1) P1[(size_t)gm * dout + gn] = f2bf_hi(c);
                else       P2[(size_t)gm * dout + (gn - dout)] = c;
            }
        }
    }
}

// ---------------- fused epilogue: h_next = bf16(leaky(mean_nbr(P1) + P2 + bias)) ----------------
// Edge loop 4-deep batched for memory-level parallelism.
template <int DOUT>
__global__ __launch_bounds__(256) void agg_post(
    const short* __restrict__ P1, const float* __restrict__ P2,
    const float* __restrict__ bias,
    const int* __restrict__ rowptr, const int* __restrict__ col,
    short* __restrict__ oh) {
    constexpr int TPN = DOUT / 8;
    constexpr int NPB = 256 / TPN;
    int node = blockIdx.x * NPB + threadIdx.x / TPN;
    if (node >= NN) return;
    int t = threadIdx.x % TPN;
    int s = rowptr[node], e = rowptr[node + 1];
    float acc[8] = {};
    int j = s;
    for (; j + 4 <= e; j += 4) {
        int c0 = col[j], c1 = col[j + 1], c2 = col[j + 2], c3 = col[j + 3];
        bf16x8 v0 = *(const bf16x8*)&P1[(size_t)c0 * DOUT + t * 8];
        bf16x8 v1 = *(const bf16x8*)&P1[(size_t)c1 * DOUT + t * 8];
        bf16x8 v2 = *(const bf16x8*)&P1[(size_t)c2 * DOUT + t * 8];
        bf16x8 v3 = *(const bf16x8*)&P1[(size_t)c3 * DOUT + t * 8];
        #pragma unroll
        for (int m = 0; m < 8; ++m)
            acc[m] += (bf2f(v0[m]) + bf2f(v1[m])) + (bf2f(v2[m]) + bf2f(v3[m]));
    }
    for (; j < e; ++j) {
        int c = col[j];
        bf16x8 v = *(const bf16x8*)&P1[(size_t)c * DOUT + t * 8];
        #pragma unroll
        for (int m = 0; m < 8; ++m) acc[m] += bf2f(v[m]);
    }
    float inv = 1.f / fmaxf((float)(e - s), 1.f);
    const float* p2 = &P2[(size_t)node * DOUT + t * 8];
    float4 pa = *(const float4*)p2;
    float4 pb = *(const float4*)(p2 + 4);
    float4 ba = *(const float4*)&bias[t * 8];
    float4 bb = *(const float4*)&bias[t * 8 + 4];
    float p2v[8] = {pa.x, pa.y, pa.z, pa.w, pb.x, pb.y, pb.z, pb.w};
    float bv[8]  = {ba.x, ba.y, ba.z, ba.w, bb.x, bb.y, bb.z, bb.w};
    bf16x8 vh;
    #pragma unroll
    for (int m = 0; m < 8; ++m) {
        float c = acc[m] * inv + p2v[m] + bv[m];
        c = (c >= 0.f) ? c : 0.01f * c;
        vh[m] = f2bf_hi(c);
    }
    *(bf16x8*)&oh[(size_t)node * DOUT + t * 8] = vh;
}

// ---------------- edge-parallel pooled-adjacency gather ----------------
#define ESPLIT 32
__global__ __launch_bounds__(256) void sgather(const short* __restrict__ h5,
                                               const int* __restrict__ batch,
                                               const int* __restrict__ rowptr,
                                               const int* __restrict__ col,
                                               const float* __restrict__ wgt,
                                               float* __restrict__ ap) {
    int gi = blockIdx.x, c = blockIdx.y;
    int t = threadIdx.x;   // feature
    int lo = 0, hi = NN;
    while (lo < hi) { int m = (lo + hi) >> 1; if (batch[m] < gi) lo = m + 1; else hi = m; }
    int start = lo;
    hi = NN;
    while (lo < hi) { int m = (lo + hi) >> 1; if (batch[m] < gi + 1) lo = m + 1; else hi = m; }
    int end = lo;
    int e0 = rowptr[start], e1 = rowptr[end];
    int L = e1 - e0;
    int ps = e0 + (int)(((long)L * c) / ESPLIT);
    int pe = e0 + (int)(((long)L * (c + 1)) / ESPLIT);
    float acc = 0.f;
    int p = ps;
    for (; p + 4 <= pe; p += 4) {
        int c0 = col[p], c1 = col[p + 1], c2 = col[p + 2], c3 = col[p + 3];
        float w0 = wgt[p], w1 = wgt[p + 1], w2 = wgt[p + 2], w3 = wgt[p + 3];
        float a0 = bf2f(h5[(size_t)c0 * 256 + t]);
        float a1 = bf2f(h5[(size_t)c1 * 256 + t]);
        float a2 = bf2f(h5[(size_t)c2 * 256 + t]);
        float a3 = bf2f(h5[(size_t)c3 * 256 + t]);
        acc += (w0 * a0 + w1 * a1) + (w2 * a2 + w3 * a3);
    }
    for (; p < pe; ++p)
        acc += wgt[p] * bf2f(h5[(size_t)col[p] * 256 + t]);
    if (pe > ps) atomicAdd(&ap[gi * 256 + t], acc);
}

// ---------------- per-graph mean of h5 (bf16) ----------------
#define PSPLIT 16
__global__ __launch_bounds__(256) void pool_h(const short* __restrict__ h5,
                                              const int* __restrict__ batch,
                                              float* __restrict__ hp, int* __restrict__ gcnt) {
    int gi = blockIdx.x, c = blockIdx.y;
    int t = threadIdx.x;
    int lo = 0, hi = NN;
    while (lo < hi) { int m = (lo + hi) >> 1; if (batch[m] < gi) lo = m + 1; else hi = m; }
    int start = lo;
    hi = NN;
    while (lo < hi) { int m = (lo + hi) >> 1; if (batch[m] < gi + 1) lo = m + 1; else hi = m; }
    int end = lo;
    int L = end - start;
    if (c == 0 && t == 0) gcnt[gi] = L;
    int cs = start + (int)(((long)L * c) / PSPLIT);
    int ce = start + (int)(((long)L * (c + 1)) / PSPLIT);
    float acc = 0.f;
    for (int n = cs; n < ce; ++n) acc += bf2f(h5[(size_t)n * 256 + t]);
    if (ce > cs) atomicAdd(&hp[gi * 256 + t], acc);
}

// ---------------- fused layer-6 + head (64 rows, exact f32) ----------------
__global__ __launch_bounds__(256) void head_kernel(
    const float* __restrict__ ap, const float* __restrict__ hp,
    const int* __restrict__ gcnt,
    const float* __restrict__ Wl6, const float* __restrict__ Wr6,
    const float* __restrict__ bl6,
    const float* __restrict__ Wlin, const float* __restrict__ blin,
    float* __restrict__ out) {
    __shared__ float a_s[256], h_s[256], t6[256];
    int g = blockIdx.x, t = threadIdx.x;
    float inv = 1.f / fmaxf((float)gcnt[g], 1.f);
    a_s[t] = ap[g * 256 + t] * inv;
    h_s[t] = hp[g * 256 + t] * inv;
    __syncthreads();
    float acc = 0.f;
    for (int k = 0; k < 256; ++k)
        acc += a_s[k] * Wl6[k * 256 + t] + h_s[k] * Wr6[k * 256 + t];
    t6[t] = acc + bl6[t];
    __syncthreads();
    if (t < 6) {
        float s = 0.f;
        for (int k = 0; k < 256; ++k) s += t6[k] * Wlin[k * 6 + t];
        out[g * 6 + t] = s + blin[t];
    }
}

extern "C" void kernel_launch(void* const* d_in, const int* in_sizes, int n_in,
                              void* d_out, int out_size, void* d_ws, size_t ws_size,
                              hipStream_t stream) {
    const float* x = (const float*)d_in[0];
    const int* ei = (const int*)d_in[1];
    const int* batch = (const int*)d_in[2];
    const float *Wl[6], *bl[6], *Wr[6];
    for (int l = 0; l < 6; ++l) {
        Wl[l] = (const float*)d_in[3 + 3 * l];
        bl[l] = (const float*)d_in[4 + 3 * l];
        Wr[l] = (const float*)d_in[5 + 3 * l];
    }
    const float* Wlin = (const float*)d_in[21];
    const float* blin = (const float*)d_in[22];
    float* out = (float*)d_out;

    char* ws = (char*)d_ws;
    size_t off = 0;
    auto alloc = [&](size_t bytes) {
        void* p = ws + off;
        off += (bytes + 255) & ~(size_t)255;
        return p;
    };
    short* xh   = (short*)alloc((size_t)MP * 128 * 2);
    short* hA   = (short*)alloc((size_t)MP * 512 * 2);
    short* hB   = (short*)alloc((size_t)MP * 512 * 2);
    short* P1   = (short*)alloc((size_t)MP * 512 * 2);
    float* P2   = (float*)alloc((size_t)MP * 512 * 4);
    int* col    = (int*)alloc((size_t)NE * 4);
    float* wgt  = (float*)alloc((size_t)NE * 4);
    // ---- zeroed region start ----
    float* ap   = (float*)alloc((size_t)NG * 256 * 4);
    float* hp   = (float*)alloc((size_t)NG * 256 * 4);
    int* deg    = (int*)alloc((size_t)NN * 4);
    int* wcount = (int*)alloc((size_t)NN * 4);
    int* gcnt   = (int*)alloc((size_t)NG * 4);
    // ---- zeroed region end ----
    int* rowptr = (int*)alloc((size_t)(NN + 1) * 4);
    short* wtbuf = (short*)alloc((size_t)4 * 688128 * 2);
    (void)ws_size; (void)in_sizes; (void)n_in; (void)out_size;

    size_t zero_bytes = (size_t)((char*)gcnt - (char*)ap) + NG * 4;
    hipMemsetAsync((void*)ap, 0, zero_bytes, stream);

    const int* src = ei;
    const int* dst = ei + NE;
    hist_kernel<<<(NE + 255) / 256, 256, 0, stream>>>(dst, deg);
    scan_kernel<<<1, 1024, 0, stream>>>(deg, rowptr);
    fill_kernel<<<(NE + 255) / 256, 256, 0, stream>>>(src, dst, rowptr, deg, wcount, col, wgt);
    xbf_kernel<<<(NN * 16 + 255) / 256, 256, 0, stream>>>(x, xh);

    const int dins[5]  = {128, 256, 256, 512, 512};
    const int douts[5] = {256, 256, 512, 512, 256};

    // batched weight transpose+round for layers 1-5 -> B^T = [Wl ; Wr], bf16
    short* Bth[5];
    {
        WPack pack;
        short* p = wtbuf;
        int tcum = 0;
        for (int l = 0; l < 5; ++l) {
            size_t half = (size_t)dins[l] * douts[l];
            int ntiles = (dins[l] / 32) * (douts[l] / 32);
            Bth[l] = p; p += 2 * half;
            pack.d[2 * l]     = { Wl[l], Bth[l],        dins[l], douts[l], tcum }; tcum += ntiles;
            pack.d[2 * l + 1] = { Wr[l], Bth[l] + half, dins[l], douts[l], tcum }; tcum += ntiles;
        }
        wconv_all<<<tcum, 256, 0, stream>>>(pack);
    }

    const short* cur = xh;
    short* hbuf[2] = {hA, hB};
    for (int l = 0; l < 5; ++l) {
        int K = dins[l], dout = douts[l];
        int ncol = (2 * dout) >> 7;            // 4 or 8
        int ncsh = (ncol == 4) ? 2 : 3;
        int nwg = (MP / 128) * ncol;
        gemm_mfma<<<nwg, 256, 0, stream>>>(cur, Bth[l], P1, P2, NN, K, dout, ncsh);
        if (dout == 256)
            agg_post<256><<<(NN + 7) / 8, 256, 0, stream>>>(P1, P2, bl[l], rowptr, col, hbuf[l & 1]);
        else
            agg_post<512><<<(NN + 3) / 4, 256, 0, stream>>>(P1, P2, bl[l], rowptr, col, hbuf[l & 1]);
        cur = hbuf[l & 1];
    }

    // fused layer-6 + pool + head (exact: pool commutes with the linear layer)
    dim3 egrid(NG, ESPLIT);
    sgather<<<egrid, 256, 0, stream>>>(cur, batch, rowptr, col, wgt, ap);
    dim3 pgrid(NG, PSPLIT);
    pool_h<<<pgrid, 256, 0, stream>>>(cur, batch, hp, gcnt);
    head_kernel<<<NG, 256, 0, stream>>>(ap, hp, gcnt, Wl[5], Wr[5], bl[5], Wlin, blin, out);
}

// Round 12
// 397.458 us; speedup vs baseline: 3.1909x; 1.0658x over previous
//
#include <hip/hip_runtime.h>

#define NN 20000
#define MP 20096   // NN padded to 157*128
#define NE 160000
#define NG 64

typedef __attribute__((ext_vector_type(8))) short bf16x8;
typedef __attribute__((ext_vector_type(4))) float f32x4;

__device__ __forceinline__ short f2bf_hi(float x) {
    unsigned u = __float_as_uint(x);
    return (short)((u + 0x7FFFu + ((u >> 16) & 1u)) >> 16);
}

__device__ __forceinline__ float bf2f(short h) {
    return __uint_as_float(((unsigned)(unsigned short)h) << 16);
}

typedef const __attribute__((address_space(1))) unsigned int* as1_u32p;
typedef __attribute__((address_space(3))) unsigned int* as3_u32p;
__device__ __forceinline__ void gll16(const void* g, void* l) {
    __builtin_amdgcn_global_load_lds((as1_u32p)g, (as3_u32p)l, 16, 0, 0);
}

// ---------------- CSR build ----------------
__global__ void hist_kernel(const int* __restrict__ dst, int* __restrict__ deg) {
    int e = blockIdx.x * 256 + threadIdx.x;
    if (e < NE) atomicAdd(&deg[dst[e]], 1);
}

__global__ void scan_kernel(const int* __restrict__ deg, int* __restrict__ rowptr) {
    __shared__ int wsum[16];
    __shared__ int carry_s;
    int t = threadIdx.x;
    int lane = t & 63, w = t >> 6;
    if (t == 0) carry_s = 0;
    __syncthreads();
    for (int base = 0; base < NN; base += 1024) {
        int i = base + t;
        int v = (i < NN) ? deg[i] : 0;
        int s = v;
        #pragma unroll
        for (int off = 1; off < 64; off <<= 1) {
            int u = __shfl_up(s, off, 64);
            if (lane >= off) s += u;
        }
        if (lane == 63) wsum[w] = s;
        __syncthreads();
        if (w == 0 && lane < 16) {
            int ws = wsum[lane];
            #pragma unroll
            for (int off = 1; off < 16; off <<= 1) {
                int u = __shfl_up(ws, off, 64);
                if (lane >= off) ws += u;
            }
            wsum[lane] = ws;
        }
        __syncthreads();
        int wpre = (w > 0) ? wsum[w - 1] : 0;
        int carry = carry_s;
        if (i < NN) rowptr[i] = carry + wpre + s - v;
        int total = wsum[15];
        __syncthreads();
        if (t == 0) carry_s = carry + total;
        __syncthreads();
    }
    if (t == 0) rowptr[NN] = carry_s;
}

// also writes per-CSR-position pool weight wgt[p] = 1/max(deg[dst],1)
__global__ void fill_kernel(const int* __restrict__ src, const int* __restrict__ dst,
                            const int* __restrict__ rowptr, const int* __restrict__ deg,
                            int* __restrict__ wcount, int* __restrict__ col,
                            float* __restrict__ wgt) {
    int e = blockIdx.x * 256 + threadIdx.x;
    if (e < NE) {
        int d = dst[e];
        int p = rowptr[d] + atomicAdd(&wcount[d], 1);
        col[p] = src[e];
        wgt[p] = 1.f / fmaxf((float)deg[d], 1.f);
    }
}

// ---------------- x -> bf16 (hi only) ----------------
__global__ void xbf_kernel(const float* __restrict__ x, short* __restrict__ xh) {
    int i = blockIdx.x * 256 + threadIdx.x;   // over NN*16 groups of 8 floats
    if (i >= NN * 16) return;
    float4 a = *(const float4*)&x[(size_t)i * 8];
    float4 b = *(const float4*)&x[(size_t)i * 8 + 4];
    bf16x8 v;
    v[0] = f2bf_hi(a.x); v[1] = f2bf_hi(a.y); v[2] = f2bf_hi(a.z); v[3] = f2bf_hi(a.w);
    v[4] = f2bf_hi(b.x); v[5] = f2bf_hi(b.y); v[6] = f2bf_hi(b.z); v[7] = f2bf_hi(b.w);
    *(bf16x8*)&xh[(size_t)i * 8] = v;
}

// ---------------- batched W transpose + bf16 round (layers 1-5) ----------------
struct WDesc { const float* W; short* Wh; int K; int dout; int tstart; };
struct WPack { WDesc d[10]; };

__global__ __launch_bounds__(256) void wconv_all(WPack p) {
    __shared__ float tile[32][33];
    int bid = blockIdx.x;
    int i = 0;
    #pragma unroll
    for (int k = 1; k < 10; ++k)
        if (bid >= p.d[k].tstart) i = k;
    const float* W = p.d[i].W;
    short* Wh = p.d[i].Wh;
    int K = p.d[i].K, dout = p.d[i].dout;
    int local = bid - p.d[i].tstart;
    int ntk = K >> 5;
    int kb = (local % ntk) * 32, nb = (local / ntk) * 32;
    int t = threadIdx.x;
    int lr = t >> 5, lc = t & 31;
    #pragma unroll
    for (int r = 0; r < 4; ++r)
        tile[lr + r * 8][lc] = W[(size_t)(kb + lr + r * 8) * dout + nb + lc];
    __syncthreads();
    int nn = t >> 3, kq = (t & 7) * 4;
    short4 h;
    h.x = f2bf_hi(tile[kq + 0][nn]);
    h.y = f2bf_hi(tile[kq + 1][nn]);
    h.z = f2bf_hi(tile[kq + 2][nn]);
    h.w = f2bf_hi(tile[kq + 3][nn]);
    *(short4*)&Wh[(size_t)(nb + nn) * K + kb + kq] = h;
}

// ---------------- single-A single-B GEMM: [P1|P2] = h_bf16 @ W_bf16 ----------------
// 128x128 tile, 4 waves 2x2, counted-vmcnt 2-deep pipeline, bijective XCD swizzle.
// Both output halves stored bf16 (P1 = Wl product, P2 = Wr self-term).
__global__ __launch_bounds__(256, 4) void gemm_mfma(
    const short* __restrict__ A,
    const short* __restrict__ Bh,                                 // [2*dout][K] bf16
    short* __restrict__ P1, short* __restrict__ P2,
    int M, int K, int dout, int ncsh) {
    __shared__ short lds[2][2][4096];   // [dbuf][A,B][128*32]
    int tid = threadIdx.x;
    int lane = tid & 63, w = tid >> 6;
    int wm = w >> 1, wn = w & 1;

    // bijective XCD swizzle (m204), panel-major work ids
    int nwg = gridDim.x;
    int q = nwg >> 3, r = nwg & 7;
    int xcd = blockIdx.x & 7, idx = blockIdx.x >> 3;
    int swz = (xcd < r ? xcd * (q + 1) : r * (q + 1) + (xcd - r) * q) + idx;
    int mblk = (swz >> ncsh) << 7;
    int nblk = (swz & ((1 << ncsh) - 1)) << 7;

    int rl = lane >> 2;                              // staging: row within 16-row DMA
    int gchunk = (lane & 3) ^ ((lane >> 3) & 3);     // pre-swizzled source chunk
    int nsteps = K >> 5;

    auto stage = [&](int b, int t) {
        int kc = t << 5;
        short* L = &lds[b][0][0];
        size_t ko = (size_t)kc + gchunk * 8;
        #pragma unroll
        for (int qq = 0; qq < 2; ++qq) {
            int row = w * 32 + qq * 16;
            int gr = row + rl;
            gll16(A  + (size_t)(mblk + gr) * K + ko, L + 0 * 4096 + row * 32);
            gll16(Bh + (size_t)(nblk + gr) * K + ko, L + 1 * 4096 + row * 32);
        }
    };

    f32x4 acc[4][4] = {};
    int chunk_sw = (((lane >> 4) ^ ((lane >> 1) & 3))) << 3;  // swizzled read offset (shorts)
    int ar = (wm << 6) + (lane & 15);
    int br = (wn << 6) + (lane & 15);

    stage(0, 0);
    stage(1, 1);
    for (int t = 0; t < nsteps; ++t) {
        int b = t & 1;
        if (t < nsteps - 1) asm volatile("s_waitcnt vmcnt(4)" ::: "memory");
        else                asm volatile("s_waitcnt vmcnt(0)" ::: "memory");
        __builtin_amdgcn_s_barrier();          // tile t landed on all waves
        __builtin_amdgcn_sched_barrier(0);
        const short* L = &lds[b][0][0];
        bf16x8 av[4], bv[4];
        #pragma unroll
        for (int i = 0; i < 4; ++i) {
            av[i] = *(const bf16x8*)(L + 0 * 4096 + (ar + i * 16) * 32 + chunk_sw);
            bv[i] = *(const bf16x8*)(L + 1 * 4096 + (br + i * 16) * 32 + chunk_sw);
        }
        #pragma unroll
        for (int i = 0; i < 4; ++i)
            #pragma unroll
            for (int j = 0; j < 4; ++j)
                acc[i][j] = __builtin_amdgcn_mfma_f32_16x16x32_bf16(av[i], bv[j], acc[i][j], 0, 0, 0);
        __builtin_amdgcn_sched_barrier(0);
        __builtin_amdgcn_s_barrier();          // all waves done reading buffer b
        __builtin_amdgcn_sched_barrier(0);
        if (t + 2 < nsteps) stage(b, t + 2);   // overwrite b for step t+2 (WAR-safe)
    }

    // epilogue: C/D layout col=lane&15, row=(lane>>4)*4+reg
    int crow = mblk + (wm << 6) + ((lane >> 4) << 2);
    int ccol = nblk + (wn << 6) + (lane & 15);
    bool is_p1 = (nblk < dout);   // 128-wide n-block lies entirely in one half
    short* P = is_p1 ? P1 : P2;
    int cbase = is_p1 ? ccol : (ccol - dout);
    #pragma unroll
    for (int i = 0; i < 4; ++i) {
        #pragma unroll
        for (int r = 0; r < 4; ++r) {
            int gm = crow + i * 16 + r;
            if (gm >= M) continue;
            #pragma unroll
            for (int j = 0; j < 4; ++j)
                P[(size_t)gm * dout + cbase + j * 16] = f2bf_hi(acc[i][j][r]);
        }
    }
}

// ---------------- fused epilogue: h_next = bf16(leaky(mean_nbr(P1) + P2 + bias)) ----------------
// 8-deep clamped edge chunks: 8 col loads, then 8 independent row loads in flight.
template <int DOUT>
__global__ __launch_bounds__(256) void agg_post(
    const short* __restrict__ P1, const short* __restrict__ P2,
    const float* __restrict__ bias,
    const int* __restrict__ rowptr, const int* __restrict__ col,
    short* __restrict__ oh) {
    constexpr int TPN = DOUT / 8;
    constexpr int NPB = 256 / TPN;
    int node = blockIdx.x * NPB + threadIdx.x / TPN;
    if (node >= NN) return;
    int t = threadIdx.x % TPN;
    int s = rowptr[node], e = rowptr[node + 1];
    float acc[8] = {};
    for (int j0 = s; j0 < e; j0 += 8) {
        int idx[8];
        #pragma unroll
        for (int k = 0; k < 8; ++k) {
            int jj = j0 + k;
            idx[k] = col[(jj < e) ? jj : s];
        }
        bf16x8 v[8];
        #pragma unroll
        for (int k = 0; k < 8; ++k)
            v[k] = *(const bf16x8*)&P1[(size_t)idx[k] * DOUT + t * 8];
        #pragma unroll
        for (int k = 0; k < 8; ++k) {
            float msk = (j0 + k < e) ? 1.f : 0.f;
            #pragma unroll
            for (int m = 0; m < 8; ++m)
                acc[m] += msk * bf2f(v[k][m]);
        }
    }
    float inv = 1.f / fmaxf((float)(e - s), 1.f);
    bf16x8 p2 = *(const bf16x8*)&P2[(size_t)node * DOUT + t * 8];
    float4 ba = *(const float4*)&bias[t * 8];
    float4 bb = *(const float4*)&bias[t * 8 + 4];
    float bv[8] = {ba.x, ba.y, ba.z, ba.w, bb.x, bb.y, bb.z, bb.w};
    bf16x8 vh;
    #pragma unroll
    for (int m = 0; m < 8; ++m) {
        float c = acc[m] * inv + bf2f(p2[m]) + bv[m];
        c = (c >= 0.f) ? c : 0.01f * c;
        vh[m] = f2bf_hi(c);
    }
    *(bf16x8*)&oh[(size_t)node * DOUT + t * 8] = vh;
}

// ---------------- edge-parallel pooled-adjacency gather ----------------
#define ESPLIT 32
__global__ __launch_bounds__(256) void sgather(const short* __restrict__ h5,
                                               const int* __restrict__ batch,
                                               const int* __restrict__ rowptr,
                                               const int* __restrict__ col,
                                               const float* __restrict__ wgt,
                                               float* __restrict__ ap) {
    int gi = blockIdx.x, c = blockIdx.y;
    int t = threadIdx.x;   // feature
    int lo = 0, hi = NN;
    while (lo < hi) { int m = (lo + hi) >> 1; if (batch[m] < gi) lo = m + 1; else hi = m; }
    int start = lo;
    hi = NN;
    while (lo < hi) { int m = (lo + hi) >> 1; if (batch[m] < gi + 1) lo = m + 1; else hi = m; }
    int end = lo;
    int e0 = rowptr[start], e1 = rowptr[end];
    int L = e1 - e0;
    int ps = e0 + (int)(((long)L * c) / ESPLIT);
    int pe = e0 + (int)(((long)L * (c + 1)) / ESPLIT);
    float acc = 0.f;
    int p = ps;
    for (; p + 4 <= pe; p += 4) {
        int c0 = col[p], c1 = col[p + 1], c2 = col[p + 2], c3 = col[p + 3];
        float w0 = wgt[p], w1 = wgt[p + 1], w2 = wgt[p + 2], w3 = wgt[p + 3];
        float a0 = bf2f(h5[(size_t)c0 * 256 + t]);
        float a1 = bf2f(h5[(size_t)c1 * 256 + t]);
        float a2 = bf2f(h5[(size_t)c2 * 256 + t]);
        float a3 = bf2f(h5[(size_t)c3 * 256 + t]);
        acc += (w0 * a0 + w1 * a1) + (w2 * a2 + w3 * a3);
    }
    for (; p < pe; ++p)
        acc += wgt[p] * bf2f(h5[(size_t)col[p] * 256 + t]);
    if (pe > ps) atomicAdd(&ap[gi * 256 + t], acc);
}

// ---------------- per-graph mean of h5 (bf16) ----------------
#define PSPLIT 16
__global__ __launch_bounds__(256) void pool_h(const short* __restrict__ h5,
                                              const int* __restrict__ batch,
                                              float* __restrict__ hp, int* __restrict__ gcnt) {
    int gi = blockIdx.x, c = blockIdx.y;
    int t = threadIdx.x;
    int lo = 0, hi = NN;
    while (lo < hi) { int m = (lo + hi) >> 1; if (batch[m] < gi) lo = m + 1; else hi = m; }
    int start = lo;
    hi = NN;
    while (lo < hi) { int m = (lo + hi) >> 1; if (batch[m] < gi + 1) lo = m + 1; else hi = m; }
    int end = lo;
    int L = end - start;
    if (c == 0 && t == 0) gcnt[gi] = L;
    int cs = start + (int)(((long)L * c) / PSPLIT);
    int ce = start + (int)(((long)L * (c + 1)) / PSPLIT);
    float acc = 0.f;
    for (int n = cs; n < ce; ++n) acc += bf2f(h5[(size_t)n * 256 + t]);
    if (ce > cs) atomicAdd(&hp[gi * 256 + t], acc);
}

// ---------------- fused layer-6 + head (64 rows, exact f32) ----------------
__global__ __launch_bounds__(256) void head_kernel(
    const float* __restrict__ ap, const float* __restrict__ hp,
    const int* __restrict__ gcnt,
    const float* __restrict__ Wl6, const float* __restrict__ Wr6,
    const float* __restrict__ bl6,
    const float* __restrict__ Wlin, const float* __restrict__ blin,
    float* __restrict__ out) {
    __shared__ float a_s[256], h_s[256], t6[256];
    int g = blockIdx.x, t = threadIdx.x;
    float inv = 1.f / fmaxf((float)gcnt[g], 1.f);
    a_s[t] = ap[g * 256 + t] * inv;
    h_s[t] = hp[g * 256 + t] * inv;
    __syncthreads();
    float acc = 0.f;
    for (int k = 0; k < 256; ++k)
        acc += a_s[k] * Wl6[k * 256 + t] + h_s[k] * Wr6[k * 256 + t];
    t6[t] = acc + bl6[t];
    __syncthreads();
    if (t < 6) {
        float s = 0.f;
        for (int k = 0; k < 256; ++k) s += t6[k] * Wlin[k * 6 + t];
        out[g * 6 + t] = s + blin[t];
    }
}

extern "C" void kernel_launch(void* const* d_in, const int* in_sizes, int n_in,
                              void* d_out, int out_size, void* d_ws, size_t ws_size,
                              hipStream_t stream) {
    const float* x = (const float*)d_in[0];
    const int* ei = (const int*)d_in[1];
    const int* batch = (const int*)d_in[2];
    const float *Wl[6], *bl[6], *Wr[6];
    for (int l = 0; l < 6; ++l) {
        Wl[l] = (const float*)d_in[3 + 3 * l];
        bl[l] = (const float*)d_in[4 + 3 * l];
        Wr[l] = (const float*)d_in[5 + 3 * l];
    }
    const float* Wlin = (const float*)d_in[21];
    const float* blin = (const float*)d_in[22];
    float* out = (float*)d_out;

    char* ws = (char*)d_ws;
    size_t off = 0;
    auto alloc = [&](size_t bytes) {
        void* p = ws + off;
        off += (bytes + 255) & ~(size_t)255;
        return p;
    };
    short* xh   = (short*)alloc((size_t)MP * 128 * 2);
    short* hA   = (short*)alloc((size_t)MP * 512 * 2);
    short* hB   = (short*)alloc((size_t)MP * 512 * 2);
    short* P1   = (short*)alloc((size_t)MP * 512 * 2);
    short* P2   = (short*)alloc((size_t)MP * 512 * 2);
    int* col    = (int*)alloc((size_t)NE * 4);
    float* wgt  = (float*)alloc((size_t)NE * 4);
    // ---- zeroed region start ----
    float* ap   = (float*)alloc((size_t)NG * 256 * 4);
    float* hp   = (float*)alloc((size_t)NG * 256 * 4);
    int* deg    = (int*)alloc((size_t)NN * 4);
    int* wcount = (int*)alloc((size_t)NN * 4);
    int* gcnt   = (int*)alloc((size_t)NG * 4);
    // ---- zeroed region end ----
    int* rowptr = (int*)alloc((size_t)(NN + 1) * 4);
    short* wtbuf = (short*)alloc((size_t)4 * 688128 * 2);
    (void)ws_size; (void)in_sizes; (void)n_in; (void)out_size;

    size_t zero_bytes = (size_t)((char*)gcnt - (char*)ap) + NG * 4;
    hipMemsetAsync((void*)ap, 0, zero_bytes, stream);

    const int* src = ei;
    const int* dst = ei + NE;
    hist_kernel<<<(NE + 255) / 256, 256, 0, stream>>>(dst, deg);
    scan_kernel<<<1, 1024, 0, stream>>>(deg, rowptr);
    fill_kernel<<<(NE + 255) / 256, 256, 0, stream>>>(src, dst, rowptr, deg, wcount, col, wgt);
    xbf_kernel<<<(NN * 16 + 255) / 256, 256, 0, stream>>>(x, xh);

    const int dins[5]  = {128, 256, 256, 512, 512};
    const int douts[5] = {256, 256, 512, 512, 256};

    // batched weight transpose+round for layers 1-5 -> B^T = [Wl ; Wr], bf16
    short* Bth[5];
    {
        WPack pack;
        short* p = wtbuf;
        int tcum = 0;
        for (int l = 0; l < 5; ++l) {
            size_t half = (size_t)dins[l] * douts[l];
            int ntiles = (dins[l] / 32) * (douts[l] / 32);
            Bth[l] = p; p += 2 * half;
            pack.d[2 * l]     = { Wl[l], Bth[l],        dins[l], douts[l], tcum }; tcum += ntiles;
            pack.d[2 * l + 1] = { Wr[l], Bth[l] + half, dins[l], douts[l], tcum }; tcum += ntiles;
        }
        wconv_all<<<tcum, 256, 0, stream>>>(pack);
    }

    const short* cur = xh;
    short* hbuf[2] = {hA, hB};
    for (int l = 0; l < 5; ++l) {
        int K = dins[l], dout = douts[l];
        int ncol = (2 * dout) >> 7;            // 4 or 8
        int ncsh = (ncol == 4) ? 2 : 3;
        int nwg = (MP / 128) * ncol;
        gemm_mfma<<<nwg, 256, 0, stream>>>(cur, Bth[l], P1, P2, NN, K, dout, ncsh);
        if (dout == 256)
            agg_post<256><<<(NN + 7) / 8, 256, 0, stream>>>(P1, P2, bl[l], rowptr, col, hbuf[l & 1]);
        else
            agg_post<512><<<(NN + 3) / 4, 256, 0, stream>>>(P1, P2, bl[l], rowptr, col, hbuf[l & 1]);
        cur = hbuf[l & 1];
    }

    // fused layer-6 + pool + head (exact: pool commutes with the linear layer)
    dim3 egrid(NG, ESPLIT);
    sgather<<<egrid, 256, 0, stream>>>(cur, batch, rowptr, col, wgt, ap);
    dim3 pgrid(NG, PSPLIT);
    pool_h<<<pgrid, 256, 0, stream>>>(cur, batch, hp, gcnt);
    head_kernel<<<NG, 256, 0, stream>>>(ap, hp, gcnt, Wl[5], Wr[5], bl[5], Wlin, blin, out);
}

// Round 13
// 380.629 us; speedup vs baseline: 3.3320x; 1.0442x over previous
//
#include <hip/hip_runtime.h>

#define NN 20000
#define MP 20096   // NN padded to 157*128
#define NE 160000
#define NG 64

typedef __attribute__((ext_vector_type(8))) short bf16x8;
typedef __attribute__((ext_vector_type(4))) float f32x4;

__device__ __forceinline__ short f2bf_hi(float x) {
    unsigned u = __float_as_uint(x);
    return (short)((u + 0x7FFFu + ((u >> 16) & 1u)) >> 16);
}

__device__ __forceinline__ float bf2f(short h) {
    return __uint_as_float(((unsigned)(unsigned short)h) << 16);
}

typedef const __attribute__((address_space(1))) unsigned int* as1_u32p;
typedef __attribute__((address_space(3))) unsigned int* as3_u32p;
__device__ __forceinline__ void gll16(const void* g, void* l) {
    __builtin_amdgcn_global_load_lds((as1_u32p)g, (as3_u32p)l, 16, 0, 0);
}

// ---------------- merged prep: hist (atomic deg) + x->bf16 + W transpose/round ----------------
struct WDesc { const float* W; short* Wh; int K; int dout; int tstart; };
struct WPack { WDesc d[10]; };

#define HIST_BLOCKS 625          // NE/256
#define XBF_BLOCKS 1250          // NN*16/256
#define WCONV_BASE (HIST_BLOCKS + XBF_BLOCKS)

__global__ __launch_bounds__(256) void prep_kernel(WPack p,
                                                   const int* __restrict__ dst,
                                                   int* __restrict__ deg,
                                                   const float* __restrict__ x,
                                                   short* __restrict__ xh) {
    __shared__ float tile[32][33];
    int bid = blockIdx.x;
    int t = threadIdx.x;
    if (bid < HIST_BLOCKS) {
        int e = bid * 256 + t;
        atomicAdd(&deg[dst[e]], 1);
        return;
    }
    if (bid < WCONV_BASE) {
        int i = (bid - HIST_BLOCKS) * 256 + t;   // exactly NN*16 groups
        float4 a = *(const float4*)&x[(size_t)i * 8];
        float4 b = *(const float4*)&x[(size_t)i * 8 + 4];
        bf16x8 v;
        v[0] = f2bf_hi(a.x); v[1] = f2bf_hi(a.y); v[2] = f2bf_hi(a.z); v[3] = f2bf_hi(a.w);
        v[4] = f2bf_hi(b.x); v[5] = f2bf_hi(b.y); v[6] = f2bf_hi(b.z); v[7] = f2bf_hi(b.w);
        *(bf16x8*)&xh[(size_t)i * 8] = v;
        return;
    }
    int wb = bid - WCONV_BASE;
    int i = 0;
    #pragma unroll
    for (int k = 1; k < 10; ++k)
        if (wb >= p.d[k].tstart) i = k;
    const float* W = p.d[i].W;
    short* Wh = p.d[i].Wh;
    int K = p.d[i].K, dout = p.d[i].dout;
    int local = wb - p.d[i].tstart;
    int ntk = K >> 5;
    int kb = (local % ntk) * 32, nb = (local / ntk) * 32;
    int lr = t >> 5, lc = t & 31;
    #pragma unroll
    for (int r = 0; r < 4; ++r)
        tile[lr + r * 8][lc] = W[(size_t)(kb + lr + r * 8) * dout + nb + lc];
    __syncthreads();
    int nn = t >> 3, kq = (t & 7) * 4;
    short4 h;
    h.x = f2bf_hi(tile[kq + 0][nn]);
    h.y = f2bf_hi(tile[kq + 1][nn]);
    h.z = f2bf_hi(tile[kq + 2][nn]);
    h.w = f2bf_hi(tile[kq + 3][nn]);
    *(short4*)&Wh[(size_t)(nb + nn) * K + kb + kq] = h;
}

// ---------------- parallel 3-pass exclusive scan of deg -> rowptr ----------------
#define SCAN_BLOCKS 20           // ceil(NN/1024)

__global__ void scan_part(const int* __restrict__ deg, int* __restrict__ bsum) {
    __shared__ int wsum[16];
    int b = blockIdx.x, t = threadIdx.x;
    int i = b * 1024 + t;
    int v = (i < NN) ? deg[i] : 0;
    int lane = t & 63, w = t >> 6;
    int s = v;
    #pragma unroll
    for (int off = 1; off < 64; off <<= 1) s += __shfl_xor(s, off, 64);
    if (lane == 0) wsum[w] = s;
    __syncthreads();
    if (t == 0) {
        int tot = 0;
        #pragma unroll
        for (int k = 0; k < 16; ++k) tot += wsum[k];
        bsum[b] = tot;
    }
}

__global__ void scan_mid(const int* __restrict__ bsum, int* __restrict__ boff,
                         int* __restrict__ rowptr) {
    int t = threadIdx.x;   // 64
    int v = (t < SCAN_BLOCKS) ? bsum[t] : 0;
    int s = v;
    #pragma unroll
    for (int off = 1; off < 64; off <<= 1) {
        int u = __shfl_up(s, off, 64);
        if (t >= off) s += u;
    }
    if (t < SCAN_BLOCKS) boff[t] = s - v;
    if (t == SCAN_BLOCKS - 1) rowptr[NN] = s;
}

__global__ void scan_fin(const int* __restrict__ deg, const int* __restrict__ boff,
                         int* __restrict__ rowptr) {
    __shared__ int wsum[16];
    int b = blockIdx.x, t = threadIdx.x;
    int i = b * 1024 + t;
    int v = (i < NN) ? deg[i] : 0;
    int lane = t & 63, w = t >> 6;
    int s = v;
    #pragma unroll
    for (int off = 1; off < 64; off <<= 1) {
        int u = __shfl_up(s, off, 64);
        if (lane >= off) s += u;
    }
    if (lane == 63) wsum[w] = s;
    __syncthreads();
    if (w == 0 && lane < 16) {
        int ws = wsum[lane];
        #pragma unroll
        for (int off = 1; off < 16; off <<= 1) {
            int u = __shfl_up(ws, off, 64);
            if (lane >= off) ws += u;
        }
        wsum[lane] = ws;
    }
    __syncthreads();
    int wpre = (w > 0) ? wsum[w - 1] : 0;
    if (i < NN) rowptr[i] = boff[b] + wpre + s - v;
}

// also writes per-CSR-position pool weight wgt[p] = 1/max(deg[dst],1)
__global__ void fill_kernel(const int* __restrict__ src, const int* __restrict__ dst,
                            const int* __restrict__ rowptr, const int* __restrict__ deg,
                            int* __restrict__ wcount, int* __restrict__ col,
                            float* __restrict__ wgt) {
    int e = blockIdx.x * 256 + threadIdx.x;
    if (e < NE) {
        int d = dst[e];
        int p = rowptr[d] + atomicAdd(&wcount[d], 1);
        col[p] = src[e];
        wgt[p] = 1.f / fmaxf((float)deg[d], 1.f);
    }
}

// ---------------- single-A single-B GEMM: [P1|P2] = h_bf16 @ W_bf16 ----------------
// 128x128 tile, 4 waves 2x2, counted-vmcnt 2-deep pipeline, bijective XCD swizzle.
__global__ __launch_bounds__(256, 4) void gemm_mfma(
    const short* __restrict__ A,
    const short* __restrict__ Bh,                                 // [2*dout][K] bf16
    short* __restrict__ P1, short* __restrict__ P2,
    int M, int K, int dout, int ncsh) {
    __shared__ short lds[2][2][4096];   // [dbuf][A,B][128*32]
    int tid = threadIdx.x;
    int lane = tid & 63, w = tid >> 6;
    int wm = w >> 1, wn = w & 1;

    // bijective XCD swizzle (m204), panel-major work ids
    int nwg = gridDim.x;
    int q = nwg >> 3, r = nwg & 7;
    int xcd = blockIdx.x & 7, idx = blockIdx.x >> 3;
    int swz = (xcd < r ? xcd * (q + 1) : r * (q + 1) + (xcd - r) * q) + idx;
    int mblk = (swz >> ncsh) << 7;
    int nblk = (swz & ((1 << ncsh) - 1)) << 7;

    int rl = lane >> 2;                              // staging: row within 16-row DMA
    int gchunk = (lane & 3) ^ ((lane >> 3) & 3);     // pre-swizzled source chunk
    int nsteps = K >> 5;

    auto stage = [&](int b, int t) {
        int kc = t << 5;
        short* L = &lds[b][0][0];
        size_t ko = (size_t)kc + gchunk * 8;
        #pragma unroll
        for (int qq = 0; qq < 2; ++qq) {
            int row = w * 32 + qq * 16;
            int gr = row + rl;
            gll16(A  + (size_t)(mblk + gr) * K + ko, L + 0 * 4096 + row * 32);
            gll16(Bh + (size_t)(nblk + gr) * K + ko, L + 1 * 4096 + row * 32);
        }
    };

    f32x4 acc[4][4] = {};
    int chunk_sw = (((lane >> 4) ^ ((lane >> 1) & 3))) << 3;  // swizzled read offset (shorts)
    int ar = (wm << 6) + (lane & 15);
    int br = (wn << 6) + (lane & 15);

    stage(0, 0);
    stage(1, 1);
    for (int t = 0; t < nsteps; ++t) {
        int b = t & 1;
        if (t < nsteps - 1) asm volatile("s_waitcnt vmcnt(4)" ::: "memory");
        else                asm volatile("s_waitcnt vmcnt(0)" ::: "memory");
        __builtin_amdgcn_s_barrier();          // tile t landed on all waves
        __builtin_amdgcn_sched_barrier(0);
        const short* L = &lds[b][0][0];
        bf16x8 av[4], bv[4];
        #pragma unroll
        for (int i = 0; i < 4; ++i) {
            av[i] = *(const bf16x8*)(L + 0 * 4096 + (ar + i * 16) * 32 + chunk_sw);
            bv[i] = *(const bf16x8*)(L + 1 * 4096 + (br + i * 16) * 32 + chunk_sw);
        }
        #pragma unroll
        for (int i = 0; i < 4; ++i)
            #pragma unroll
            for (int j = 0; j < 4; ++j)
                acc[i][j] = __builtin_amdgcn_mfma_f32_16x16x32_bf16(av[i], bv[j], acc[i][j], 0, 0, 0);
        __builtin_amdgcn_sched_barrier(0);
        __builtin_amdgcn_s_barrier();          // all waves done reading buffer b
        __builtin_amdgcn_sched_barrier(0);
        if (t + 2 < nsteps) stage(b, t + 2);   // overwrite b for step t+2 (WAR-safe)
    }

    // epilogue: C/D layout col=lane&15, row=(lane>>4)*4+reg
    int crow = mblk + (wm << 6) + ((lane >> 4) << 2);
    int ccol = nblk + (wn << 6) + (lane & 15);
    bool is_p1 = (nblk < dout);   // 128-wide n-block lies entirely in one half
    short* P = is_p1 ? P1 : P2;
    int cbase = is_p1 ? ccol : (ccol - dout);
    #pragma unroll
    for (int i = 0; i < 4; ++i) {
        #pragma unroll
        for (int r = 0; r < 4; ++r) {
            int gm = crow + i * 16 + r;
            if (gm >= M) continue;
            #pragma unroll
            for (int j = 0; j < 4; ++j)
                P[(size_t)gm * dout + cbase + j * 16] = f2bf_hi(acc[i][j][r]);
        }
    }
}

// ---------------- fused epilogue: h_next = bf16(leaky(mean_nbr(P1) + P2 + bias)) ----------------
// 8-deep clamped edge chunks: 8 col loads, then 8 independent row loads in flight.
template <int DOUT>
__global__ __launch_bounds__(256) void agg_post(
    const short* __restrict__ P1, const short* __restrict__ P2,
    const float* __restrict__ bias,
    const int* __restrict__ rowptr, const int* __restrict__ col,
    short* __restrict__ oh) {
    constexpr int TPN = DOUT / 8;
    constexpr int NPB = 256 / TPN;
    int node = blockIdx.x * NPB + threadIdx.x / TPN;
    if (node >= NN) return;
    int t = threadIdx.x % TPN;
    int s = rowptr[node], e = rowptr[node + 1];
    float acc[8] = {};
    for (int j0 = s; j0 < e; j0 += 8) {
        int idx[8];
        #pragma unroll
        for (int k = 0; k < 8; ++k) {
            int jj = j0 + k;
            idx[k] = col[(jj < e) ? jj : s];
        }
        bf16x8 v[8];
        #pragma unroll
        for (int k = 0; k < 8; ++k)
            v[k] = *(const bf16x8*)&P1[(size_t)idx[k] * DOUT + t * 8];
        #pragma unroll
        for (int k = 0; k < 8; ++k) {
            float msk = (j0 + k < e) ? 1.f : 0.f;
            #pragma unroll
            for (int m = 0; m < 8; ++m)
                acc[m] += msk * bf2f(v[k][m]);
        }
    }
    float inv = 1.f / fmaxf((float)(e - s), 1.f);
    bf16x8 p2 = *(const bf16x8*)&P2[(size_t)node * DOUT + t * 8];
    float4 ba = *(const float4*)&bias[t * 8];
    float4 bb = *(const float4*)&bias[t * 8 + 4];
    float bv[8] = {ba.x, ba.y, ba.z, ba.w, bb.x, bb.y, bb.z, bb.w};
    bf16x8 vh;
    #pragma unroll
    for (int m = 0; m < 8; ++m) {
        float c = acc[m] * inv + bf2f(p2[m]) + bv[m];
        c = (c >= 0.f) ? c : 0.01f * c;
        vh[m] = f2bf_hi(c);
    }
    *(bf16x8*)&oh[(size_t)node * DOUT + t * 8] = vh;
}

// ---------------- edge-parallel pooled-adjacency gather ----------------
#define ESPLIT 32
__global__ __launch_bounds__(256) void sgather(const short* __restrict__ h5,
                                               const int* __restrict__ batch,
                                               const int* __restrict__ rowptr,
                                               const int* __restrict__ col,
                                               const float* __restrict__ wgt,
                                               float* __restrict__ ap) {
    int gi = blockIdx.x, c = blockIdx.y;
    int t = threadIdx.x;   // feature
    int lo = 0, hi = NN;
    while (lo < hi) { int m = (lo + hi) >> 1; if (batch[m] < gi) lo = m + 1; else hi = m; }
    int start = lo;
    hi = NN;
    while (lo < hi) { int m = (lo + hi) >> 1; if (batch[m] < gi + 1) lo = m + 1; else hi = m; }
    int end = lo;
    int e0 = rowptr[start], e1 = rowptr[end];
    int L = e1 - e0;
    int ps = e0 + (int)(((long)L * c) / ESPLIT);
    int pe = e0 + (int)(((long)L * (c + 1)) / ESPLIT);
    float acc = 0.f;
    int p = ps;
    for (; p + 4 <= pe; p += 4) {
        int c0 = col[p], c1 = col[p + 1], c2 = col[p + 2], c3 = col[p + 3];
        float w0 = wgt[p], w1 = wgt[p + 1], w2 = wgt[p + 2], w3 = wgt[p + 3];
        float a0 = bf2f(h5[(size_t)c0 * 256 + t]);
        float a1 = bf2f(h5[(size_t)c1 * 256 + t]);
        float a2 = bf2f(h5[(size_t)c2 * 256 + t]);
        float a3 = bf2f(h5[(size_t)c3 * 256 + t]);
        acc += (w0 * a0 + w1 * a1) + (w2 * a2 + w3 * a3);
    }
    for (; p < pe; ++p)
        acc += wgt[p] * bf2f(h5[(size_t)col[p] * 256 + t]);
    if (pe > ps) atomicAdd(&ap[gi * 256 + t], acc);
}

// ---------------- per-graph mean of h5 (bf16) ----------------
#define PSPLIT 16
__global__ __launch_bounds__(256) void pool_h(const short* __restrict__ h5,
                                              const int* __restrict__ batch,
                                              float* __restrict__ hp, int* __restrict__ gcnt) {
    int gi = blockIdx.x, c = blockIdx.y;
    int t = threadIdx.x;
    int lo = 0, hi = NN;
    while (lo < hi) { int m = (lo + hi) >> 1; if (batch[m] < gi) lo = m + 1; else hi = m; }
    int start = lo;
    hi = NN;
    while (lo < hi) { int m = (lo + hi) >> 1; if (batch[m] < gi + 1) lo = m + 1; else hi = m; }
    int end = lo;
    int L = end - start;
    if (c == 0 && t == 0) gcnt[gi] = L;
    int cs = start + (int)(((long)L * c) / PSPLIT);
    int ce = start + (int)(((long)L * (c + 1)) / PSPLIT);
    float acc = 0.f;
    for (int n = cs; n < ce; ++n) acc += bf2f(h5[(size_t)n * 256 + t]);
    if (ce > cs) atomicAdd(&hp[gi * 256 + t], acc);
}

// ---------------- fused layer-6 + head (64 rows, exact f32) ----------------
__global__ __launch_bounds__(256) void head_kernel(
    const float* __restrict__ ap, const float* __restrict__ hp,
    const int* __restrict__ gcnt,
    const float* __restrict__ Wl6, const float* __restrict__ Wr6,
    const float* __restrict__ bl6,
    const float* __restrict__ Wlin, const float* __restrict__ blin,
    float* __restrict__ out) {
    __shared__ float a_s[256], h_s[256], t6[256];
    int g = blockIdx.x, t = threadIdx.x;
    float inv = 1.f / fmaxf((float)gcnt[g], 1.f);
    a_s[t] = ap[g * 256 + t] * inv;
    h_s[t] = hp[g * 256 + t] * inv;
    __syncthreads();
    float acc = 0.f;
    for (int k = 0; k < 256; ++k)
        acc += a_s[k] * Wl6[k * 256 + t] + h_s[k] * Wr6[k * 256 + t];
    t6[t] = acc + bl6[t];
    __syncthreads();
    if (t < 6) {
        float s = 0.f;
        for (int k = 0; k < 256; ++k) s += t6[k] * Wlin[k * 6 + t];
        out[g * 6 + t] = s + blin[t];
    }
}

extern "C" void kernel_launch(void* const* d_in, const int* in_sizes, int n_in,
                              void* d_out, int out_size, void* d_ws, size_t ws_size,
                              hipStream_t stream) {
    const float* x = (const float*)d_in[0];
    const int* ei = (const int*)d_in[1];
    const int* batch = (const int*)d_in[2];
    const float *Wl[6], *bl[6], *Wr[6];
    for (int l = 0; l < 6; ++l) {
        Wl[l] = (const float*)d_in[3 + 3 * l];
        bl[l] = (const float*)d_in[4 + 3 * l];
        Wr[l] = (const float*)d_in[5 + 3 * l];
    }
    const float* Wlin = (const float*)d_in[21];
    const float* blin = (const float*)d_in[22];
    float* out = (float*)d_out;

    char* ws = (char*)d_ws;
    size_t off = 0;
    auto alloc = [&](size_t bytes) {
        void* p = ws + off;
        off += (bytes + 255) & ~(size_t)255;
        return p;
    };
    short* xh   = (short*)alloc((size_t)MP * 128 * 2);
    short* hA   = (short*)alloc((size_t)MP * 512 * 2);
    short* hB   = (short*)alloc((size_t)MP * 512 * 2);
    short* P1   = (short*)alloc((size_t)MP * 512 * 2);
    short* P2   = (short*)alloc((size_t)MP * 512 * 2);
    int* col    = (int*)alloc((size_t)NE * 4);
    float* wgt  = (float*)alloc((size_t)NE * 4);
    int* bsum   = (int*)alloc(64 * 4);
    int* boff   = (int*)alloc(64 * 4);
    // ---- zeroed region start ----
    float* ap   = (float*)alloc((size_t)NG * 256 * 4);
    float* hp   = (float*)alloc((size_t)NG * 256 * 4);
    int* deg    = (int*)alloc((size_t)NN * 4);
    int* wcount = (int*)alloc((size_t)NN * 4);
    int* gcnt   = (int*)alloc((size_t)NG * 4);
    // ---- zeroed region end ----
    int* rowptr = (int*)alloc((size_t)(NN + 1) * 4);
    short* wtbuf = (short*)alloc((size_t)4 * 688128 * 2);
    (void)ws_size; (void)in_sizes; (void)n_in; (void)out_size;

    size_t zero_bytes = (size_t)((char*)gcnt - (char*)ap) + NG * 4;
    hipMemsetAsync((void*)ap, 0, zero_bytes, stream);

    const int* src = ei;
    const int* dst = ei + NE;

    const int dins[5]  = {128, 256, 256, 512, 512};
    const int douts[5] = {256, 256, 512, 512, 256};

    // merged prep: hist + xbf + wconv in one launch
    short* Bth[5];
    int tcum = 0;
    {
        WPack pack;
        short* p = wtbuf;
        for (int l = 0; l < 5; ++l) {
            size_t half = (size_t)dins[l] * douts[l];
            int ntiles = (dins[l] / 32) * (douts[l] / 32);
            Bth[l] = p; p += 2 * half;
            pack.d[2 * l]     = { Wl[l], Bth[l],        dins[l], douts[l], tcum }; tcum += ntiles;
            pack.d[2 * l + 1] = { Wr[l], Bth[l] + half, dins[l], douts[l], tcum }; tcum += ntiles;
        }
        prep_kernel<<<WCONV_BASE + tcum, 256, 0, stream>>>(pack, dst, deg, x, xh);
    }

    // parallel 3-pass scan: deg -> rowptr
    scan_part<<<SCAN_BLOCKS, 1024, 0, stream>>>(deg, bsum);
    scan_mid<<<1, 64, 0, stream>>>(bsum, boff, rowptr);
    scan_fin<<<SCAN_BLOCKS, 1024, 0, stream>>>(deg, boff, rowptr);
    fill_kernel<<<(NE + 255) / 256, 256, 0, stream>>>(src, dst, rowptr, deg, wcount, col, wgt);

    const short* cur = xh;
    short* hbuf[2] = {hA, hB};
    for (int l = 0; l < 5; ++l) {
        int K = dins[l], dout = douts[l];
        int ncol = (2 * dout) >> 7;            // 4 or 8
        int ncsh = (ncol == 4) ? 2 : 3;
        int nwg = (MP / 128) * ncol;
        gemm_mfma<<<nwg, 256, 0, stream>>>(cur, Bth[l], P1, P2, NN, K, dout, ncsh);
        if (dout == 256)
            agg_post<256><<<(NN + 7) / 8, 256, 0, stream>>>(P1, P2, bl[l], rowptr, col, hbuf[l & 1]);
        else
            agg_post<512><<<(NN + 3) / 4, 256, 0, stream>>>(P1, P2, bl[l], rowptr, col, hbuf[l & 1]);
        cur = hbuf[l & 1];
    }

    // fused layer-6 + pool + head (exact: pool commutes with the linear layer)
    dim3 egrid(NG, ESPLIT);
    sgather<<<egrid, 256, 0, stream>>>(cur, batch, rowptr, col, wgt, ap);
    dim3 pgrid(NG, PSPLIT);
    pool_h<<<pgrid, 256, 0, stream>>>(cur, batch, hp, gcnt);
    head_kernel<<<NG, 256, 0, stream>>>(ap, hp, gcnt, Wl[5], Wr[5], bl[5], Wlin, blin, out);
}

// Round 15
// 346.257 us; speedup vs baseline: 3.6627x; 1.0993x over previous
//
#include <hip/hip_runtime.h>

#define NN 20000
#define MP 20096   // NN padded to 157*128
#define NE 160000
#define NG 64

typedef __attribute__((ext_vector_type(8))) short bf16x8;
typedef __attribute__((ext_vector_type(4))) float f32x4;

__device__ __forceinline__ short f2bf_hi(float x) {
    unsigned u = __float_as_uint(x);
    return (short)((u + 0x7FFFu + ((u >> 16) & 1u)) >> 16);
}

__device__ __forceinline__ float bf2f(short h) {
    return __uint_as_float(((unsigned)(unsigned short)h) << 16);
}

typedef const __attribute__((address_space(1))) unsigned int* as1_u32p;
typedef __attribute__((address_space(3))) unsigned int* as3_u32p;
__device__ __forceinline__ void gll16(const void* g, void* l) {
    __builtin_amdgcn_global_load_lds((as1_u32p)g, (as3_u32p)l, 16, 0, 0);
}

// ---------------- merged prep: hist (atomic deg) + x->bf16 + W transpose/round ----------------
// WDesc writes W^T tile into Wh[(n)*Kst + koff + k] -> supports K-concat ([Wl|Wr] along K)
// and row-stacked ([Wl;Wr] via base-pointer row offset) layouts.
struct WDesc { const float* W; short* Wh; int Kst; int koff; int K; int dout; int tstart; };
struct WPack { WDesc d[10]; };

#define HIST_BLOCKS 625          // NE/256
#define XBF_BLOCKS 1250          // NN*16/256
#define WCONV_BASE (HIST_BLOCKS + XBF_BLOCKS)

__global__ __launch_bounds__(256) void prep_kernel(WPack p,
                                                   const int* __restrict__ dst,
                                                   int* __restrict__ deg,
                                                   const float* __restrict__ x,
                                                   short* __restrict__ xh) {
    __shared__ float tile[32][33];
    int bid = blockIdx.x;
    int t = threadIdx.x;
    if (bid < HIST_BLOCKS) {
        int e = bid * 256 + t;
        atomicAdd(&deg[dst[e]], 1);
        return;
    }
    if (bid < WCONV_BASE) {
        int i = (bid - HIST_BLOCKS) * 256 + t;   // exactly NN*16 groups
        float4 a = *(const float4*)&x[(size_t)i * 8];
        float4 b = *(const float4*)&x[(size_t)i * 8 + 4];
        bf16x8 v;
        v[0] = f2bf_hi(a.x); v[1] = f2bf_hi(a.y); v[2] = f2bf_hi(a.z); v[3] = f2bf_hi(a.w);
        v[4] = f2bf_hi(b.x); v[5] = f2bf_hi(b.y); v[6] = f2bf_hi(b.z); v[7] = f2bf_hi(b.w);
        *(bf16x8*)&xh[(size_t)i * 8] = v;
        return;
    }
    int wb = bid - WCONV_BASE;
    int i = 0;
    #pragma unroll
    for (int k = 1; k < 10; ++k)
        if (wb >= p.d[k].tstart) i = k;
    const float* W = p.d[i].W;
    short* Wh = p.d[i].Wh;
    int Kst = p.d[i].Kst, koff = p.d[i].koff;
    int K = p.d[i].K, dout = p.d[i].dout;
    int local = wb - p.d[i].tstart;
    int ntk = K >> 5;
    int kb = (local % ntk) * 32, nb = (local / ntk) * 32;
    int lr = t >> 5, lc = t & 31;
    #pragma unroll
    for (int r = 0; r < 4; ++r)
        tile[lr + r * 8][lc] = W[(size_t)(kb + lr + r * 8) * dout + nb + lc];
    __syncthreads();
    int nn = t >> 3, kq = (t & 7) * 4;
    short4 h;
    h.x = f2bf_hi(tile[kq + 0][nn]);
    h.y = f2bf_hi(tile[kq + 1][nn]);
    h.z = f2bf_hi(tile[kq + 2][nn]);
    h.w = f2bf_hi(tile[kq + 3][nn]);
    *(short4*)&Wh[(size_t)(nb + nn) * Kst + koff + kb + kq] = h;
}

// ---------------- parallel 3-pass exclusive scan of deg -> rowptr ----------------
#define SCAN_BLOCKS 20           // ceil(NN/1024)

__global__ void scan_part(const int* __restrict__ deg, int* __restrict__ bsum) {
    __shared__ int wsum[16];
    int b = blockIdx.x, t = threadIdx.x;
    int i = b * 1024 + t;
    int v = (i < NN) ? deg[i] : 0;
    int lane = t & 63, w = t >> 6;
    int s = v;
    #pragma unroll
    for (int off = 1; off < 64; off <<= 1) s += __shfl_xor(s, off, 64);
    if (lane == 0) wsum[w] = s;
    __syncthreads();
    if (t == 0) {
        int tot = 0;
        #pragma unroll
        for (int k = 0; k < 16; ++k) tot += wsum[k];
        bsum[b] = tot;
    }
}

__global__ void scan_mid(const int* __restrict__ bsum, int* __restrict__ boff,
                         int* __restrict__ rowptr) {
    int t = threadIdx.x;   // 64
    int v = (t < SCAN_BLOCKS) ? bsum[t] : 0;
    int s = v;
    #pragma unroll
    for (int off = 1; off < 64; off <<= 1) {
        int u = __shfl_up(s, off, 64);
        if (t >= off) s += u;
    }
    if (t < SCAN_BLOCKS) boff[t] = s - v;
    if (t == SCAN_BLOCKS - 1) rowptr[NN] = s;
}

__global__ void scan_fin(const int* __restrict__ deg, const int* __restrict__ boff,
                         int* __restrict__ rowptr) {
    __shared__ int wsum[16];
    int b = blockIdx.x, t = threadIdx.x;
    int i = b * 1024 + t;
    int v = (i < NN) ? deg[i] : 0;
    int lane = t & 63, w = t >> 6;
    int s = v;
    #pragma unroll
    for (int off = 1; off < 64; off <<= 1) {
        int u = __shfl_up(s, off, 64);
        if (lane >= off) s += u;
    }
    if (lane == 63) wsum[w] = s;
    __syncthreads();
    if (w == 0 && lane < 16) {
        int ws = wsum[lane];
        #pragma unroll
        for (int off = 1; off < 16; off <<= 1) {
            int u = __shfl_up(ws, off, 64);
            if (lane >= off) ws += u;
        }
        wsum[lane] = ws;
    }
    __syncthreads();
    int wpre = (w > 0) ? wsum[w - 1] : 0;
    if (i < NN) rowptr[i] = boff[b] + wpre + s - v;
}

// also writes per-CSR-position pool weight wgt[p] = 1/max(deg[dst],1)
__global__ void fill_kernel(const int* __restrict__ src, const int* __restrict__ dst,
                            const int* __restrict__ rowptr, const int* __restrict__ deg,
                            int* __restrict__ wcount, int* __restrict__ col,
                            float* __restrict__ wgt) {
    int e = blockIdx.x * 256 + threadIdx.x;
    if (e < NE) {
        int d = dst[e];
        int p = rowptr[d] + atomicAdd(&wcount[d], 1);
        col[p] = src[e];
        wgt[p] = 1.f / fmaxf((float)deg[d], 1.f);
    }
}

// ---------------- mean aggregation: agg = bf16(mean_nbr(h)), 8-deep clamped gather ----------------
template <int K>
__global__ __launch_bounds__(256) void agg_mean(
    const short* __restrict__ h, const int* __restrict__ rowptr,
    const int* __restrict__ col, short* __restrict__ agg) {
    constexpr int TPN = K / 8;
    constexpr int NPB = 256 / TPN;
    int node = blockIdx.x * NPB + threadIdx.x / TPN;
    if (node >= NN) return;
    int t = threadIdx.x % TPN;
    int s = rowptr[node], e = rowptr[node + 1];
    float acc[8] = {};
    for (int j0 = s; j0 < e; j0 += 8) {
        int idx[8];
        #pragma unroll
        for (int k = 0; k < 8; ++k) {
            int jj = j0 + k;
            idx[k] = col[(jj < e) ? jj : s];
        }
        bf16x8 v[8];
        #pragma unroll
        for (int k = 0; k < 8; ++k)
            v[k] = *(const bf16x8*)&h[(size_t)idx[k] * K + t * 8];
        #pragma unroll
        for (int k = 0; k < 8; ++k) {
            float msk = (j0 + k < e) ? 1.f : 0.f;
            #pragma unroll
            for (int m = 0; m < 8; ++m)
                acc[m] += msk * bf2f(v[k][m]);
        }
    }
    float inv = 1.f / fmaxf((float)(e - s), 1.f);
    bf16x8 vh;
    #pragma unroll
    for (int m = 0; m < 8; ++m) vh[m] = f2bf_hi(acc[m] * inv);
    *(bf16x8*)&agg[(size_t)node * K + t * 8] = vh;
}

// ---------------- agg-first GEMM: h_next = bf16(leaky([agg|h] @ [Wl;Wr] + bias)) ----------------
// A = K-concat of agg (first K) and h (second K); Bt = [dout][2K] bf16.
__global__ __launch_bounds__(256, 4) void gemm_af(
    const short* __restrict__ A1, const short* __restrict__ A2,
    const short* __restrict__ Bt, const float* __restrict__ bias,
    short* __restrict__ H, int M, int K, int dout, int ncsh) {
    __shared__ short lds[2][2][4096];
    int tid = threadIdx.x;
    int lane = tid & 63, w = tid >> 6;
    int wm = w >> 1, wn = w & 1;

    int nwg = gridDim.x;
    int q = nwg >> 3, r = nwg & 7;
    int xcd = blockIdx.x & 7, idx = blockIdx.x >> 3;
    int swz = (xcd < r ? xcd * (q + 1) : r * (q + 1) + (xcd - r) * q) + idx;
    int mblk = (swz >> ncsh) << 7;
    int nblk = (swz & ((1 << ncsh) - 1)) << 7;

    int rl = lane >> 2;
    int gchunk = (lane & 3) ^ ((lane >> 3) & 3);
    int KK = K << 1;
    int s1 = K >> 5;
    int nsteps = KK >> 5;

    auto stage = [&](int b, int t) {
        const short* A; int kc;
        if (t < s1) { A = A1; kc = t << 5; }
        else        { A = A2; kc = (t - s1) << 5; }
        short* L = &lds[b][0][0];
        size_t koA = (size_t)kc + gchunk * 8;
        size_t koB = (size_t)(t << 5) + gchunk * 8;
        #pragma unroll
        for (int qq = 0; qq < 2; ++qq) {
            int row = w * 32 + qq * 16;
            int gr = row + rl;
            gll16(A  + (size_t)(mblk + gr) * K  + koA, L + 0 * 4096 + row * 32);
            gll16(Bt + (size_t)(nblk + gr) * KK + koB, L + 1 * 4096 + row * 32);
        }
    };

    f32x4 acc[4][4] = {};
    int chunk_sw = (((lane >> 4) ^ ((lane >> 1) & 3))) << 3;
    int ar = (wm << 6) + (lane & 15);
    int br = (wn << 6) + (lane & 15);
    int ccol = nblk + (wn << 6) + (lane & 15);

    // bias preload + materialize so loop vmcnt counts stay exact
    float bv0 = bias[ccol], bv1 = bias[ccol + 16], bv2 = bias[ccol + 32], bv3 = bias[ccol + 48];
    asm volatile("" : "+v"(bv0), "+v"(bv1), "+v"(bv2), "+v"(bv3));

    stage(0, 0);
    stage(1, 1);
    for (int t = 0; t < nsteps; ++t) {
        int b = t & 1;
        if (t < nsteps - 1) asm volatile("s_waitcnt vmcnt(4)" ::: "memory");
        else                asm volatile("s_waitcnt vmcnt(0)" ::: "memory");
        __builtin_amdgcn_s_barrier();
        __builtin_amdgcn_sched_barrier(0);
        const short* L = &lds[b][0][0];
        bf16x8 av[4], bv[4];
        #pragma unroll
        for (int i = 0; i < 4; ++i) {
            av[i] = *(const bf16x8*)(L + 0 * 4096 + (ar + i * 16) * 32 + chunk_sw);
            bv[i] = *(const bf16x8*)(L + 1 * 4096 + (br + i * 16) * 32 + chunk_sw);
        }
        #pragma unroll
        for (int i = 0; i < 4; ++i)
            #pragma unroll
            for (int j = 0; j < 4; ++j)
                acc[i][j] = __builtin_amdgcn_mfma_f32_16x16x32_bf16(av[i], bv[j], acc[i][j], 0, 0, 0);
        __builtin_amdgcn_sched_barrier(0);
        __builtin_amdgcn_s_barrier();
        __builtin_amdgcn_sched_barrier(0);
        if (t + 2 < nsteps) stage(b, t + 2);
    }

    int crow = mblk + (wm << 6) + ((lane >> 4) << 2);
    float bvv[4] = {bv0, bv1, bv2, bv3};
    #pragma unroll
    for (int i = 0; i < 4; ++i) {
        #pragma unroll
        for (int r = 0; r < 4; ++r) {
            int gm = crow + i * 16 + r;
            if (gm >= M) continue;
            #pragma unroll
            for (int j = 0; j < 4; ++j) {
                float c = acc[i][j][r] + bvv[j];
                c = (c >= 0.f) ? c : 0.01f * c;
                H[(size_t)gm * dout + ccol + j * 16] = f2bf_hi(c);
            }
        }
    }
}

// ---------------- GEMM-first (L5): [P1|P2] = h @ [Wl|Wr], Bt = [2*dout][K] ----------------
__global__ __launch_bounds__(256, 4) void gemm_gf(
    const short* __restrict__ A,
    const short* __restrict__ Bh,
    short* __restrict__ P1, short* __restrict__ P2,
    int M, int K, int dout, int ncsh) {
    __shared__ short lds[2][2][4096];
    int tid = threadIdx.x;
    int lane = tid & 63, w = tid >> 6;
    int wm = w >> 1, wn = w & 1;

    int nwg = gridDim.x;
    int q = nwg >> 3, r = nwg & 7;
    int xcd = blockIdx.x & 7, idx = blockIdx.x >> 3;
    int swz = (xcd < r ? xcd * (q + 1) : r * (q + 1) + (xcd - r) * q) + idx;
    int mblk = (swz >> ncsh) << 7;
    int nblk = (swz & ((1 << ncsh) - 1)) << 7;

    int rl = lane >> 2;
    int gchunk = (lane & 3) ^ ((lane >> 3) & 3);
    int nsteps = K >> 5;

    auto stage = [&](int b, int t) {
        int kc = t << 5;
        short* L = &lds[b][0][0];
        size_t ko = (size_t)kc + gchunk * 8;
        #pragma unroll
        for (int qq = 0; qq < 2; ++qq) {
            int row = w * 32 + qq * 16;
            int gr = row + rl;
            gll16(A  + (size_t)(mblk + gr) * K + ko, L + 0 * 4096 + row * 32);
            gll16(Bh + (size_t)(nblk + gr) * K + ko, L + 1 * 4096 + row * 32);
        }
    };

    f32x4 acc[4][4] = {};
    int chunk_sw = (((lane >> 4) ^ ((lane >> 1) & 3))) << 3;
    int ar = (wm << 6) + (lane & 15);
    int br = (wn << 6) + (lane & 15);

    stage(0, 0);
    stage(1, 1);
    for (int t = 0; t < nsteps; ++t) {
        int b = t & 1;
        if (t < nsteps - 1) asm volatile("s_waitcnt vmcnt(4)" ::: "memory");
        else                asm volatile("s_waitcnt vmcnt(0)" ::: "memory");
        __builtin_amdgcn_s_barrier();
        __builtin_amdgcn_sched_barrier(0);
        const short* L = &lds[b][0][0];
        bf16x8 av[4], bv[4];
        #pragma unroll
        for (int i = 0; i < 4; ++i) {
            av[i] = *(const bf16x8*)(L + 0 * 4096 + (ar + i * 16) * 32 + chunk_sw);
            bv[i] = *(const bf16x8*)(L + 1 * 4096 + (br + i * 16) * 32 + chunk_sw);
        }
        #pragma unroll
        for (int i = 0; i < 4; ++i)
            #pragma unroll
            for (int j = 0; j < 4; ++j)
                acc[i][j] = __builtin_amdgcn_mfma_f32_16x16x32_bf16(av[i], bv[j], acc[i][j], 0, 0, 0);
        __builtin_amdgcn_sched_barrier(0);
        __builtin_amdgcn_s_barrier();
        __builtin_amdgcn_sched_barrier(0);
        if (t + 2 < nsteps) stage(b, t + 2);
    }

    int crow = mblk + (wm << 6) + ((lane >> 4) << 2);
    int ccol = nblk + (wn << 6) + (lane & 15);
    bool is_p1 = (nblk < dout);
    short* P = is_p1 ? P1 : P2;
    int cbase = is_p1 ? ccol : (ccol - dout);
    #pragma unroll
    for (int i = 0; i < 4; ++i) {
        #pragma unroll
        for (int r = 0; r < 4; ++r) {
            int gm = crow + i * 16 + r;
            if (gm >= M) continue;
            #pragma unroll
            for (int j = 0; j < 4; ++j)
                P[(size_t)gm * dout + cbase + j * 16] = f2bf_hi(acc[i][j][r]);
        }
    }
}

// ---------------- L5 epilogue: h5 = bf16(leaky(mean_nbr(P1) + P2 + bias)) ----------------
__global__ __launch_bounds__(256) void agg_post256(
    const short* __restrict__ P1, const short* __restrict__ P2,
    const float* __restrict__ bias,
    const int* __restrict__ rowptr, const int* __restrict__ col,
    short* __restrict__ oh) {
    constexpr int DOUT = 256;
    constexpr int TPN = DOUT / 8;
    int node = blockIdx.x * 8 + threadIdx.x / TPN;
    if (node >= NN) return;
    int t = threadIdx.x % TPN;
    int s = rowptr[node], e = rowptr[node + 1];
    float acc[8] = {};
    for (int j0 = s; j0 < e; j0 += 8) {
        int idx[8];
        #pragma unroll
        for (int k = 0; k < 8; ++k) {
            int jj = j0 + k;
            idx[k] = col[(jj < e) ? jj : s];
        }
        bf16x8 v[8];
        #pragma unroll
        for (int k = 0; k < 8; ++k)
            v[k] = *(const bf16x8*)&P1[(size_t)idx[k] * DOUT + t * 8];
        #pragma unroll
        for (int k = 0; k < 8; ++k) {
            float msk = (j0 + k < e) ? 1.f : 0.f;
            #pragma unroll
            for (int m = 0; m < 8; ++m)
                acc[m] += msk * bf2f(v[k][m]);
        }
    }
    float inv = 1.f / fmaxf((float)(e - s), 1.f);
    bf16x8 p2 = *(const bf16x8*)&P2[(size_t)node * DOUT + t * 8];
    float4 ba = *(const float4*)&bias[t * 8];
    float4 bb = *(const float4*)&bias[t * 8 + 4];
    float bv[8] = {ba.x, ba.y, ba.z, ba.w, bb.x, bb.y, bb.z, bb.w};
    bf16x8 vh;
    #pragma unroll
    for (int m = 0; m < 8; ++m) {
        float c = acc[m] * inv + bf2f(p2[m]) + bv[m];
        c = (c >= 0.f) ? c : 0.01f * c;
        vh[m] = f2bf_hi(c);
    }
    *(bf16x8*)&oh[(size_t)node * DOUT + t * 8] = vh;
}

// ---------------- fused tail: pooled-adjacency gather + per-graph mean ----------------
#define ESPLIT 32
__global__ __launch_bounds__(256) void tail_pool(const short* __restrict__ h5,
                                                 const int* __restrict__ batch,
                                                 const int* __restrict__ rowptr,
                                                 const int* __restrict__ col,
                                                 const float* __restrict__ wgt,
                                                 float* __restrict__ ap,
                                                 float* __restrict__ hp,
                                                 int* __restrict__ gcnt) {
    int gi = blockIdx.x, c = blockIdx.y;
    int t = threadIdx.x;
    int lo = 0, hi = NN;
    while (lo < hi) { int m = (lo + hi) >> 1; if (batch[m] < gi) lo = m + 1; else hi = m; }
    int start = lo;
    hi = NN;
    while (lo < hi) { int m = (lo + hi) >> 1; if (batch[m] < gi + 1) lo = m + 1; else hi = m; }
    int end = lo;
    if (c == 0 && t == 0) gcnt[gi] = end - start;
    // ap: edge-parallel weighted gather
    int e0 = rowptr[start], e1 = rowptr[end];
    int L = e1 - e0;
    int ps = e0 + (int)(((long)L * c) / ESPLIT);
    int pe = e0 + (int)(((long)L * (c + 1)) / ESPLIT);
    float acc = 0.f;
    int p = ps;
    for (; p + 4 <= pe; p += 4) {
        int c0 = col[p], c1 = col[p + 1], c2 = col[p + 2], c3 = col[p + 3];
        float w0 = wgt[p], w1 = wgt[p + 1], w2 = wgt[p + 2], w3 = wgt[p + 3];
        float a0 = bf2f(h5[(size_t)c0 * 256 + t]);
        float a1 = bf2f(h5[(size_t)c1 * 256 + t]);
        float a2 = bf2f(h5[(size_t)c2 * 256 + t]);
        float a3 = bf2f(h5[(size_t)c3 * 256 + t]);
        acc += (w0 * a0 + w1 * a1) + (w2 * a2 + w3 * a3);
    }
    for (; p < pe; ++p)
        acc += wgt[p] * bf2f(h5[(size_t)col[p] * 256 + t]);
    if (pe > ps) atomicAdd(&ap[gi * 256 + t], acc);
    // hp: node-parallel sum
    int Ln = end - start;
    int cs = start + (int)(((long)Ln * c) / ESPLIT);
    int ce = start + (int)(((long)Ln * (c + 1)) / ESPLIT);
    float acch = 0.f;
    for (int n = cs; n < ce; ++n) acch += bf2f(h5[(size_t)n * 256 + t]);
    if (ce > cs) atomicAdd(&hp[gi * 256 + t], acch);
}

// ---------------- fused layer-6 + head (64 rows, exact f32) ----------------
__global__ __launch_bounds__(256) void head_kernel(
    const float* __restrict__ ap, const float* __restrict__ hp,
    const int* __restrict__ gcnt,
    const float* __restrict__ Wl6, const float* __restrict__ Wr6,
    const float* __restrict__ bl6,
    const float* __restrict__ Wlin, const float* __restrict__ blin,
    float* __restrict__ out) {
    __shared__ float a_s[256], h_s[256], t6[256];
    int g = blockIdx.x, t = threadIdx.x;
    float inv = 1.f / fmaxf((float)gcnt[g], 1.f);
    a_s[t] = ap[g * 256 + t] * inv;
    h_s[t] = hp[g * 256 + t] * inv;
    __syncthreads();
    float acc = 0.f;
    for (int k = 0; k < 256; ++k)
        acc += a_s[k] * Wl6[k * 256 + t] + h_s[k] * Wr6[k * 256 + t];
    t6[t] = acc + bl6[t];
    __syncthreads();
    if (t < 6) {
        float s = 0.f;
        for (int k = 0; k < 256; ++k) s += t6[k] * Wlin[k * 6 + t];
        out[g * 6 + t] = s + blin[t];
    }
}

extern "C" void kernel_launch(void* const* d_in, const int* in_sizes, int n_in,
                              void* d_out, int out_size, void* d_ws, size_t ws_size,
                              hipStream_t stream) {
    const float* x = (const float*)d_in[0];
    const int* ei = (const int*)d_in[1];
    const int* batch = (const int*)d_in[2];
    const float *Wl[6], *bl[6], *Wr[6];
    for (int l = 0; l < 6; ++l) {
        Wl[l] = (const float*)d_in[3 + 3 * l];
        bl[l] = (const float*)d_in[4 + 3 * l];
        Wr[l] = (const float*)d_in[5 + 3 * l];
    }
    const float* Wlin = (const float*)d_in[21];
    const float* blin = (const float*)d_in[22];
    float* out = (float*)d_out;

    char* ws = (char*)d_ws;
    size_t off = 0;
    auto alloc = [&](size_t bytes) {
        void* p = ws + off;
        off += (bytes + 255) & ~(size_t)255;
        return p;
    };
    short* xh   = (short*)alloc((size_t)MP * 128 * 2);
    short* hA   = (short*)alloc((size_t)MP * 512 * 2);
    short* hB   = (short*)alloc((size_t)MP * 512 * 2);
    short* aggb = (short*)alloc((size_t)MP * 512 * 2);
    short* P1   = (short*)alloc((size_t)MP * 256 * 2);
    short* P2   = (short*)alloc((size_t)MP * 256 * 2);
    int* col    = (int*)alloc((size_t)NE * 4);
    float* wgt  = (float*)alloc((size_t)NE * 4);
    int* bsum   = (int*)alloc(64 * 4);
    int* boff   = (int*)alloc(64 * 4);
    // ---- zeroed region start ----
    float* ap   = (float*)alloc((size_t)NG * 256 * 4);
    float* hp   = (float*)alloc((size_t)NG * 256 * 4);
    int* deg    = (int*)alloc((size_t)NN * 4);
    int* wcount = (int*)alloc((size_t)NN * 4);
    int* gcnt   = (int*)alloc((size_t)NG * 4);
    // ---- zeroed region end ----
    int* rowptr = (int*)alloc((size_t)(NN + 1) * 4);
    short* wtbuf = (short*)alloc((size_t)4 * 688128 * 2);
    (void)ws_size; (void)in_sizes; (void)n_in; (void)out_size;

    size_t zero_bytes = (size_t)((char*)gcnt - (char*)ap) + NG * 4;
    hipMemsetAsync((void*)ap, 0, zero_bytes, stream);

    const int* src = ei;
    const int* dst = ei + NE;

    const int dins[5]  = {128, 256, 256, 512, 512};
    const int douts[5] = {256, 256, 512, 512, 256};

    // weight layouts:
    // l=0..3 (agg-first): Bt_l = [dout][2K], Wl in k-cols [0,K), Wr in [K,2K)
    // l=4 (GEMM-first):   Bt_4 = [2*dout][K], Wl rows [0,dout), Wr rows [dout,2dout)
    short* Bt[5];
    int tcum = 0;
    {
        WPack pack;
        short* p = wtbuf;
        for (int l = 0; l < 5; ++l) {
            int K = dins[l], dout = douts[l];
            int ntiles = (K / 32) * (dout / 32);
            if (l < 4) {
                Bt[l] = p; p += (size_t)dout * 2 * K;
                pack.d[2 * l]     = { Wl[l], Bt[l], 2 * K, 0, K, dout, tcum }; tcum += ntiles;
                pack.d[2 * l + 1] = { Wr[l], Bt[l], 2 * K, K, K, dout, tcum }; tcum += ntiles;
            } else {
                Bt[l] = p; p += (size_t)2 * dout * K;
                pack.d[2 * l]     = { Wl[l], Bt[l],                     K, 0, K, dout, tcum }; tcum += ntiles;
                pack.d[2 * l + 1] = { Wr[l], Bt[l] + (size_t)dout * K,  K, 0, K, dout, tcum }; tcum += ntiles;
            }
        }
        prep_kernel<<<WCONV_BASE + tcum, 256, 0, stream>>>(pack, dst, deg, x, xh);
    }

    // parallel 3-pass scan: deg -> rowptr, then CSR fill
    scan_part<<<SCAN_BLOCKS, 1024, 0, stream>>>(deg, bsum);
    scan_mid<<<1, 64, 0, stream>>>(bsum, boff, rowptr);
    scan_fin<<<SCAN_BLOCKS, 1024, 0, stream>>>(deg, boff, rowptr);
    fill_kernel<<<(NE + 255) / 256, 256, 0, stream>>>(src, dst, rowptr, deg, wcount, col, wgt);

    // layers 1-4: agg-first (gather min-width stream, GEMM writes h directly)
    // L1: x(128) -> hA(256)
    agg_mean<128><<<(NN + 15) / 16, 256, 0, stream>>>(xh, rowptr, col, aggb);
    gemm_af<<<(MP / 128) * 2, 256, 0, stream>>>(aggb, xh, Bt[0], bl[0], hA, NN, 128, 256, 1);
    // L2: hA(256) -> hB(256)
    agg_mean<256><<<(NN + 7) / 8, 256, 0, stream>>>(hA, rowptr, col, aggb);
    gemm_af<<<(MP / 128) * 2, 256, 0, stream>>>(aggb, hA, Bt[1], bl[1], hB, NN, 256, 256, 1);
    // L3: hB(256) -> hA(512)
    agg_mean<256><<<(NN + 7) / 8, 256, 0, stream>>>(hB, rowptr, col, aggb);
    gemm_af<<<(MP / 128) * 4, 256, 0, stream>>>(aggb, hB, Bt[2], bl[2], hA, NN, 256, 512, 2);
    // L4: hA(512) -> hB(512)
    agg_mean<512><<<(NN + 3) / 4, 256, 0, stream>>>(hA, rowptr, col, aggb);
    gemm_af<<<(MP / 128) * 4, 256, 0, stream>>>(aggb, hA, Bt[3], bl[3], hB, NN, 512, 512, 2);
    // L5: GEMM-first: hB(512) -> P1|P2(256) -> hA(256)
    gemm_gf<<<(MP / 128) * 4, 256, 0, stream>>>(hB, Bt[4], P1, P2, NN, 512, 256, 2);
    agg_post256<<<(NN + 7) / 8, 256, 0, stream>>>(P1, P2, bl[4], rowptr, col, hA);

    // fused layer-6 + pool + head (exact: pool commutes with the linear layer)
    dim3 tgrid(NG, ESPLIT);
    tail_pool<<<tgrid, 256, 0, stream>>>(hA, batch, rowptr, col, wgt, ap, hp, gcnt);
    head_kernel<<<NG, 256, 0, stream>>>(ap, hp, gcnt, Wl[5], Wr[5], bl[5], Wlin, blin, out);
}